// Round 7
// baseline (855.652 us; speedup 1.0000x reference)
//
#include <hip/hip_runtime.h>

#define HA 256
#define WA 256
#define HB 128
#define WB 128
#define PA 48
#define PB 48
#define PP 96
#define MM 32
#define NPIXA (HA*WA)   // 65536
#define NPIXB (HB*WB)   // 16384

__device__ __forceinline__ float gelu_f(float x) {
    float z = 0.7978845608028654f * (x + 0.044715f * x * x * x);
    float e = __expf(2.0f * z);
    return x - x / (e + 1.0f);
}

// ---------------- tables + encoder fused ----------------
__global__ __launch_bounds__(256) void k_pre(
        float* tfxAT, float* tfyA, float* tiyA, float* tixAT,
        float* tfxBT, float* tfyB, float* tixB, float* tiyB,
        const float* u_a, const float* x_a, const float* u_b, const float* x_b,
        const float* wa, const float* ba, const float* wb, const float* bb,
        float* UA, float* UB) {
    const float TWO_PI = 6.28318530717958647692f;
    int bid = blockIdx.x;
    if (bid < 48) {
        int t = bid * 256 + threadIdx.x;
        if (t < MM * WA) {
            int k = t / WA, x = t - k * WA;
            int m = (k * x) & (WA - 1);
            float ang = TWO_PI * (float)m / (float)WA;
            float s, c; __sincosf(ang, &s, &c);
            float sc = 1.0f / (float)(HA * WA);
            tfxAT[(x*MM + k)*2]   = c * sc;
            tfxAT[(x*MM + k)*2+1] = -s * sc;
            tixAT[(x*MM + k)*2]   = c;
            tixAT[(x*MM + k)*2+1] = s;
            int ky = k - 16;
            int my = (ky * x) & (HA - 1);
            float angy = TWO_PI * (float)my / (float)HA;
            float sy, cy; __sincosf(angy, &sy, &cy);
            tfyA[2*t] = cy; tfyA[2*t+1] = -sy;
            tiyA[2*t] = cy; tiyA[2*t+1] = sy;
        } else if (t < MM * WA + MM * WB) {
            int t2 = t - MM * WA;
            int k = t2 / WB, x = t2 - k * WB;
            int m = (k * x) & (WB - 1);
            float ang = TWO_PI * (float)m / (float)WB;
            float s, c; __sincosf(ang, &s, &c);
            float sc = 1.0f / (float)(HB * WB);
            tfxBT[(x*MM + k)*2]   = c * sc;
            tfxBT[(x*MM + k)*2+1] = -s * sc;
            float wgt = (k == 0) ? 1.0f : 2.0f;
            tixB[2*t2] = wgt * c; tixB[2*t2+1] = wgt * s;
            int ky = k - 16;
            int my = (ky * x) & (HB - 1);
            float angy = TWO_PI * (float)my / (float)HB;
            float sy, cy; __sincosf(angy, &sy, &cy);
            tfyB[2*t2] = cy; tfyB[2*t2+1] = -sy;
            tiyB[2*t2] = cy; tiyB[2*t2+1] = sy;
        }
    } else {
        int eb = bid - 48;
        int o = eb / 320;
        int chunk = eb - o * 320;
        if (chunk < 256) {
            int pix = chunk * 256 + threadIdx.x;
            UA[(size_t)o*NPIXA + pix] = wa[o*3+0]*x_a[pix] + wa[o*3+1]*x_a[NPIXA+pix]
                                      + wa[o*3+2]*u_a[pix] + ba[o];
        } else {
            int pix = (chunk - 256) * 256 + threadIdx.x;
            UB[(size_t)o*NPIXB + pix] = wb[o*3+0]*x_b[pix] + wb[o*3+1]*x_b[NPIXB+pix]
                                      + wb[o*3+2]*u_b[pix] + bb[o];
        }
    }
}

// ---------------- forward DFT along x ----------------
__global__ __launch_bounds__(256) void k_fwd_x(
        const float* __restrict__ UA, const float* __restrict__ UB,
        float2* __restrict__ FA, float2* __restrict__ FB,
        const float* __restrict__ tfxAT, const float* __restrict__ tfxBT) {
    extern __shared__ float ls[];
    int bid = blockIdx.x;
    const float* U; float2* F; const float2* tT; int N;
    const int NBA = PA * HA / 32;   // 384
    if (bid < NBA) { U = UA; F = FA; tT = (const float2*)tfxAT; N = WA; }
    else { bid -= NBA; U = UB; F = FB; tT = (const float2*)tfxBT; N = WB; }
    int r0 = bid * 32;
    int tot4 = 32 * N / 4;
    const float4* src = (const float4*)(U + (size_t)r0 * N);
    for (int i = threadIdx.x; i < tot4; i += 256) ((float4*)ls)[i] = src[i];
    __syncthreads();
    int kx = threadIdx.x & 31;
    int rg = (threadIdx.x >> 5) * 4;
    float ar0=0,ai0=0,ar1=0,ai1=0,ar2=0,ai2=0,ar3=0,ai3=0;
    for (int x = 0; x < N; ++x) {
        float2 t = tT[x*MM + kx];
        float u0 = ls[(rg+0)*N + x];
        float u1 = ls[(rg+1)*N + x];
        float u2 = ls[(rg+2)*N + x];
        float u3 = ls[(rg+3)*N + x];
        ar0 += u0*t.x; ai0 += u0*t.y;
        ar1 += u1*t.x; ai1 += u1*t.y;
        ar2 += u2*t.x; ai2 += u2*t.y;
        ar3 += u3*t.x; ai3 += u3*t.y;
    }
    F[(size_t)(r0+rg+0)*MM + kx] = make_float2(ar0, ai0);
    F[(size_t)(r0+rg+1)*MM + kx] = make_float2(ar1, ai1);
    F[(size_t)(r0+rg+2)*MM + kx] = make_float2(ar2, ai2);
    F[(size_t)(r0+rg+3)*MM + kx] = make_float2(ar3, ai3);
}

// ---------------- forward DFT along y: LDS-chunked ----------------
__global__ __launch_bounds__(256) void k_fwd_y(
        const float2* __restrict__ FA, const float2* __restrict__ FB, float2* CIN,
        const float* __restrict__ tfyA, const float* __restrict__ tfyB) {
    __shared__ float2 fch[64*32];    // 16 KB: 64-row F chunk
    __shared__ float2 tls[8*256];    // 16 KB: 8 T rows
    int bid = blockIdx.x;
    const float2* F; const float2* tab; int Ny, pbase;
    if (bid < PA*4) { F = FA; tab = (const float2*)tfyA; Ny = HA; pbase = 0; }
    else { bid -= PA*4; F = FB; tab = (const float2*)tfyB; Ny = HB; pbase = PA; }
    int c = bid >> 2, jg = bid & 3;
    int t = threadIdx.x;
    for (int idx = t; idx < 8*Ny; idx += 256)
        tls[idx] = tab[jg*8*Ny + idx];
    int j = t >> 5, kx = t & 31;
    float re = 0.f, im = 0.f;
    for (int ch = 0; ch < Ny/64; ++ch) {
        __syncthreads();
        const float4* src = (const float4*)(F + (size_t)c*Ny*MM + ch*64*MM);
        for (int idx = t; idx < 1024; idx += 256) ((float4*)fch)[idx] = src[idx];
        __syncthreads();
        const float2* tj = tls + j*Ny + ch*64;
        #pragma unroll 4
        for (int y = 0; y < 64; ++y) {
            float2 f = fch[y*32 + kx];
            float2 tv = tj[y];
            re += f.x*tv.x - f.y*tv.y;
            im += f.x*tv.y + f.y*tv.x;
        }
    }
    CIN[((pbase + c)*MM + jg*8 + j)*MM + kx] = make_float2(re, im);
}

// ---------------- spectral channel mix ----------------
__global__ __launch_bounds__(256) void k_spectral(
        const float* __restrict__ Wre, const float* __restrict__ Wim,
        const float2* __restrict__ CIN, float2* __restrict__ COUT) {
    int t = blockIdx.x * 256 + threadIdx.x;
    int p = t >> 10;
    int mode = t & 1023;
    const float* wr = Wre + (size_t)p * PP * 1024 + mode;
    const float* wi = Wim + (size_t)p * PP * 1024 + mode;
    float re = 0.f, im = 0.f;
    #pragma unroll 8
    for (int q = 0; q < PP; ++q) {
        float a = wr[(size_t)q << 10];
        float b = wi[(size_t)q << 10];
        float2 cv = CIN[(q << 10) + mode];
        re += a*cv.x - b*cv.y;
        im += a*cv.y + b*cv.x;
    }
    COUT[t] = make_float2(re, im);
}

// ---------------- inverse DFT along y, A channels: COUT -> DA ----------------
__global__ __launch_bounds__(256) void k_invy_a(
        const float2* __restrict__ COUT, float2* __restrict__ DA,
        const float* __restrict__ tiyA) {
    int c = blockIdx.x >> 5, yg = blockIdx.x & 31;
    int kx = threadIdx.x & 31, yr = threadIdx.x >> 5;
    int y = yg * 8 + yr;
    float re = 0.f, im = 0.f;
    const float2* crow = COUT + (size_t)c * MM * MM + kx;
    const float2* tab = (const float2*)tiyA;
    #pragma unroll 8
    for (int j = 0; j < MM; ++j) {
        float2 w = crow[j * MM];
        float2 tv = tab[j * HA + y];
        re += w.x*tv.x - w.y*tv.y;
        im += w.x*tv.y + w.y*tv.x;
    }
    DA[(size_t)(c*HA + y)*MM + kx] = make_float2(re, im);
}

// ---------------- fused inverse tail ----------------
// A (blocks 0..1023): quarter-row (y, xq): DA -> inv_x (reg twiddle-table) ->
//   conv1x1+gelu x2 + resid -> UA.  B (1024..1791): inv_y + inv_x -> SB.
__global__ __launch_bounds__(256) void k_inv_tail(
        const float2* __restrict__ COUT, const float2* __restrict__ DA,
        float* __restrict__ UA, float* __restrict__ SB,
        const float* __restrict__ tiyB, const float* __restrict__ tixB,
        const float* __restrict__ tixAT,
        const float* __restrict__ w1, const float* __restrict__ b1,
        const float* __restrict__ w2, const float* __restrict__ b2) {
    __shared__ float sm[8688];
    int t = threadIdx.x;
    if (blockIdx.x < 1024) {
        float* b0   = sm;                    // [48][66] conv1 out (overlays Dw)
        float2* Dw  = (float2*)sm;           // [48][33]
        float* sl   = sm + 3168;             // [48][66] inv-x out
        float* wl   = sm + 6336;             // 2304
        float* bl   = sm + 8640;             // 48
        int y  = blockIdx.x >> 2;
        int xq = (blockIdx.x & 3) * 64;
        for (int idx = t; idx < 1536; idx += 256) {
            int c = idx >> 5, k = idx & 31;
            float2 v = DA[(size_t)(c*HA + y)*MM + k];
            float wgt = (k == 0) ? 1.0f : 2.0f;
            Dw[c*33 + k] = make_float2(v.x*wgt, v.y*wgt);
        }
        for (int idx = t; idx < 2304; idx += 256) {
            int o = idx % 48, i = idx / 48;
            wl[i*48 + o] = w1[o*48 + i];
        }
        if (t < 48) bl[t] = b1[t];
        __syncthreads();
        // phase 2: inv-x DFT, lane = channel, wave covers 16 x's
        {
            int w = t >> 6, lane = t & 63;
            float dwr[32], dwi[32];
            #pragma unroll
            for (int k = 0; k < 32; ++k) { dwr[k] = 0.f; dwi[k] = 0.f; }
            if (lane < 48) {
                const float2* dr = Dw + lane*33;
                #pragma unroll
                for (int k = 0; k < 32; ++k) { float2 v = dr[k]; dwr[k] = v.x; dwi[k] = v.y; }
            }
            int xbase = xq + w*16;
            for (int j = 0; j < 16; ++j) {
                const float4* tw4 = (const float4*)(tixAT + (size_t)(xbase + j) * (MM*2));
                float acc = 0.f;
                #pragma unroll
                for (int k4 = 0; k4 < 16; ++k4) {
                    float4 tv = tw4[k4];
                    acc += dwr[2*k4]*tv.x   - dwi[2*k4]*tv.y;
                    acc += dwr[2*k4+1]*tv.z - dwi[2*k4+1]*tv.w;
                }
                if (lane < 48) sl[lane*66 + w*16 + j] = acc;
            }
        }
        __syncthreads();
        int pp = t & 31, og = t >> 5;   // 32 px-pairs x 8 groups of 6 oc
        // phase 3: conv1 + gelu -> b0
        {
            float acc[6][2];
            #pragma unroll
            for (int oo = 0; oo < 6; ++oo) { float bv = bl[og*6+oo]; acc[oo][0]=bv; acc[oo][1]=bv; }
            for (int i = 0; i < 48; ++i) {
                float2 s = *(const float2*)(sl + i*66 + pp*2);
                const float* wb_ = wl + i*48 + og*6;
                float2 wa_ = *(const float2*)(wb_);
                float2 wbq = *(const float2*)(wb_+2);
                float2 wc_ = *(const float2*)(wb_+4);
                float wq[6] = {wa_.x, wa_.y, wbq.x, wbq.y, wc_.x, wc_.y};
                #pragma unroll
                for (int oo = 0; oo < 6; ++oo) { acc[oo][0]+=wq[oo]*s.x; acc[oo][1]+=wq[oo]*s.y; }
            }
            __syncthreads();   // all Dw/sl reads done before b0 overlays Dw
            #pragma unroll
            for (int oo = 0; oo < 6; ++oo) {
                int o = og*6+oo;
                float2 g; g.x = gelu_f(acc[oo][0]); g.y = gelu_f(acc[oo][1]);
                *(float2*)(b0 + o*66 + pp*2) = g;
            }
        }
        __syncthreads();
        for (int idx = t; idx < 2304; idx += 256) {
            int o = idx % 48, i = idx / 48;
            wl[i*48 + o] = w2[o*48 + i];
        }
        if (t < 48) bl[t] = b2[t];
        __syncthreads();
        // phase 4: conv2 + gelu + residual -> UA
        {
            float acc[6][2];
            #pragma unroll
            for (int oo = 0; oo < 6; ++oo) { float bv = bl[og*6+oo]; acc[oo][0]=bv; acc[oo][1]=bv; }
            for (int i = 0; i < 48; ++i) {
                float2 s = *(const float2*)(b0 + i*66 + pp*2);
                const float* wb_ = wl + i*48 + og*6;
                float2 wa_ = *(const float2*)(wb_);
                float2 wbq = *(const float2*)(wb_+2);
                float2 wc_ = *(const float2*)(wb_+4);
                float wq[6] = {wa_.x, wa_.y, wbq.x, wbq.y, wc_.x, wc_.y};
                #pragma unroll
                for (int oo = 0; oo < 6; ++oo) { acc[oo][0]+=wq[oo]*s.x; acc[oo][1]+=wq[oo]*s.y; }
            }
            #pragma unroll
            for (int oo = 0; oo < 6; ++oo) {
                int o = og*6+oo;
                size_t obase = (size_t)o*NPIXA + (size_t)y*WA + xq + pp*2;
                float2 rv = *(const float2*)(UA + obase);
                float2 r;
                r.x = gelu_f(acc[oo][0]) + rv.x;
                r.y = gelu_f(acc[oo][1]) + rv.y;
                *(float2*)(UA + obase) = r;
            }
        }
    } else {
        int b = blockIdx.x - 1024;
        int c = b >> 4, yg = b & 15;
        int kx = t & 31, yr = t >> 5;
        int y = yg * 8 + yr;
        float re = 0.f, im = 0.f;
        const float2* crow = COUT + (size_t)(PA + c) * MM * MM + kx;
        const float2* tab = (const float2*)tiyB;
        #pragma unroll 8
        for (int j = 0; j < 32; ++j) {
            float2 w = crow[j * MM];
            float2 tv = tab[j * HB + y];
            re += w.x*tv.x - w.y*tv.y;
            im += w.x*tv.y + w.y*tv.x;
        }
        float2* ds = (float2*)sm;
        ds[yr*32 + kx] = make_float2(re, im);
        __syncthreads();
        int x = t & 127, rp = t >> 7;
        const float2* txb = (const float2*)tixB;
        for (int rr = rp; rr < 8; rr += 2) {
            const float2* drow = ds + rr*32;
            float a = 0.f;
            #pragma unroll
            for (int k2 = 0; k2 < 32; ++k2) {
                float2 tv = txb[k2*WB + x];
                float2 d = drow[k2];
                a += d.x*tv.x - d.y*tv.y;
            }
            SB[((size_t)c*HB + yg*8 + rr)*WB + x] = a;
        }
    }
}

// ---------------- B-branch 3x3 conv: 1 px/lane, no shuffles, 2-deep prefetch ----------------
// grid (64, 16): block = 2 rows x 2 half-rows (4 waves), oc-group of 3.
__global__ __launch_bounds__(256) void k_conv3x3(
        const float* __restrict__ in, float* __restrict__ out,
        const float* __restrict__ w, const float* __restrict__ b,
        const float* resid) {
    __shared__ __attribute__((aligned(16))) float wl[PB*9*4];
    __shared__ float bl[3];
    int o0 = blockIdx.y * 3;
    for (int idx = threadIdx.x; idx < PB*9*3; idx += 256) {
        int oo = idx % 3;
        int r = idx / 3;
        int tap = r % 9;
        int ic = r / 9;
        wl[(ic*9+tap)*4 + oo] = w[((size_t)(o0+oo)*PB + ic)*9 + tap];
    }
    if (threadIdx.x < 3) bl[threadIdx.x] = b[o0+threadIdx.x];
    __syncthreads();

    int wv = threadIdx.x >> 6;
    int lane = threadIdx.x & 63;
    int row = blockIdx.x * 2 + (wv >> 1);
    int x = ((wv & 1) << 6) + lane;

    float acc[3];
    acc[0] = bl[0]; acc[1] = bl[1]; acc[2] = bl[2];

    auto loadrow = [&](int ic, float* dst) {
        const float* ip = in + (size_t)ic*NPIXB;
        #pragma unroll
        for (int dy = 0; dy < 3; ++dy) {
            int gy = row - 1 + dy;
            if (gy >= 0 && gy < HB) {
                const float* rp_ = ip + gy*WB;
                dst[dy*3+0] = (x > 0)   ? rp_[x-1] : 0.f;
                dst[dy*3+1] = rp_[x];
                dst[dy*3+2] = (x < 127) ? rp_[x+1] : 0.f;
            } else {
                dst[dy*3+0] = 0.f; dst[dy*3+1] = 0.f; dst[dy*3+2] = 0.f;
            }
        }
    };

    float cur[9], nxt[9];
    loadrow(0, cur);
    loadrow(1, nxt);
    for (int ic = 0; ic < PB; ++ic) {
        float fut[9];
        if (ic + 2 < PB) loadrow(ic + 2, fut);
        const float* wb_ = wl + ic*36;
        #pragma unroll
        for (int tap = 0; tap < 9; ++tap) {
            float4 w3 = *(const float4*)(wb_ + tap*4);
            float s = cur[tap];
            acc[0] += w3.x*s;
            acc[1] += w3.y*s;
            acc[2] += w3.z*s;
        }
        #pragma unroll
        for (int q = 0; q < 9; ++q) { cur[q] = nxt[q]; nxt[q] = fut[q]; }
    }
    #pragma unroll
    for (int oo = 0; oo < 3; ++oo) {
        size_t obase = (size_t)(o0+oo)*NPIXB + (size_t)row*WB + x;
        float r = gelu_f(acc[oo]);
        if (resid) r += resid[obase];
        out[obase] = r;
    }
}

// ---------------- decoder: 48->1 both branches ----------------
__global__ __launch_bounds__(256) void k_decode(
        const float* __restrict__ UA, const float* __restrict__ UB,
        const float* dwa, const float* dba,
        const float* dwb, const float* dbb, float* outp) {
    int t = blockIdx.x*256 + threadIdx.x;
    if (t < NPIXA) {
        float acc = dba[0];
        #pragma unroll 8
        for (int p = 0; p < PA; ++p) acc += dwa[p]*UA[(size_t)p*NPIXA + t];
        outp[t] = acc;
    } else {
        int u = t - NPIXA;
        float acc = dbb[0];
        #pragma unroll 8
        for (int p = 0; p < PB; ++p) acc += dwb[p]*UB[(size_t)p*NPIXB + u];
        outp[t] = acc;
    }
}

extern "C" void kernel_launch(void* const* d_in, const int* in_sizes, int n_in,
                              void* d_out, int out_size, void* d_ws, size_t ws_size,
                              hipStream_t stream) {
    const float* u_a   = (const float*)d_in[0];
    const float* x_a   = (const float*)d_in[1];
    const float* u_b   = (const float*)d_in[2];
    const float* x_b   = (const float*)d_in[3];
    const float* enc_a_w = (const float*)d_in[4];
    const float* enc_a_b = (const float*)d_in[5];
    const float* enc_b_w = (const float*)d_in[6];
    const float* enc_b_b = (const float*)d_in[7];
    const float* dec_a_w = (const float*)d_in[8];
    const float* dec_a_b = (const float*)d_in[9];
    const float* dec_b_w = (const float*)d_in[10];
    const float* dec_b_b = (const float*)d_in[11];
    const float* c1a_w = (const float*)d_in[12];
    const float* c1a_b = (const float*)d_in[13];
    const float* c2a_w = (const float*)d_in[14];
    const float* c2a_b = (const float*)d_in[15];
    const float* c1b_w = (const float*)d_in[16];
    const float* c1b_b = (const float*)d_in[17];
    const float* c2b_w = (const float*)d_in[18];
    const float* c2b_b = (const float*)d_in[19];
    const float* A_re = (const float*)d_in[20];
    const float* A_im = (const float*)d_in[21];

    float* ws = (float*)d_ws;
    size_t off = 0;
    auto alloc = [&](size_t n) { float* p = ws + off; off += n; return p; };
    float* TfxAT = alloc(MM*WA*2);
    float* TixAT = alloc(MM*WA*2);
    float* TfyA  = alloc(MM*HA*2);
    float* TiyA  = alloc(MM*HA*2);
    float* TfxBT = alloc(MM*WB*2);
    float* TfyB  = alloc(MM*HB*2);
    float* TixB  = alloc(MM*WB*2);
    float* TiyB  = alloc(MM*HB*2);
    float* UA = alloc((size_t)PA*NPIXA);
    float* UB = alloc((size_t)PB*NPIXB);
    float* SB = alloc((size_t)PB*NPIXB);
    float* TB = alloc((size_t)PB*NPIXB);
    float2* FA = (float2*)alloc((size_t)PA*HA*MM*2);   // doubles as DA
    float2* FB = (float2*)alloc((size_t)PB*HB*MM*2);
    float2* CIN  = (float2*)alloc((size_t)PP*MM*MM*2);
    float2* COUT = (float2*)alloc((size_t)PP*MM*MM*2);
    if (off * sizeof(float) > ws_size) return;

    k_pre<<<dim3(48 + 48*320), dim3(256), 0, stream>>>(
        TfxAT,TfyA,TiyA,TixAT,TfxBT,TfyB,TixB,TiyB,
        u_a,x_a,u_b,x_b, enc_a_w,enc_a_b,enc_b_w,enc_b_b, UA,UB);
    for (int l = 0; l < 4; ++l) {
        k_fwd_x<<<dim3(576), dim3(256), 32768, stream>>>(UA,UB,FA,FB,TfxAT,TfxBT);
        k_fwd_y<<<dim3(384), dim3(256), 0, stream>>>(FA,FB,CIN,TfyA,TfyB);
        k_spectral<<<dim3(384), dim3(256), 0, stream>>>(
            A_re + (size_t)l*PP*PP*MM*MM, A_im + (size_t)l*PP*PP*MM*MM, CIN, COUT);
        k_invy_a<<<dim3(1536), dim3(256), 0, stream>>>(COUT, FA, TiyA);
        k_inv_tail<<<dim3(1792), dim3(256), 0, stream>>>(COUT, FA, UA, SB,
            TiyB, TixB, TixAT,
            c1a_w + (size_t)l*PA*PA, c1a_b + (size_t)l*PA,
            c2a_w + (size_t)l*PA*PA, c2a_b + (size_t)l*PA);
        k_conv3x3<<<dim3(64,16), dim3(256), 0, stream>>>(SB, TB,
            c1b_w + (size_t)l*PB*PB*9, c1b_b + (size_t)l*PB, (const float*)nullptr);
        k_conv3x3<<<dim3(64,16), dim3(256), 0, stream>>>(TB, UB,
            c2b_w + (size_t)l*PB*PB*9, c2b_b + (size_t)l*PB, UB);
    }
    k_decode<<<dim3(320), dim3(256), 0, stream>>>(UA, UB,
        dec_a_w, dec_a_b, dec_b_w, dec_b_b, (float*)d_out);
}

// Round 8
// 648.533 us; speedup vs baseline: 1.3194x; 1.3194x over previous
//
#include <hip/hip_runtime.h>

#define HA 256
#define WA 256
#define HB 128
#define WB 128
#define PA 48
#define PB 48
#define PP 96
#define MM 32
#define NPIXA (HA*WA)   // 65536
#define NPIXB (HB*WB)   // 16384

typedef short bf16x8 __attribute__((ext_vector_type(8)));
typedef float f32x4 __attribute__((ext_vector_type(4)));

__device__ __forceinline__ float gelu_f(float x) {
    float z = 0.7978845608028654f * (x + 0.044715f * x * x * x);
    float e = __expf(2.0f * z);
    return x - x / (e + 1.0f);
}

__device__ __forceinline__ short f2bf(float f) {
    unsigned u = __float_as_uint(f);
    unsigned r = (u + 0x7FFFu + ((u >> 16) & 1u)) >> 16;
    return (short)r;
}

// ---------------- tables + encoder + conv-weight transform, fused ----------------
__global__ __launch_bounds__(256) void k_pre(
        float* tfxAT, float* tfyA, float* tiyA, float* tixAT,
        float* tfxBT, float* tfyB, float* tixB, float* tiyB,
        const float* u_a, const float* x_a, const float* u_b, const float* x_b,
        const float* wa, const float* ba, const float* wb, const float* bb,
        float* UA, float* UB,
        const float* c1b_w, const float* c2b_w, short* WT) {
    const float TWO_PI = 6.28318530717958647692f;
    int bid = blockIdx.x;
    if (bid < 48) {
        int t = bid * 256 + threadIdx.x;
        if (t < MM * WA) {
            int k = t / WA, x = t - k * WA;
            int m = (k * x) & (WA - 1);
            float ang = TWO_PI * (float)m / (float)WA;
            float s, c; __sincosf(ang, &s, &c);
            float sc = 1.0f / (float)(HA * WA);
            tfxAT[(x*MM + k)*2]   = c * sc;
            tfxAT[(x*MM + k)*2+1] = -s * sc;
            tixAT[(x*MM + k)*2]   = c;
            tixAT[(x*MM + k)*2+1] = s;
            int ky = k - 16;
            int my = (ky * x) & (HA - 1);
            float angy = TWO_PI * (float)my / (float)HA;
            float sy, cy; __sincosf(angy, &sy, &cy);
            tfyA[2*t] = cy; tfyA[2*t+1] = -sy;
            tiyA[2*t] = cy; tiyA[2*t+1] = sy;
        } else if (t < MM * WA + MM * WB) {
            int t2 = t - MM * WA;
            int k = t2 / WB, x = t2 - k * WB;
            int m = (k * x) & (WB - 1);
            float ang = TWO_PI * (float)m / (float)WB;
            float s, c; __sincosf(ang, &s, &c);
            float sc = 1.0f / (float)(HB * WB);
            tfxBT[(x*MM + k)*2]   = c * sc;
            tfxBT[(x*MM + k)*2+1] = -s * sc;
            float wgt = (k == 0) ? 1.0f : 2.0f;
            tixB[2*t2] = wgt * c; tixB[2*t2+1] = wgt * s;
            int ky = k - 16;
            int my = (ky * x) & (HB - 1);
            float angy = TWO_PI * (float)my / (float)HB;
            float sy, cy; __sincosf(angy, &sy, &cy);
            tfyB[2*t2] = cy; tfyB[2*t2+1] = -sy;
            tiyB[2*t2] = cy; tiyB[2*t2+1] = sy;
        }
    } else if (bid < 48 + 48*320) {
        int eb = bid - 48;
        int o = eb / 320;
        int chunk = eb - o * 320;
        if (chunk < 256) {
            int pix = chunk * 256 + threadIdx.x;
            UA[(size_t)o*NPIXA + pix] = wa[o*3+0]*x_a[pix] + wa[o*3+1]*x_a[NPIXA+pix]
                                      + wa[o*3+2]*u_a[pix] + ba[o];
        } else {
            int pix = (chunk - 256) * 256 + threadIdx.x;
            UB[(size_t)o*NPIXB + pix] = wb[o*3+0]*x_b[pix] + wb[o*3+1]*x_b[NPIXB+pix]
                                      + wb[o*3+2]*u_b[pix] + bb[o];
        }
    } else {
        int g = (bid - (48 + 48*320)) * 256 + threadIdx.x;
        if (g < 4*2*9*48*64) {
            int l  = g / 55296;
            int r1 = g - l*55296;
            int cv = r1 / 27648;
            int r2 = r1 - cv*27648;
            int tap = r2 / 3072;
            int r3 = r2 - tap*3072;
            int oc = r3 >> 6;
            int ic = r3 & 63;
            const float* src = cv ? c2b_w : c1b_w;
            float v = 0.f;
            if (ic < 48) v = src[(((size_t)l*48 + oc)*48 + ic)*9 + tap];
            WT[g] = f2bf(v);
        }
    }
}

// ---------------- forward DFT along x ----------------
__global__ __launch_bounds__(256) void k_fwd_x(
        const float* __restrict__ UA, const float* __restrict__ UB,
        float2* __restrict__ FA, float2* __restrict__ FB,
        const float* __restrict__ tfxAT, const float* __restrict__ tfxBT) {
    extern __shared__ float ls[];
    int bid = blockIdx.x;
    const float* U; float2* F; const float2* tT; int N;
    const int NBA = PA * HA / 32;   // 384
    if (bid < NBA) { U = UA; F = FA; tT = (const float2*)tfxAT; N = WA; }
    else { bid -= NBA; U = UB; F = FB; tT = (const float2*)tfxBT; N = WB; }
    int r0 = bid * 32;
    int tot4 = 32 * N / 4;
    const float4* src = (const float4*)(U + (size_t)r0 * N);
    for (int i = threadIdx.x; i < tot4; i += 256) ((float4*)ls)[i] = src[i];
    __syncthreads();
    int kx = threadIdx.x & 31;
    int rg = (threadIdx.x >> 5) * 4;
    float ar0=0,ai0=0,ar1=0,ai1=0,ar2=0,ai2=0,ar3=0,ai3=0;
    for (int x = 0; x < N; ++x) {
        float2 t = tT[x*MM + kx];
        float u0 = ls[(rg+0)*N + x];
        float u1 = ls[(rg+1)*N + x];
        float u2 = ls[(rg+2)*N + x];
        float u3 = ls[(rg+3)*N + x];
        ar0 += u0*t.x; ai0 += u0*t.y;
        ar1 += u1*t.x; ai1 += u1*t.y;
        ar2 += u2*t.x; ai2 += u2*t.y;
        ar3 += u3*t.x; ai3 += u3*t.y;
    }
    F[(size_t)(r0+rg+0)*MM + kx] = make_float2(ar0, ai0);
    F[(size_t)(r0+rg+1)*MM + kx] = make_float2(ar1, ai1);
    F[(size_t)(r0+rg+2)*MM + kx] = make_float2(ar2, ai2);
    F[(size_t)(r0+rg+3)*MM + kx] = make_float2(ar3, ai3);
}

// ---------------- forward DFT along y ----------------
__global__ __launch_bounds__(256) void k_fwd_y(
        const float2* __restrict__ FA, const float2* __restrict__ FB, float2* CIN,
        const float* __restrict__ tfyA, const float* __restrict__ tfyB) {
    int bid = blockIdx.x;
    const float2* F; const float2* tab; int Ny, pbase;
    if (bid < PA*4) { F = FA; tab = (const float2*)tfyA; Ny = HA; pbase = 0; }
    else { bid -= PA*4; F = FB; tab = (const float2*)tfyB; Ny = HB; pbase = PA; }
    int c = bid >> 2;
    int j = (bid & 3) * 8 + (threadIdx.x >> 5);
    int kx = threadIdx.x & 31;
    float re = 0.f, im = 0.f;
    const float2* fr = F + (size_t)c * Ny * MM + kx;
    const float2* tj = tab + j * Ny;
    #pragma unroll 4
    for (int y = 0; y < Ny; ++y) {
        float2 f = fr[y * MM];
        float2 t = tj[y];
        re += f.x*t.x - f.y*t.y;
        im += f.x*t.y + f.y*t.x;
    }
    CIN[((pbase + c)*MM + j)*MM + kx] = make_float2(re, im);
}

// ---------------- spectral channel mix ----------------
__global__ __launch_bounds__(256) void k_spectral(
        const float* __restrict__ Wre, const float* __restrict__ Wim,
        const float2* __restrict__ CIN, float2* __restrict__ COUT) {
    int t = blockIdx.x * 256 + threadIdx.x;
    int p = t >> 10;
    int mode = t & 1023;
    const float* wr = Wre + (size_t)p * PP * 1024 + mode;
    const float* wi = Wim + (size_t)p * PP * 1024 + mode;
    float re = 0.f, im = 0.f;
    #pragma unroll 8
    for (int q = 0; q < PP; ++q) {
        float a = wr[(size_t)q << 10];
        float b = wi[(size_t)q << 10];
        float2 cv = CIN[(q << 10) + mode];
        re += a*cv.x - b*cv.y;
        im += a*cv.y + b*cv.x;
    }
    COUT[t] = make_float2(re, im);
}

// ---------------- fused inverse ----------------
__global__ __launch_bounds__(256) void k_inv(
        const float2* __restrict__ COUT, float* __restrict__ UA,
        float* __restrict__ SB,
        const float* __restrict__ tiyA, const float* __restrict__ tiyB,
        const float* __restrict__ tixB, const float* __restrict__ tixAT,
        const float* __restrict__ w1, const float* __restrict__ b1,
        const float* __restrict__ w2, const float* __restrict__ b2) {
    __shared__ float sm[14896];
    int t = threadIdx.x;
    if (blockIdx.x < 512) {
        float* sl   = sm;
        float* b0   = sm + 6240;
        float2* Dw  = (float2*)(sm + 6240);
        float* wl   = sm + 12480;
        float* bl   = sm + 14784;
        float2* tl  = (float2*)(sm + 14832);
        int y  = blockIdx.x >> 1;
        int xh = (blockIdx.x & 1) << 7;
        if (t < 32) tl[t] = ((const float2*)tiyA)[t*HA + y];
        for (int idx = t; idx < 2304; idx += 256) {
            int o = idx % 48, i = idx / 48;
            wl[i*48 + o] = w1[o*48 + i];
        }
        if (t < 48) bl[t] = b1[t];
        __syncthreads();
        {
            int kx = t & 31, c0 = t >> 5;
            float re[6] = {0,0,0,0,0,0}, im[6] = {0,0,0,0,0,0};
            for (int j = 0; j < 32; ++j) {
                float2 ty = tl[j];
                #pragma unroll
                for (int k = 0; k < 6; ++k) {
                    float2 w = COUT[((c0 + 8*k)*32 + j)*32 + kx];
                    re[k] += w.x*ty.x - w.y*ty.y;
                    im[k] += w.x*ty.y + w.y*ty.x;
                }
            }
            float wgt = (kx == 0) ? 1.0f : 2.0f;
            #pragma unroll
            for (int k = 0; k < 6; ++k)
                Dw[(c0 + 8*k)*33 + kx] = make_float2(re[k]*wgt, im[k]*wgt);
        }
        __syncthreads();
        {
            int w = t >> 6, lane = t & 63;
            float dwr[32], dwi[32];
            #pragma unroll
            for (int k = 0; k < 32; ++k) { dwr[k] = 0.f; dwi[k] = 0.f; }
            if (lane < 48) {
                const float2* dr = Dw + lane*33;
                #pragma unroll
                for (int k = 0; k < 32; ++k) { float2 v = dr[k]; dwr[k] = v.x; dwi[k] = v.y; }
            }
            int xbase = xh + w*32;
            for (int j = 0; j < 32; ++j) {
                const float4* tw4 = (const float4*)(tixAT + (size_t)(xbase + j) * (MM*2));
                float acc = 0.f;
                #pragma unroll
                for (int k4 = 0; k4 < 16; ++k4) {
                    float4 tv = tw4[k4];
                    acc += dwr[2*k4]*tv.x   - dwi[2*k4]*tv.y;
                    acc += dwr[2*k4+1]*tv.z - dwi[2*k4+1]*tv.w;
                }
                if (lane < 48) sl[lane*130 + w*32 + j] = acc;
            }
        }
        __syncthreads();
        int pp = t & 63, og = t >> 6;
        {
            float acc[12][2];
            #pragma unroll
            for (int oo = 0; oo < 12; ++oo) { float bv = bl[og*12+oo]; acc[oo][0]=bv; acc[oo][1]=bv; }
            for (int i = 0; i < 48; ++i) {
                float2 s = *(const float2*)(sl + i*130 + pp*2);
                const float4* wv = (const float4*)(wl + i*48 + og*12);
                float wq[12];
                *(float4*)(wq+0)=wv[0]; *(float4*)(wq+4)=wv[1]; *(float4*)(wq+8)=wv[2];
                #pragma unroll
                for (int oo = 0; oo < 12; ++oo) { acc[oo][0]+=wq[oo]*s.x; acc[oo][1]+=wq[oo]*s.y; }
            }
            __syncthreads();
            #pragma unroll
            for (int oo = 0; oo < 12; ++oo) {
                int o = og*12+oo;
                float2 g; g.x = gelu_f(acc[oo][0]); g.y = gelu_f(acc[oo][1]);
                *(float2*)(b0 + o*130 + pp*2) = g;
            }
        }
        __syncthreads();
        for (int idx = t; idx < 2304; idx += 256) {
            int o = idx % 48, i = idx / 48;
            wl[i*48 + o] = w2[o*48 + i];
        }
        if (t < 48) bl[t] = b2[t];
        __syncthreads();
        {
            float acc[12][2];
            #pragma unroll
            for (int oo = 0; oo < 12; ++oo) { float bv = bl[og*12+oo]; acc[oo][0]=bv; acc[oo][1]=bv; }
            for (int i = 0; i < 48; ++i) {
                float2 s = *(const float2*)(b0 + i*130 + pp*2);
                const float4* wv = (const float4*)(wl + i*48 + og*12);
                float wq[12];
                *(float4*)(wq+0)=wv[0]; *(float4*)(wq+4)=wv[1]; *(float4*)(wq+8)=wv[2];
                #pragma unroll
                for (int oo = 0; oo < 12; ++oo) { acc[oo][0]+=wq[oo]*s.x; acc[oo][1]+=wq[oo]*s.y; }
            }
            #pragma unroll
            for (int oo = 0; oo < 12; ++oo) {
                int o = og*12+oo;
                size_t obase = (size_t)o*NPIXA + (size_t)y*WA + xh + pp*2;
                float2 rv = *(const float2*)(UA + obase);
                float2 r;
                r.x = gelu_f(acc[oo][0]) + rv.x;
                r.y = gelu_f(acc[oo][1]) + rv.y;
                *(float2*)(UA + obase) = r;
            }
        }
    } else {
        int b = blockIdx.x - 512;
        int c = b >> 4, yg = b & 15;
        int kx = t & 31, yr = t >> 5;
        int y = yg * 8 + yr;
        float re = 0.f, im = 0.f;
        const float2* crow = COUT + (size_t)(PA + c) * MM * MM + kx;
        const float2* tab = (const float2*)tiyB;
        #pragma unroll 8
        for (int j = 0; j < 32; ++j) {
            float2 w = crow[j * MM];
            float2 tv = tab[j * HB + y];
            re += w.x*tv.x - w.y*tv.y;
            im += w.x*tv.y + w.y*tv.x;
        }
        float2* ds = (float2*)sm;
        ds[yr*32 + kx] = make_float2(re, im);
        __syncthreads();
        int x = t & 127, rp = t >> 7;
        const float2* txb = (const float2*)tixB;
        for (int rr = rp; rr < 8; rr += 2) {
            const float2* drow = ds + rr*32;
            float a = 0.f;
            #pragma unroll
            for (int k2 = 0; k2 < 32; ++k2) {
                float2 tv = txb[k2*WB + x];
                float2 d = drow[k2];
                a += d.x*tv.x - d.y*tv.y;
            }
            SB[((size_t)c*HB + yg*8 + rr)*WB + x] = a;
        }
    }
}

// ---------------- B-branch 3x3 conv via MFMA (bf16 in, f32 acc) ----------------
__global__ __launch_bounds__(256) void k_conv3x3_mfma(
        const float* __restrict__ in, float* __restrict__ out,
        const short* __restrict__ wt, const float* __restrict__ bias,
        const float* resid) {
    __shared__ float smf[3072];            // 12288 B: bf16 tile (7776 B), then reduce buf
    short* tile = (short*)smf;
    int y  = blockIdx.x >> 3;
    int x0 = (blockIdx.x & 7) << 4;
    int tid = threadIdx.x;

    for (int idx = tid; idx < 3456; idx += 256) {   // 3 rows x 64 ic x 18 px
        int r = idx / 1152;
        int rem = idx - r*1152;
        int ic = rem / 18;
        int px = rem - ic*18;
        int gy = y - 1 + r, gx = x0 - 1 + px;
        float v = 0.f;
        if (ic < 48 && gy >= 0 && gy < HB && gx >= 0 && gx < WB)
            v = in[(size_t)ic*NPIXB + gy*WB + gx];
        tile[(r*18 + px)*72 + ic] = f2bf(v);
    }
    __syncthreads();

    int w = tid >> 6, lane = tid & 63;
    int n = lane & 15, kg = lane >> 4, m = lane & 15;
    f32x4 acc0 = {0.f,0.f,0.f,0.f}, acc1 = {0.f,0.f,0.f,0.f}, acc2 = {0.f,0.f,0.f,0.f};
    for (int s = w; s < 18; s += 4) {
        int tap = s >> 1;
        int kb = (s & 1) << 5;
        int dy = tap / 3, dx = tap - dy*3;
        bf16x8 bfrag = *(const bf16x8*)(tile + ((dy*18 + n + dx)*72 + kb + kg*8));
        const short* ap = wt + ((size_t)tap*48)*64 + kb + kg*8;
        bf16x8 a0 = *(const bf16x8*)(ap + (size_t)(m     )*64);
        bf16x8 a1 = *(const bf16x8*)(ap + (size_t)(16 + m)*64);
        bf16x8 a2 = *(const bf16x8*)(ap + (size_t)(32 + m)*64);
        acc0 = __builtin_amdgcn_mfma_f32_16x16x32_bf16(a0, bfrag, acc0, 0, 0, 0);
        acc1 = __builtin_amdgcn_mfma_f32_16x16x32_bf16(a1, bfrag, acc1, 0, 0, 0);
        acc2 = __builtin_amdgcn_mfma_f32_16x16x32_bf16(a2, bfrag, acc2, 0, 0, 0);
    }
    __syncthreads();
    float4* red = (float4*)smf;
    red[(w*3 + 0)*64 + lane] = make_float4(acc0[0], acc0[1], acc0[2], acc0[3]);
    red[(w*3 + 1)*64 + lane] = make_float4(acc1[0], acc1[1], acc1[2], acc1[3]);
    red[(w*3 + 2)*64 + lane] = make_float4(acc2[0], acc2[1], acc2[2], acc2[3]);
    __syncthreads();
    if (tid < 192) {
        int mt = tid >> 6, ln = tid & 63;
        float4 s0 = red[(0*3 + mt)*64 + ln];
        float4 s1 = red[(1*3 + mt)*64 + ln];
        float4 s2 = red[(2*3 + mt)*64 + ln];
        float4 s3 = red[(3*3 + mt)*64 + ln];
        float sum[4];
        sum[0] = s0.x + s1.x + s2.x + s3.x;
        sum[1] = s0.y + s1.y + s2.y + s3.y;
        sum[2] = s0.z + s1.z + s2.z + s3.z;
        sum[3] = s0.w + s1.w + s2.w + s3.w;
        int px = x0 + (ln & 15);
        #pragma unroll
        for (int r = 0; r < 4; ++r) {
            int oc = mt*16 + (ln >> 4)*4 + r;
            float v = sum[r] + bias[oc];
            v = gelu_f(v);
            size_t o = (size_t)oc*NPIXB + (size_t)y*WB + px;
            if (resid) v += resid[o];
            out[o] = v;
        }
    }
}

// ---------------- decoder: 48->1 both branches ----------------
__global__ __launch_bounds__(256) void k_decode(
        const float* __restrict__ UA, const float* __restrict__ UB,
        const float* dwa, const float* dba,
        const float* dwb, const float* dbb, float* outp) {
    int t = blockIdx.x*256 + threadIdx.x;
    if (t < NPIXA) {
        float acc = dba[0];
        #pragma unroll 8
        for (int p = 0; p < PA; ++p) acc += dwa[p]*UA[(size_t)p*NPIXA + t];
        outp[t] = acc;
    } else {
        int u = t - NPIXA;
        float acc = dbb[0];
        #pragma unroll 8
        for (int p = 0; p < PB; ++p) acc += dwb[p]*UB[(size_t)p*NPIXB + u];
        outp[t] = acc;
    }
}

extern "C" void kernel_launch(void* const* d_in, const int* in_sizes, int n_in,
                              void* d_out, int out_size, void* d_ws, size_t ws_size,
                              hipStream_t stream) {
    const float* u_a   = (const float*)d_in[0];
    const float* x_a   = (const float*)d_in[1];
    const float* u_b   = (const float*)d_in[2];
    const float* x_b   = (const float*)d_in[3];
    const float* enc_a_w = (const float*)d_in[4];
    const float* enc_a_b = (const float*)d_in[5];
    const float* enc_b_w = (const float*)d_in[6];
    const float* enc_b_b = (const float*)d_in[7];
    const float* dec_a_w = (const float*)d_in[8];
    const float* dec_a_b = (const float*)d_in[9];
    const float* dec_b_w = (const float*)d_in[10];
    const float* dec_b_b = (const float*)d_in[11];
    const float* c1a_w = (const float*)d_in[12];
    const float* c1a_b = (const float*)d_in[13];
    const float* c2a_w = (const float*)d_in[14];
    const float* c2a_b = (const float*)d_in[15];
    const float* c1b_w = (const float*)d_in[16];
    const float* c1b_b = (const float*)d_in[17];
    const float* c2b_w = (const float*)d_in[18];
    const float* c2b_b = (const float*)d_in[19];
    const float* A_re = (const float*)d_in[20];
    const float* A_im = (const float*)d_in[21];

    float* ws = (float*)d_ws;
    size_t off = 0;
    auto alloc = [&](size_t n) { float* p = ws + off; off += n; return p; };
    short* WT    = (short*)alloc(4*2*9*48*64/2);   // 221184 bf16 = 110592 floats
    float* TfxAT = alloc(MM*WA*2);
    float* TixAT = alloc(MM*WA*2);
    float* TfyA  = alloc(MM*HA*2);
    float* TiyA  = alloc(MM*HA*2);
    float* TfxBT = alloc(MM*WB*2);
    float* TfyB  = alloc(MM*HB*2);
    float* TixB  = alloc(MM*WB*2);
    float* TiyB  = alloc(MM*HB*2);
    float* UA = alloc((size_t)PA*NPIXA);
    float* UB = alloc((size_t)PB*NPIXB);
    float* SB = alloc((size_t)PB*NPIXB);
    float* TB = alloc((size_t)PB*NPIXB);
    float2* FA = (float2*)alloc((size_t)PA*HA*MM*2);
    float2* FB = (float2*)alloc((size_t)PB*HB*MM*2);
    float2* CIN  = (float2*)alloc((size_t)PP*MM*MM*2);
    float2* COUT = (float2*)alloc((size_t)PP*MM*MM*2);
    if (off * sizeof(float) > ws_size) return;

    k_pre<<<dim3(48 + 48*320 + 864), dim3(256), 0, stream>>>(
        TfxAT,TfyA,TiyA,TixAT,TfxBT,TfyB,TixB,TiyB,
        u_a,x_a,u_b,x_b, enc_a_w,enc_a_b,enc_b_w,enc_b_b, UA,UB,
        c1b_w, c2b_w, WT);
    for (int l = 0; l < 4; ++l) {
        k_fwd_x<<<dim3(576), dim3(256), 32768, stream>>>(UA,UB,FA,FB,TfxAT,TfxBT);
        k_fwd_y<<<dim3(384), dim3(256), 0, stream>>>(FA,FB,CIN,TfyA,TfyB);
        k_spectral<<<dim3(384), dim3(256), 0, stream>>>(
            A_re + (size_t)l*PP*PP*MM*MM, A_im + (size_t)l*PP*PP*MM*MM, CIN, COUT);
        k_inv<<<dim3(512 + 768), dim3(256), 0, stream>>>(COUT, UA, SB,
            TiyA, TiyB, TixB, TixAT,
            c1a_w + (size_t)l*PA*PA, c1a_b + (size_t)l*PA,
            c2a_w + (size_t)l*PA*PA, c2a_b + (size_t)l*PA);
        k_conv3x3_mfma<<<dim3(1024), dim3(256), 0, stream>>>(SB, TB,
            WT + (size_t)(l*2 + 0)*27648, c1b_b + (size_t)l*PB, (const float*)nullptr);
        k_conv3x3_mfma<<<dim3(1024), dim3(256), 0, stream>>>(TB, UB,
            WT + (size_t)(l*2 + 1)*27648, c2b_b + (size_t)l*PB, UB);
    }
    k_decode<<<dim3(320), dim3(256), 0, stream>>>(UA, UB,
        dec_a_w, dec_a_b, dec_b_w, dec_b_b, (float*)d_out);
}

// Round 9
// 567.718 us; speedup vs baseline: 1.5072x; 1.1424x over previous
//
#include <hip/hip_runtime.h>

#define HA 256
#define WA 256
#define HB 128
#define WB 128
#define PA 48
#define PB 48
#define PP 96
#define MM 32
#define NPIXA (HA*WA)   // 65536
#define NPIXB (HB*WB)   // 16384

typedef short bf16x8 __attribute__((ext_vector_type(8)));
typedef float f32x4 __attribute__((ext_vector_type(4)));

__device__ __forceinline__ float gelu_f(float x) {
    float z = 0.7978845608028654f * (x + 0.044715f * x * x * x);
    float e = __expf(2.0f * z);
    return x - x / (e + 1.0f);
}

__device__ __forceinline__ short f2bf(float f) {
    unsigned u = __float_as_uint(f);
    unsigned r = (u + 0x7FFFu + ((u >> 16) & 1u)) >> 16;
    return (short)r;
}

__device__ __forceinline__ unsigned pack2(float a, float b) {
    return (unsigned)(unsigned short)f2bf(a) | ((unsigned)(unsigned short)f2bf(b) << 16);
}

// ---------------- tables + encoder + weight transforms, fused ----------------
// sections: [0,48) trig tables | [48,15408) encode | [15408,16272) conv3x3 WT
//           [16272,16336) TbfA | [16336,16368) TbfB | [16368,16464) conv1x1 WcT
__global__ __launch_bounds__(256) void k_pre(
        float* tfyA, float* tiyA, float* tixAT,
        float* tfyB, float* tixB, float* tiyB,
        const float* u_a, const float* x_a, const float* u_b, const float* x_b,
        const float* wa, const float* ba, const float* wb, const float* bb,
        float* UA, float* UB,
        const float* c1b_w, const float* c2b_w, short* WT,
        short* TbfA, short* TbfB,
        const float* c1a_w, const float* c2a_w, short* WcT) {
    const float TWO_PI = 6.28318530717958647692f;
    int bid = blockIdx.x;
    if (bid < 48) {
        int t = bid * 256 + threadIdx.x;
        if (t < MM * WA) {
            int k = t / WA, x = t - k * WA;
            int m = (k * x) & (WA - 1);
            float ang = TWO_PI * (float)m / (float)WA;
            float s, c; __sincosf(ang, &s, &c);
            tixAT[(x*MM + k)*2]   = c;
            tixAT[(x*MM + k)*2+1] = s;
            int ky = k - 16;
            int my = (ky * x) & (HA - 1);
            float angy = TWO_PI * (float)my / (float)HA;
            float sy, cy; __sincosf(angy, &sy, &cy);
            tfyA[2*t] = cy; tfyA[2*t+1] = -sy;
            tiyA[2*t] = cy; tiyA[2*t+1] = sy;
        } else if (t < MM * WA + MM * WB) {
            int t2 = t - MM * WA;
            int k = t2 / WB, x = t2 - k * WB;
            int m = (k * x) & (WB - 1);
            float ang = TWO_PI * (float)m / (float)WB;
            float s, c; __sincosf(ang, &s, &c);
            float wgt = (k == 0) ? 1.0f : 2.0f;
            tixB[2*t2] = wgt * c; tixB[2*t2+1] = wgt * s;
            int ky = k - 16;
            int my = (ky * x) & (HB - 1);
            float angy = TWO_PI * (float)my / (float)HB;
            float sy, cy; __sincosf(angy, &sy, &cy);
            tfyB[2*t2] = cy; tfyB[2*t2+1] = -sy;
            tiyB[2*t2] = cy; tiyB[2*t2+1] = sy;
        }
    } else if (bid < 48 + 48*320) {
        int eb = bid - 48;
        int o = eb / 320;
        int chunk = eb - o * 320;
        if (chunk < 256) {
            int pix = chunk * 256 + threadIdx.x;
            UA[(size_t)o*NPIXA + pix] = wa[o*3+0]*x_a[pix] + wa[o*3+1]*x_a[NPIXA+pix]
                                      + wa[o*3+2]*u_a[pix] + ba[o];
        } else {
            int pix = (chunk - 256) * 256 + threadIdx.x;
            UB[(size_t)o*NPIXB + pix] = wb[o*3+0]*x_b[pix] + wb[o*3+1]*x_b[NPIXB+pix]
                                      + wb[o*3+2]*u_b[pix] + bb[o];
        }
    } else if (bid < 16272) {
        int g = (bid - (48 + 48*320)) * 256 + threadIdx.x;
        if (g < 4*2*9*48*64) {
            int l  = g / 55296;
            int r1 = g - l*55296;
            int cv = r1 / 27648;
            int r2 = r1 - cv*27648;
            int tap = r2 / 3072;
            int r3 = r2 - tap*3072;
            int oc = r3 >> 6;
            int ic = r3 & 63;
            const float* src = cv ? c2b_w : c1b_w;
            float v = 0.f;
            if (ic < 48) v = src[(((size_t)l*48 + oc)*48 + ic)*9 + tap];
            WT[g] = f2bf(v);
        }
    } else if (bid < 16336) {
        // TbfA[col][x]: forward-x twiddles bf16, col=2k+comp, scaled 1/(HA*WA)
        int g = (bid - 16272) * 256 + threadIdx.x;   // < 16384
        int col = g >> 8, x = g & 255;
        int k = col >> 1, comp = col & 1;
        int m = (k * x) & (WA - 1);
        float ang = TWO_PI * (float)m / (float)WA;
        float s, c; __sincosf(ang, &s, &c);
        float sc = 1.0f / (float)(HA * WA);
        TbfA[col*WA + x] = f2bf(comp ? -s * sc : c * sc);
    } else if (bid < 16368) {
        int g = (bid - 16336) * 256 + threadIdx.x;   // < 8192
        int col = g >> 7, x = g & 127;
        int k = col >> 1, comp = col & 1;
        int m = (k * x) & (WB - 1);
        float ang = TWO_PI * (float)m / (float)WB;
        float s, c; __sincosf(ang, &s, &c);
        float sc = 1.0f / (float)(HB * WB);
        TbfB[col*WB + x] = f2bf(comp ? -s * sc : c * sc);
    } else {
        // conv1x1 A-branch weights, transposed [l][cv][oc][ic64] bf16
        int g = (bid - 16368) * 256 + threadIdx.x;   // < 24576
        int l  = g / 6144;
        int r  = g - l*6144;
        int cv = r / 3072;
        int r2 = r - cv*3072;
        int oc = r2 >> 6;
        int ic = r2 & 63;
        const float* src = cv ? c2a_w : c1a_w;
        float v = 0.f;
        if (ic < 48) v = src[((size_t)l*48 + oc)*48 + ic];
        WcT[g] = f2bf(v);
    }
}

// ---------------- forward DFT along x via MFMA ----------------
// block = 32 rows; F[row][col] = sum_x U[row][x] * T[x][col], col = 2kx+comp.
__global__ __launch_bounds__(256) void k_fwd_x(
        const float* __restrict__ UA, const float* __restrict__ UB,
        float2* __restrict__ FA, float2* __restrict__ FB,
        const short* __restrict__ TbfA, const short* __restrict__ TbfB) {
    extern __shared__ short lsb[];   // [32][N+8] bf16
    int bid = blockIdx.x;
    const float* U; float2* F; const short* T; int N;
    if (bid < 384) { U = UA; F = FA; T = TbfA; N = WA; }
    else { bid -= 384; U = UB; F = FB; T = TbfB; N = WB; }
    int r0 = bid * 32;
    int NP = N + 8;
    int nq = N >> 2;
    const float4* src = (const float4*)(U + (size_t)r0 * N);
    for (int i = threadIdx.x; i < 32*nq; i += 256) {
        int r = i / nq, q = i - r*nq;
        float4 v = src[i];
        *(uint2*)(lsb + r*NP + q*4) = make_uint2(pack2(v.x, v.y), pack2(v.z, v.w));
    }
    __syncthreads();
    int wv = threadIdx.x >> 6, lane = threadIdx.x & 63;
    int n = lane & 15, kg = lane >> 4;
    int col = wv*16 + n;
    const short* Tc = T + (size_t)col * N;
    f32x4 acc0 = {0.f,0.f,0.f,0.f}, acc1 = {0.f,0.f,0.f,0.f};
    for (int ks = 0; ks < (N >> 5); ++ks) {
        bf16x8 bfrag = *(const bf16x8*)(Tc + ks*32 + kg*8);
        bf16x8 a0 = *(const bf16x8*)(lsb + (size_t)n*NP + ks*32 + kg*8);
        bf16x8 a1 = *(const bf16x8*)(lsb + (size_t)(16+n)*NP + ks*32 + kg*8);
        acc0 = __builtin_amdgcn_mfma_f32_16x16x32_bf16(a0, bfrag, acc0, 0, 0, 0);
        acc1 = __builtin_amdgcn_mfma_f32_16x16x32_bf16(a1, bfrag, acc1, 0, 0, 0);
    }
    int kxg = col >> 1, comp = col & 1;
    #pragma unroll
    for (int r = 0; r < 4; ++r) {
        int row = kg*4 + r;
        ((float*)(F + (size_t)(r0+row)*MM + kxg))[comp]    = acc0[r];
        ((float*)(F + (size_t)(r0+16+row)*MM + kxg))[comp] = acc1[r];
    }
}

// ---------------- forward DFT along y ----------------
__global__ __launch_bounds__(256) void k_fwd_y(
        const float2* __restrict__ FA, const float2* __restrict__ FB, float2* CIN,
        const float* __restrict__ tfyA, const float* __restrict__ tfyB) {
    int bid = blockIdx.x;
    const float2* F; const float* tab; int Ny, pbase;
    if (bid < PA*4) { F = FA; tab = tfyA; Ny = HA; pbase = 0; }
    else { bid -= PA*4; F = FB; tab = tfyB; Ny = HB; pbase = PA; }
    int c = bid >> 2;
    int j = (bid & 3) * 8 + (threadIdx.x >> 5);
    int kx = threadIdx.x & 31;
    float re = 0.f, im = 0.f;
    const float2* fr = F + (size_t)c * Ny * MM + kx;
    const float2* tj = (const float2*)tab + j * Ny;
    #pragma unroll 4
    for (int y = 0; y < Ny; ++y) {
        float2 f = fr[y * MM];
        float2 t = tj[y];
        re += f.x*t.x - f.y*t.y;
        im += f.x*t.y + f.y*t.x;
    }
    CIN[((pbase + c)*MM + j)*MM + kx] = make_float2(re, im);
}

// ---------------- spectral channel mix ----------------
__global__ __launch_bounds__(256) void k_spectral(
        const float* __restrict__ Wre, const float* __restrict__ Wim,
        const float2* __restrict__ CIN, float2* __restrict__ COUT) {
    int t = blockIdx.x * 256 + threadIdx.x;
    int p = t >> 10;
    int mode = t & 1023;
    const float* wr = Wre + (size_t)p * PP * 1024 + mode;
    const float* wi = Wim + (size_t)p * PP * 1024 + mode;
    float re = 0.f, im = 0.f;
    #pragma unroll 8
    for (int q = 0; q < PP; ++q) {
        float a = wr[(size_t)q << 10];
        float b = wi[(size_t)q << 10];
        float2 cv = CIN[(q << 10) + mode];
        re += a*cv.x - b*cv.y;
        im += a*cv.y + b*cv.x;
    }
    COUT[t] = make_float2(re, im);
}

// ---------------- fused inverse ----------------
// A (blocks 0..511): inv_y -> Dw -> inv_x (reg) -> sl bf16 [px][ic72]
//   -> conv1 MFMA + gelu -> b0 bf16 -> conv2 MFMA + gelu + resid -> UA
// B (512..1279): inv_y + inv_x -> SB.
__global__ __launch_bounds__(256) void k_inv(
        const float2* __restrict__ COUT, float* __restrict__ UA,
        float* __restrict__ SB,
        const float* __restrict__ tiyA, const float* __restrict__ tiyB,
        const float* __restrict__ tixB, const float* __restrict__ tixAT,
        const short* __restrict__ W1T, const short* __restrict__ W2T,
        const float* __restrict__ b1v, const float* __restrict__ b2v) {
    __shared__ __attribute__((aligned(16))) char smc[37888];
    int t = threadIdx.x;
    if (blockIdx.x < 512) {
        float2* Dw   = (float2*)smc;                 // [48][33] (12672 B)
        short* b0bf  = (short*)smc;                  // [128][72] (18432 B, overlays Dw)
        short* slbf  = (short*)(smc + 18432);        // [128][72]
        float2* tl   = (float2*)(smc + 36864);       // 32
        float* bl1   = (float*)(smc + 37120);        // 48
        float* bl2   = (float*)(smc + 37312);        // 48
        int y  = blockIdx.x >> 1;
        int xh = (blockIdx.x & 1) << 7;
        if (t < 32) tl[t] = ((const float2*)tiyA)[t*HA + y];
        if (t >= 64 && t < 112) bl1[t-64] = b1v[t-64];
        if (t >= 128 && t < 176) bl2[t-128] = b2v[t-128];
        __syncthreads();
        // phase 0: Dw(c,kx) = sum_j COUT(c,j,kx)*Tiy(j,y), c2r weight folded
        {
            int kx = t & 31, c0 = t >> 5;
            float re[6] = {0,0,0,0,0,0}, im[6] = {0,0,0,0,0,0};
            for (int j = 0; j < 32; ++j) {
                float2 ty = tl[j];
                #pragma unroll
                for (int k = 0; k < 6; ++k) {
                    float2 w = COUT[((c0 + 8*k)*32 + j)*32 + kx];
                    re[k] += w.x*ty.x - w.y*ty.y;
                    im[k] += w.x*ty.y + w.y*ty.x;
                }
            }
            float wgt = (kx == 0) ? 1.0f : 2.0f;
            #pragma unroll
            for (int k = 0; k < 6; ++k)
                Dw[(c0 + 8*k)*33 + kx] = make_float2(re[k]*wgt, im[k]*wgt);
        }
        __syncthreads();
        // phase 2: inv-x DFT, lane = channel; write sl bf16 [px][ic]
        {
            int w = t >> 6, lane = t & 63;
            float dwr[32], dwi[32];
            #pragma unroll
            for (int k = 0; k < 32; ++k) { dwr[k] = 0.f; dwi[k] = 0.f; }
            if (lane < 48) {
                const float2* dr = Dw + lane*33;
                #pragma unroll
                for (int k = 0; k < 32; ++k) { float2 v = dr[k]; dwr[k] = v.x; dwi[k] = v.y; }
            }
            int xbase = xh + w*32;
            for (int j = 0; j < 32; ++j) {
                const float4* tw4 = (const float4*)(tixAT + (size_t)(xbase + j) * (MM*2));
                float acc = 0.f;
                #pragma unroll
                for (int k4 = 0; k4 < 16; ++k4) {
                    float4 tv = tw4[k4];
                    acc += dwr[2*k4]*tv.x   - dwi[2*k4]*tv.y;
                    acc += dwr[2*k4+1]*tv.z - dwi[2*k4+1]*tv.w;
                }
                slbf[(w*32 + j)*72 + lane] = f2bf(acc);   // lanes>=48 write 0 (pad)
            }
        }
        __syncthreads();
        int wv = t >> 6, lane = t & 63;
        int n = lane & 15, kg = lane >> 4;
        // phase 3: conv1 MFMA (M=48 oc, N=32 px/wave, K=64) + gelu -> b0bf
        {
            bf16x8 aw[3][2];
            #pragma unroll
            for (int mt = 0; mt < 3; ++mt)
                #pragma unroll
                for (int ks = 0; ks < 2; ++ks)
                    aw[mt][ks] = *(const bf16x8*)(W1T + (size_t)(mt*16 + n)*64 + ks*32 + kg*8);
            f32x4 acc[2][3];
            #pragma unroll
            for (int nt = 0; nt < 2; ++nt)
                #pragma unroll
                for (int mt = 0; mt < 3; ++mt)
                    acc[nt][mt] = (f32x4){0.f,0.f,0.f,0.f};
            #pragma unroll
            for (int nt = 0; nt < 2; ++nt) {
                int ntile = wv*2 + nt;
                #pragma unroll
                for (int ks = 0; ks < 2; ++ks) {
                    bf16x8 bfrag = *(const bf16x8*)(slbf + (size_t)(ntile*16 + n)*72 + ks*32 + kg*8);
                    #pragma unroll
                    for (int mt = 0; mt < 3; ++mt)
                        acc[nt][mt] = __builtin_amdgcn_mfma_f32_16x16x32_bf16(aw[mt][ks], bfrag, acc[nt][mt], 0, 0, 0);
                }
            }
            #pragma unroll
            for (int nt = 0; nt < 2; ++nt) {
                int px = (wv*2 + nt)*16 + n;
                #pragma unroll
                for (int mt = 0; mt < 3; ++mt) {
                    int oc0 = mt*16 + kg*4;
                    float g0 = gelu_f(acc[nt][mt][0] + bl1[oc0+0]);
                    float g1 = gelu_f(acc[nt][mt][1] + bl1[oc0+1]);
                    float g2 = gelu_f(acc[nt][mt][2] + bl1[oc0+2]);
                    float g3 = gelu_f(acc[nt][mt][3] + bl1[oc0+3]);
                    *(uint2*)(b0bf + (size_t)px*72 + oc0) = make_uint2(pack2(g0,g1), pack2(g2,g3));
                }
            }
            for (int idx = t; idx < 2048; idx += 256)
                b0bf[(idx >> 4)*72 + 48 + (idx & 15)] = 0;
        }
        __syncthreads();
        // phase 4: conv2 MFMA + gelu + residual -> UA
        {
            bf16x8 aw[3][2];
            #pragma unroll
            for (int mt = 0; mt < 3; ++mt)
                #pragma unroll
                for (int ks = 0; ks < 2; ++ks)
                    aw[mt][ks] = *(const bf16x8*)(W2T + (size_t)(mt*16 + n)*64 + ks*32 + kg*8);
            f32x4 acc[2][3];
            #pragma unroll
            for (int nt = 0; nt < 2; ++nt)
                #pragma unroll
                for (int mt = 0; mt < 3; ++mt)
                    acc[nt][mt] = (f32x4){0.f,0.f,0.f,0.f};
            #pragma unroll
            for (int nt = 0; nt < 2; ++nt) {
                int ntile = wv*2 + nt;
                #pragma unroll
                for (int ks = 0; ks < 2; ++ks) {
                    bf16x8 bfrag = *(const bf16x8*)(b0bf + (size_t)(ntile*16 + n)*72 + ks*32 + kg*8);
                    #pragma unroll
                    for (int mt = 0; mt < 3; ++mt)
                        acc[nt][mt] = __builtin_amdgcn_mfma_f32_16x16x32_bf16(aw[mt][ks], bfrag, acc[nt][mt], 0, 0, 0);
                }
            }
            #pragma unroll
            for (int nt = 0; nt < 2; ++nt) {
                int px = (wv*2 + nt)*16 + n;
                #pragma unroll
                for (int mt = 0; mt < 3; ++mt) {
                    int oc0 = mt*16 + kg*4;
                    #pragma unroll
                    for (int r = 0; r < 4; ++r) {
                        int oc = oc0 + r;
                        size_t o = (size_t)oc*NPIXA + (size_t)y*WA + xh + px;
                        UA[o] = gelu_f(acc[nt][mt][r] + bl2[oc]) + UA[o];
                    }
                }
            }
        }
    } else {
        int b = blockIdx.x - 512;
        int c = b >> 4, yg = b & 15;
        int kx = t & 31, yr = t >> 5;
        int y = yg * 8 + yr;
        float re = 0.f, im = 0.f;
        const float2* crow = COUT + (size_t)(PA + c) * MM * MM + kx;
        const float2* tab = (const float2*)tiyB;
        #pragma unroll 8
        for (int j = 0; j < 32; ++j) {
            float2 w = crow[j * MM];
            float2 tv = tab[j * HB + y];
            re += w.x*tv.x - w.y*tv.y;
            im += w.x*tv.y + w.y*tv.x;
        }
        float2* ds = (float2*)smc;
        ds[yr*32 + kx] = make_float2(re, im);
        __syncthreads();
        int x = t & 127, rp = t >> 7;
        const float2* txb = (const float2*)tixB;
        for (int rr = rp; rr < 8; rr += 2) {
            const float2* drow = ds + rr*32;
            float a = 0.f;
            #pragma unroll
            for (int k2 = 0; k2 < 32; ++k2) {
                float2 tv = txb[k2*WB + x];
                float2 d = drow[k2];
                a += d.x*tv.x - d.y*tv.y;
            }
            SB[((size_t)c*HB + yg*8 + rr)*WB + x] = a;
        }
    }
}

// ---------------- B-branch 3x3 conv via MFMA (unchanged from R8) ----------------
__global__ __launch_bounds__(256) void k_conv3x3_mfma(
        const float* __restrict__ in, float* __restrict__ out,
        const short* __restrict__ wt, const float* __restrict__ bias,
        const float* resid) {
    __shared__ float smf[3072];
    short* tile = (short*)smf;
    int y  = blockIdx.x >> 3;
    int x0 = (blockIdx.x & 7) << 4;
    int tid = threadIdx.x;

    for (int idx = tid; idx < 3456; idx += 256) {
        int r = idx / 1152;
        int rem = idx - r*1152;
        int ic = rem / 18;
        int px = rem - ic*18;
        int gy = y - 1 + r, gx = x0 - 1 + px;
        float v = 0.f;
        if (ic < 48 && gy >= 0 && gy < HB && gx >= 0 && gx < WB)
            v = in[(size_t)ic*NPIXB + gy*WB + gx];
        tile[(r*18 + px)*72 + ic] = f2bf(v);
    }
    __syncthreads();

    int w = tid >> 6, lane = tid & 63;
    int n = lane & 15, kg = lane >> 4, m = lane & 15;
    f32x4 acc0 = {0.f,0.f,0.f,0.f}, acc1 = {0.f,0.f,0.f,0.f}, acc2 = {0.f,0.f,0.f,0.f};
    for (int s = w; s < 18; s += 4) {
        int tap = s >> 1;
        int kb = (s & 1) << 5;
        int dy = tap / 3, dx = tap - dy*3;
        bf16x8 bfrag = *(const bf16x8*)(tile + ((dy*18 + n + dx)*72 + kb + kg*8));
        const short* ap = wt + ((size_t)tap*48)*64 + kb + kg*8;
        bf16x8 a0 = *(const bf16x8*)(ap + (size_t)(m     )*64);
        bf16x8 a1 = *(const bf16x8*)(ap + (size_t)(16 + m)*64);
        bf16x8 a2 = *(const bf16x8*)(ap + (size_t)(32 + m)*64);
        acc0 = __builtin_amdgcn_mfma_f32_16x16x32_bf16(a0, bfrag, acc0, 0, 0, 0);
        acc1 = __builtin_amdgcn_mfma_f32_16x16x32_bf16(a1, bfrag, acc1, 0, 0, 0);
        acc2 = __builtin_amdgcn_mfma_f32_16x16x32_bf16(a2, bfrag, acc2, 0, 0, 0);
    }
    __syncthreads();
    float4* red = (float4*)smf;
    red[(w*3 + 0)*64 + lane] = make_float4(acc0[0], acc0[1], acc0[2], acc0[3]);
    red[(w*3 + 1)*64 + lane] = make_float4(acc1[0], acc1[1], acc1[2], acc1[3]);
    red[(w*3 + 2)*64 + lane] = make_float4(acc2[0], acc2[1], acc2[2], acc2[3]);
    __syncthreads();
    if (tid < 192) {
        int mt = tid >> 6, ln = tid & 63;
        float4 s0 = red[(0*3 + mt)*64 + ln];
        float4 s1 = red[(1*3 + mt)*64 + ln];
        float4 s2 = red[(2*3 + mt)*64 + ln];
        float4 s3 = red[(3*3 + mt)*64 + ln];
        float sum[4];
        sum[0] = s0.x + s1.x + s2.x + s3.x;
        sum[1] = s0.y + s1.y + s2.y + s3.y;
        sum[2] = s0.z + s1.z + s2.z + s3.z;
        sum[3] = s0.w + s1.w + s2.w + s3.w;
        int px = x0 + (ln & 15);
        #pragma unroll
        for (int r = 0; r < 4; ++r) {
            int oc = mt*16 + (ln >> 4)*4 + r;
            float v = sum[r] + bias[oc];
            v = gelu_f(v);
            size_t o = (size_t)oc*NPIXB + (size_t)y*WB + px;
            if (resid) v += resid[o];
            out[o] = v;
        }
    }
}

// ---------------- decoder: 48->1 both branches ----------------
__global__ __launch_bounds__(256) void k_decode(
        const float* __restrict__ UA, const float* __restrict__ UB,
        const float* dwa, const float* dba,
        const float* dwb, const float* dbb, float* outp) {
    int t = blockIdx.x*256 + threadIdx.x;
    if (t < NPIXA) {
        float acc = dba[0];
        #pragma unroll 8
        for (int p = 0; p < PA; ++p) acc += dwa[p]*UA[(size_t)p*NPIXA + t];
        outp[t] = acc;
    } else {
        int u = t - NPIXA;
        float acc = dbb[0];
        #pragma unroll 8
        for (int p = 0; p < PB; ++p) acc += dwb[p]*UB[(size_t)p*NPIXB + u];
        outp[t] = acc;
    }
}

extern "C" void kernel_launch(void* const* d_in, const int* in_sizes, int n_in,
                              void* d_out, int out_size, void* d_ws, size_t ws_size,
                              hipStream_t stream) {
    const float* u_a   = (const float*)d_in[0];
    const float* x_a   = (const float*)d_in[1];
    const float* u_b   = (const float*)d_in[2];
    const float* x_b   = (const float*)d_in[3];
    const float* enc_a_w = (const float*)d_in[4];
    const float* enc_a_b = (const float*)d_in[5];
    const float* enc_b_w = (const float*)d_in[6];
    const float* enc_b_b = (const float*)d_in[7];
    const float* dec_a_w = (const float*)d_in[8];
    const float* dec_a_b = (const float*)d_in[9];
    const float* dec_b_w = (const float*)d_in[10];
    const float* dec_b_b = (const float*)d_in[11];
    const float* c1a_w = (const float*)d_in[12];
    const float* c1a_b = (const float*)d_in[13];
    const float* c2a_w = (const float*)d_in[14];
    const float* c2a_b = (const float*)d_in[15];
    const float* c1b_w = (const float*)d_in[16];
    const float* c1b_b = (const float*)d_in[17];
    const float* c2b_w = (const float*)d_in[18];
    const float* c2b_b = (const float*)d_in[19];
    const float* A_re = (const float*)d_in[20];
    const float* A_im = (const float*)d_in[21];

    float* ws = (float*)d_ws;
    size_t off = 0;
    auto alloc = [&](size_t n) { float* p = ws + off; off += n; return p; };
    short* WT    = (short*)alloc(4*2*9*48*64/2);   // conv3x3 weights bf16
    short* TbfA  = (short*)alloc(64*WA/2);         // fwd-x twiddles bf16 [col][x]
    short* TbfB  = (short*)alloc(64*WB/2);
    short* WcT   = (short*)alloc(4*2*48*64/2);     // conv1x1 A weights bf16
    float* TixAT = alloc(MM*WA*2);
    float* TfyA  = alloc(MM*HA*2);
    float* TiyA  = alloc(MM*HA*2);
    float* TfyB  = alloc(MM*HB*2);
    float* TixB  = alloc(MM*WB*2);
    float* TiyB  = alloc(MM*HB*2);
    float* UA = alloc((size_t)PA*NPIXA);
    float* UB = alloc((size_t)PB*NPIXB);
    float* SB = alloc((size_t)PB*NPIXB);
    float* TB = alloc((size_t)PB*NPIXB);
    float2* FA = (float2*)alloc((size_t)PA*HA*MM*2);
    float2* FB = (float2*)alloc((size_t)PB*HB*MM*2);
    float2* CIN  = (float2*)alloc((size_t)PP*MM*MM*2);
    float2* COUT = (float2*)alloc((size_t)PP*MM*MM*2);
    if (off * sizeof(float) > ws_size) return;

    k_pre<<<dim3(16464), dim3(256), 0, stream>>>(
        TfyA, TiyA, TixAT, TfyB, TixB, TiyB,
        u_a,x_a,u_b,x_b, enc_a_w,enc_a_b,enc_b_w,enc_b_b, UA,UB,
        c1b_w, c2b_w, WT, TbfA, TbfB, c1a_w, c2a_w, WcT);
    for (int l = 0; l < 4; ++l) {
        k_fwd_x<<<dim3(576), dim3(256), 32*(WA+8)*2, stream>>>(UA,UB,FA,FB,TbfA,TbfB);
        k_fwd_y<<<dim3(384), dim3(256), 0, stream>>>(FA,FB,CIN,TfyA,TfyB);
        k_spectral<<<dim3(384), dim3(256), 0, stream>>>(
            A_re + (size_t)l*PP*PP*MM*MM, A_im + (size_t)l*PP*PP*MM*MM, CIN, COUT);
        k_inv<<<dim3(512 + 768), dim3(256), 0, stream>>>(COUT, UA, SB,
            TiyA, TiyB, TixB, TixAT,
            WcT + (size_t)(l*2 + 0)*3072, WcT + (size_t)(l*2 + 1)*3072,
            c1a_b + (size_t)l*PA, c2a_b + (size_t)l*PA);
        k_conv3x3_mfma<<<dim3(1024), dim3(256), 0, stream>>>(SB, TB,
            WT + (size_t)(l*2 + 0)*27648, c1b_b + (size_t)l*PB, (const float*)nullptr);
        k_conv3x3_mfma<<<dim3(1024), dim3(256), 0, stream>>>(TB, UB,
            WT + (size_t)(l*2 + 1)*27648, c2b_b + (size_t)l*PB, UB);
    }
    k_decode<<<dim3(320), dim3(256), 0, stream>>>(UA, UB,
        dec_a_w, dec_a_b, dec_b_w, dec_b_b, (float*)d_out);
}

// Round 10
// 413.011 us; speedup vs baseline: 2.0717x; 1.3746x over previous
//
#include <hip/hip_runtime.h>

#define HA 256
#define WA 256
#define HB 128
#define WB 128
#define PA 48
#define PB 48
#define PP 96
#define MM 32
#define NPIXA (HA*WA)   // 65536
#define NPIXB (HB*WB)   // 16384

typedef short bf16x8 __attribute__((ext_vector_type(8)));
typedef float f32x4 __attribute__((ext_vector_type(4)));

__device__ __forceinline__ float gelu_f(float x) {
    float z = 0.7978845608028654f * (x + 0.044715f * x * x * x);
    float e = __expf(2.0f * z);
    return x - x / (e + 1.0f);
}

__device__ __forceinline__ short f2bf(float f) {
    unsigned u = __float_as_uint(f);
    unsigned r = (u + 0x7FFFu + ((u >> 16) & 1u)) >> 16;
    return (short)r;
}

__device__ __forceinline__ unsigned pack2(float a, float b) {
    return (unsigned)(unsigned short)f2bf(a) | ((unsigned)(unsigned short)f2bf(b) << 16);
}

// ---------------- tables + encoder + weight transforms, fused ----------------
// [0,48) trig | [48,15408) encode | [15408,16272) WT | [16272,16336) TbfA
// [16336,16368) TbfB | [16368,16464) WcT | [16464,16592) Ty2A | [16592,16656) Ty2B
__global__ __launch_bounds__(256) void k_pre(
        float* tiyA, float* tixB, float* tiyB, short* T2x,
        const float* u_a, const float* x_a, const float* u_b, const float* x_b,
        const float* wa, const float* ba, const float* wb, const float* bb,
        float* UA, float* UB,
        const float* c1b_w, const float* c2b_w, short* WT,
        short* TbfA, short* TbfB,
        const float* c1a_w, const float* c2a_w, short* WcT,
        short* Ty2A, short* Ty2B) {
    const float TWO_PI = 6.28318530717958647692f;
    int bid = blockIdx.x;
    if (bid < 48) {
        int t = bid * 256 + threadIdx.x;
        if (t < MM * WA) {
            int k = t / WA, x = t - k * WA;
            // T2x[x][2k]=wgt*cos, [2k+1]=-wgt*sin  (inv-x, e^{+i}, c2r wgt folded)
            int m = (k * x) & (WA - 1);
            float ang = TWO_PI * (float)m / (float)WA;
            float s, c; __sincosf(ang, &s, &c);
            float wgt = (k == 0) ? 1.0f : 2.0f;
            T2x[x*64 + 2*k]   = f2bf(wgt * c);
            T2x[x*64 + 2*k+1] = f2bf(-wgt * s);
            int ky = k - 16;
            int my = (ky * x) & (HA - 1);
            float angy = TWO_PI * (float)my / (float)HA;
            float sy, cy; __sincosf(angy, &sy, &cy);
            tiyA[2*t] = cy; tiyA[2*t+1] = sy;
        } else if (t < MM * WA + MM * WB) {
            int t2 = t - MM * WA;
            int k = t2 / WB, x = t2 - k * WB;
            int m = (k * x) & (WB - 1);
            float ang = TWO_PI * (float)m / (float)WB;
            float s, c; __sincosf(ang, &s, &c);
            float wgt = (k == 0) ? 1.0f : 2.0f;
            tixB[2*t2] = wgt * c; tixB[2*t2+1] = wgt * s;
            int ky = k - 16;
            int my = (ky * x) & (HB - 1);
            float angy = TWO_PI * (float)my / (float)HB;
            float sy, cy; __sincosf(angy, &sy, &cy);
            tiyB[2*t2] = cy; tiyB[2*t2+1] = sy;
        }
    } else if (bid < 15408) {
        int eb = bid - 48;
        int o = eb / 320;
        int chunk = eb - o * 320;
        if (chunk < 256) {
            int pix = chunk * 256 + threadIdx.x;
            UA[(size_t)o*NPIXA + pix] = wa[o*3+0]*x_a[pix] + wa[o*3+1]*x_a[NPIXA+pix]
                                      + wa[o*3+2]*u_a[pix] + ba[o];
        } else {
            int pix = (chunk - 256) * 256 + threadIdx.x;
            UB[(size_t)o*NPIXB + pix] = wb[o*3+0]*x_b[pix] + wb[o*3+1]*x_b[NPIXB+pix]
                                      + wb[o*3+2]*u_b[pix] + bb[o];
        }
    } else if (bid < 16272) {
        int g = (bid - 15408) * 256 + threadIdx.x;
        if (g < 4*2*9*48*64) {
            int l  = g / 55296;
            int r1 = g - l*55296;
            int cv = r1 / 27648;
            int r2 = r1 - cv*27648;
            int tap = r2 / 3072;
            int r3 = r2 - tap*3072;
            int oc = r3 >> 6;
            int ic = r3 & 63;
            const float* src = cv ? c2b_w : c1b_w;
            float v = 0.f;
            if (ic < 48) v = src[(((size_t)l*48 + oc)*48 + ic)*9 + tap];
            WT[g] = f2bf(v);
        }
    } else if (bid < 16336) {
        int g = (bid - 16272) * 256 + threadIdx.x;   // 16384
        int col = g >> 8, x = g & 255;
        int k = col >> 1, comp = col & 1;
        int m = (k * x) & (WA - 1);
        float ang = TWO_PI * (float)m / (float)WA;
        float s, c; __sincosf(ang, &s, &c);
        float sc = 1.0f / (float)(HA * WA);
        TbfA[col*WA + x] = f2bf(comp ? -s * sc : c * sc);
    } else if (bid < 16368) {
        int g = (bid - 16336) * 256 + threadIdx.x;   // 8192
        int col = g >> 7, x = g & 127;
        int k = col >> 1, comp = col & 1;
        int m = (k * x) & (WB - 1);
        float ang = TWO_PI * (float)m / (float)WB;
        float s, c; __sincosf(ang, &s, &c);
        float sc = 1.0f / (float)(HB * WB);
        TbfB[col*WB + x] = f2bf(comp ? -s * sc : c * sc);
    } else if (bid < 16464) {
        int g = (bid - 16368) * 256 + threadIdx.x;   // 24576
        int l  = g / 6144;
        int r  = g - l*6144;
        int cv = r / 3072;
        int r2 = r - cv*3072;
        int oc = r2 >> 6;
        int ic = r2 & 63;
        const float* src = cv ? c2a_w : c1a_w;
        float v = 0.f;
        if (ic < 48) v = src[((size_t)l*48 + oc)*48 + ic];
        WcT[g] = f2bf(v);
    } else if (bid < 16592) {
        // Ty2A[2j+comp][2y+comp2]: fwd-y twiddles, e^{-i}: [cy, sy; -sy, cy]
        int g = (bid - 16464) * 256 + threadIdx.x;   // 32768
        int row = g >> 9, col = g & 511;
        int j = row >> 1, comp = row & 1;
        int y = col >> 1, comp2 = col & 1;
        int my = ((j - 16) * y) & (HA - 1);
        float ang = TWO_PI * (float)my / (float)HA;
        float sy, cy; __sincosf(ang, &sy, &cy);
        float v = comp == 0 ? (comp2 == 0 ? cy : sy) : (comp2 == 0 ? -sy : cy);
        Ty2A[g] = f2bf(v);
    } else {
        int g = (bid - 16592) * 256 + threadIdx.x;   // 16384
        int row = g >> 8, col = g & 255;
        int j = row >> 1, comp = row & 1;
        int y = col >> 1, comp2 = col & 1;
        int my = ((j - 16) * y) & (HB - 1);
        float ang = TWO_PI * (float)my / (float)HB;
        float sy, cy; __sincosf(ang, &sy, &cy);
        float v = comp == 0 ? (comp2 == 0 ? cy : sy) : (comp2 == 0 ? -sy : cy);
        Ty2B[g] = f2bf(v);
    }
}

// ---------------- forward DFT along x via MFMA; output FT bf16 [c][kx][2y] ----------------
__global__ __launch_bounds__(256) void k_fwd_x(
        const float* __restrict__ UA, const float* __restrict__ UB,
        short* __restrict__ FTA, short* __restrict__ FTB,
        const short* __restrict__ TbfA, const short* __restrict__ TbfB) {
    extern __shared__ short lsb[];   // [32][N+8] bf16
    int bid = blockIdx.x;
    const float* U; short* FT; const short* T; int N, ymask, cshift;
    if (bid < 384) { U = UA; FT = FTA; T = TbfA; N = WA; ymask = 255; cshift = 8; }
    else { bid -= 384; U = UB; FT = FTB; T = TbfB; N = WB; ymask = 127; cshift = 7; }
    int r0 = bid * 32;
    int c = r0 >> cshift;
    int ybase = r0 & ymask;
    int NP = N + 8;
    int nq = N >> 2;
    const float4* src = (const float4*)(U + (size_t)r0 * N);
    for (int i = threadIdx.x; i < 32*nq; i += 256) {
        int r = i / nq, q = i - r*nq;
        float4 v = src[i];
        *(uint2*)(lsb + r*NP + q*4) = make_uint2(pack2(v.x, v.y), pack2(v.z, v.w));
    }
    __syncthreads();
    int wv = threadIdx.x >> 6, lane = threadIdx.x & 63;
    int n = lane & 15, kg = lane >> 4;
    int col = wv*16 + n;
    const short* Tc = T + (size_t)col * N;
    f32x4 acc0 = {0.f,0.f,0.f,0.f}, acc1 = {0.f,0.f,0.f,0.f};
    for (int ks = 0; ks < (N >> 5); ++ks) {
        bf16x8 bfrag = *(const bf16x8*)(Tc + ks*32 + kg*8);
        bf16x8 a0 = *(const bf16x8*)(lsb + (size_t)n*NP + ks*32 + kg*8);
        bf16x8 a1 = *(const bf16x8*)(lsb + (size_t)(16+n)*NP + ks*32 + kg*8);
        acc0 = __builtin_amdgcn_mfma_f32_16x16x32_bf16(a0, bfrag, acc0, 0, 0, 0);
        acc1 = __builtin_amdgcn_mfma_f32_16x16x32_bf16(a1, bfrag, acc1, 0, 0, 0);
    }
    int kxg = col >> 1, comp = col & 1;
    int K2 = 2 * (ymask + 1);
    short* base = FT + ((size_t)c*32 + kxg) * K2 + comp;
    #pragma unroll
    for (int r = 0; r < 4; ++r) {
        int y0 = ybase + kg*4 + r;
        base[2*y0]        = f2bf(acc0[r]);
        base[2*(y0 + 16)] = f2bf(acc1[r]);
    }
}

// ---------------- forward DFT along y via MFMA (2-way K-split partials) ----------------
__global__ __launch_bounds__(256) void k_fwd_y(
        const short* __restrict__ FTA, const short* __restrict__ FTB,
        const short* __restrict__ Ty2A, const short* __restrict__ Ty2B,
        float* __restrict__ CINa, float* __restrict__ CINb) {
    __shared__ short lsb[32*264];
    int bid = blockIdx.x;
    const short* FT; const short* Ty; int K2, NP, pbase, c, h;
    if (bid < 96) { c = bid>>1; h = bid&1; FT = FTA; Ty = Ty2A; K2 = 512; NP = 264; pbase = 0; }
    else { int b2 = bid - 96; c = b2>>1; h = b2&1; FT = FTB; Ty = Ty2B; K2 = 256; NP = 136; pbase = 48; }
    float* CO = (h == 0) ? CINa : CINb;
    int hlen = K2 >> 1;
    int nchunk = hlen >> 3;
    for (int idx = threadIdx.x; idx < 32*nchunk; idx += 256) {
        int row = idx / nchunk, q = idx - row*nchunk;
        *(uint4*)(lsb + row*NP + q*8) =
            *(const uint4*)(FT + ((size_t)c*32 + row)*K2 + h*hlen + q*8);
    }
    __syncthreads();
    int w = threadIdx.x >> 6, lane = threadIdx.x & 63;
    int n = lane & 15, kg = lane >> 4;
    f32x4 acc0 = {0.f,0.f,0.f,0.f}, acc1 = {0.f,0.f,0.f,0.f};
    int nks = hlen >> 5;
    for (int ks = 0; ks < nks; ++ks) {
        bf16x8 af = *(const bf16x8*)(Ty + (size_t)(w*16 + n)*K2 + h*hlen + ks*32 + kg*8);
        bf16x8 b0 = *(const bf16x8*)(lsb + n*NP + ks*32 + kg*8);
        bf16x8 b1 = *(const bf16x8*)(lsb + (16+n)*NP + ks*32 + kg*8);
        acc0 = __builtin_amdgcn_mfma_f32_16x16x32_bf16(af, b0, acc0, 0, 0, 0);
        acc1 = __builtin_amdgcn_mfma_f32_16x16x32_bf16(af, b1, acc1, 0, 0, 0);
    }
    #pragma unroll
    for (int r = 0; r < 4; ++r) {
        int row = w*16 + kg*4 + r;
        int j = row >> 1, comp = row & 1;
        size_t base = (((size_t)(pbase + c))*32 + j)*32;
        CO[(base + n)*2 + comp]      = acc0[r];
        CO[(base + 16 + n)*2 + comp] = acc1[r];
    }
}

// ---------------- spectral channel mix: 2-way q-split, sums CIN partials ----------------
__global__ __launch_bounds__(256) void k_spectral(
        const float* __restrict__ Wre, const float* __restrict__ Wim,
        const float2* __restrict__ CINa, const float2* __restrict__ CINb,
        float2* __restrict__ PART) {
    int part = blockIdx.y;
    int t = blockIdx.x * 256 + threadIdx.x;
    int p = t >> 10;
    int mode = t & 1023;
    int q0 = part * 48;
    const float* wr = Wre + ((size_t)p * PP + q0) * 1024 + mode;
    const float* wi = Wim + ((size_t)p * PP + q0) * 1024 + mode;
    float re = 0.f, im = 0.f;
    #pragma unroll 8
    for (int q = 0; q < 48; ++q) {
        float a = wr[(size_t)q << 10];
        float b = wi[(size_t)q << 10];
        float2 ca = CINa[(q0 + q)*1024 + mode];
        float2 cb = CINb[(q0 + q)*1024 + mode];
        float cr = ca.x + cb.x, ci = ca.y + cb.y;
        re += a*cr - b*ci;
        im += a*ci + b*cr;
    }
    PART[((size_t)part * PP + p)*1024 + mode] = make_float2(re, im);
}

__global__ __launch_bounds__(256) void k_cred(
        const float2* __restrict__ PART, float2* __restrict__ COUT) {
    int t = blockIdx.x * 256 + threadIdx.x;   // 98304
    float2 a = PART[t];
    float2 b = PART[PP*1024 + t];
    COUT[t] = make_float2(a.x + b.x, a.y + b.y);
}

// ---------------- fused inverse ----------------
// A (0..511): inv_y (scalar) -> Dw bf16 -> inv_x MFMA -> sl bf16 -> conv1 MFMA
//   -> b0 bf16 -> conv2 MFMA + resid -> UA.   B (512..1279): inv_y + inv_x -> SB.
__global__ __launch_bounds__(256) void k_inv(
        const float2* __restrict__ COUT, float* __restrict__ UA,
        float* __restrict__ SB,
        const float* __restrict__ tiyA, const float* __restrict__ tiyB,
        const float* __restrict__ tixB, const short* __restrict__ T2x,
        const short* __restrict__ W1T, const short* __restrict__ W2T,
        const float* __restrict__ b1v, const float* __restrict__ b2v) {
    __shared__ __attribute__((aligned(16))) char smc[37888];
    int t = threadIdx.x;
    if (blockIdx.x < 512) {
        short* dwbf  = (short*)smc;                  // [48][72] (6912 B, in b0 region)
        short* b0bf  = (short*)smc;                  // [128][72] (18432 B)
        short* slbf  = (short*)(smc + 18432);        // [128][72]
        float2* tl   = (float2*)(smc + 36864);
        float* bl1   = (float*)(smc + 37120);
        float* bl2   = (float*)(smc + 37312);
        int y  = blockIdx.x >> 1;
        int xh = (blockIdx.x & 1) << 7;
        if (t < 32) tl[t] = ((const float2*)tiyA)[t*HA + y];
        if (t >= 64 && t < 112) bl1[t-64] = b1v[t-64];
        if (t >= 128 && t < 176) bl2[t-128] = b2v[t-128];
        __syncthreads();
        // phase 0: Dw(c,kx) = sum_j COUT(c,j,kx)*Tiy(j,y)  (raw, wgt in T2x)
        {
            int kx = t & 31, c0 = t >> 5;
            float re[6] = {0,0,0,0,0,0}, im[6] = {0,0,0,0,0,0};
            for (int j = 0; j < 32; ++j) {
                float2 ty = tl[j];
                #pragma unroll
                for (int k = 0; k < 6; ++k) {
                    float2 w = COUT[((c0 + 8*k)*32 + j)*32 + kx];
                    re[k] += w.x*ty.x - w.y*ty.y;
                    im[k] += w.x*ty.y + w.y*ty.x;
                }
            }
            #pragma unroll
            for (int k = 0; k < 6; ++k)
                *(unsigned*)(dwbf + (c0 + 8*k)*72 + 2*kx) = pack2(re[k], im[k]);
        }
        __syncthreads();
        int wv = t >> 6, lane = t & 63;
        int n = lane & 15, kg = lane >> 4;
        // phase 2: inv-x via MFMA: S[c][x] = Dw . T2x, M=48, N=128, K=64
        {
            f32x4 acc[2][3];
            #pragma unroll
            for (int i = 0; i < 2; ++i)
                #pragma unroll
                for (int mt = 0; mt < 3; ++mt)
                    acc[i][mt] = (f32x4){0.f,0.f,0.f,0.f};
            #pragma unroll
            for (int ks = 0; ks < 2; ++ks) {
                bf16x8 bfr[2];
                #pragma unroll
                for (int i = 0; i < 2; ++i) {
                    int px = xh + (wv*2 + i)*16 + n;
                    bfr[i] = *(const bf16x8*)(T2x + (size_t)px*64 + ks*32 + kg*8);
                }
                #pragma unroll
                for (int mt = 0; mt < 3; ++mt) {
                    bf16x8 af = *(const bf16x8*)(dwbf + (mt*16 + n)*72 + ks*32 + kg*8);
                    #pragma unroll
                    for (int i = 0; i < 2; ++i)
                        acc[i][mt] = __builtin_amdgcn_mfma_f32_16x16x32_bf16(af, bfr[i], acc[i][mt], 0, 0, 0);
                }
            }
            #pragma unroll
            for (int i = 0; i < 2; ++i) {
                int xl = (wv*2 + i)*16 + n;
                #pragma unroll
                for (int mt = 0; mt < 3; ++mt)
                    #pragma unroll
                    for (int r = 0; r < 4; ++r)
                        slbf[xl*72 + mt*16 + kg*4 + r] = f2bf(acc[i][mt][r]);
            }
            for (int idx = t; idx < 2048; idx += 256)
                slbf[(idx >> 4)*72 + 48 + (idx & 15)] = 0;
        }
        __syncthreads();
        // phase 3: conv1 MFMA + gelu -> b0bf
        {
            bf16x8 aw[3][2];
            #pragma unroll
            for (int mt = 0; mt < 3; ++mt)
                #pragma unroll
                for (int ks = 0; ks < 2; ++ks)
                    aw[mt][ks] = *(const bf16x8*)(W1T + (size_t)(mt*16 + n)*64 + ks*32 + kg*8);
            f32x4 acc[2][3];
            #pragma unroll
            for (int nt = 0; nt < 2; ++nt)
                #pragma unroll
                for (int mt = 0; mt < 3; ++mt)
                    acc[nt][mt] = (f32x4){0.f,0.f,0.f,0.f};
            #pragma unroll
            for (int nt = 0; nt < 2; ++nt) {
                int ntile = wv*2 + nt;
                #pragma unroll
                for (int ks = 0; ks < 2; ++ks) {
                    bf16x8 bfrag = *(const bf16x8*)(slbf + (size_t)(ntile*16 + n)*72 + ks*32 + kg*8);
                    #pragma unroll
                    for (int mt = 0; mt < 3; ++mt)
                        acc[nt][mt] = __builtin_amdgcn_mfma_f32_16x16x32_bf16(aw[mt][ks], bfrag, acc[nt][mt], 0, 0, 0);
                }
            }
            #pragma unroll
            for (int nt = 0; nt < 2; ++nt) {
                int px = (wv*2 + nt)*16 + n;
                #pragma unroll
                for (int mt = 0; mt < 3; ++mt) {
                    int oc0 = mt*16 + kg*4;
                    float g0 = gelu_f(acc[nt][mt][0] + bl1[oc0+0]);
                    float g1 = gelu_f(acc[nt][mt][1] + bl1[oc0+1]);
                    float g2 = gelu_f(acc[nt][mt][2] + bl1[oc0+2]);
                    float g3 = gelu_f(acc[nt][mt][3] + bl1[oc0+3]);
                    *(uint2*)(b0bf + (size_t)px*72 + oc0) = make_uint2(pack2(g0,g1), pack2(g2,g3));
                }
            }
            for (int idx = t; idx < 2048; idx += 256)
                b0bf[(idx >> 4)*72 + 48 + (idx & 15)] = 0;
        }
        __syncthreads();
        // phase 4: conv2 MFMA + gelu + residual -> UA
        {
            bf16x8 aw[3][2];
            #pragma unroll
            for (int mt = 0; mt < 3; ++mt)
                #pragma unroll
                for (int ks = 0; ks < 2; ++ks)
                    aw[mt][ks] = *(const bf16x8*)(W2T + (size_t)(mt*16 + n)*64 + ks*32 + kg*8);
            f32x4 acc[2][3];
            #pragma unroll
            for (int nt = 0; nt < 2; ++nt)
                #pragma unroll
                for (int mt = 0; mt < 3; ++mt)
                    acc[nt][mt] = (f32x4){0.f,0.f,0.f,0.f};
            #pragma unroll
            for (int nt = 0; nt < 2; ++nt) {
                int ntile = wv*2 + nt;
                #pragma unroll
                for (int ks = 0; ks < 2; ++ks) {
                    bf16x8 bfrag = *(const bf16x8*)(b0bf + (size_t)(ntile*16 + n)*72 + ks*32 + kg*8);
                    #pragma unroll
                    for (int mt = 0; mt < 3; ++mt)
                        acc[nt][mt] = __builtin_amdgcn_mfma_f32_16x16x32_bf16(aw[mt][ks], bfrag, acc[nt][mt], 0, 0, 0);
                }
            }
            #pragma unroll
            for (int nt = 0; nt < 2; ++nt) {
                int px = (wv*2 + nt)*16 + n;
                #pragma unroll
                for (int mt = 0; mt < 3; ++mt) {
                    int oc0 = mt*16 + kg*4;
                    #pragma unroll
                    for (int r = 0; r < 4; ++r) {
                        int oc = oc0 + r;
                        size_t o = (size_t)oc*NPIXA + (size_t)y*WA + xh + px;
                        UA[o] = gelu_f(acc[nt][mt][r] + bl2[oc]) + UA[o];
                    }
                }
            }
        }
    } else {
        int b = blockIdx.x - 512;
        int c = b >> 4, yg = b & 15;
        int kx = t & 31, yr = t >> 5;
        int y = yg * 8 + yr;
        float re = 0.f, im = 0.f;
        const float2* crow = COUT + (size_t)(PA + c) * MM * MM + kx;
        const float2* tab = (const float2*)tiyB;
        #pragma unroll 8
        for (int j = 0; j < 32; ++j) {
            float2 w = crow[j * MM];
            float2 tv = tab[j * HB + y];
            re += w.x*tv.x - w.y*tv.y;
            im += w.x*tv.y + w.y*tv.x;
        }
        float2* ds = (float2*)smc;
        ds[yr*32 + kx] = make_float2(re, im);
        __syncthreads();
        int x = t & 127, rp = t >> 7;
        const float2* txb = (const float2*)tixB;
        for (int rr = rp; rr < 8; rr += 2) {
            const float2* drow = ds + rr*32;
            float a = 0.f;
            #pragma unroll
            for (int k2 = 0; k2 < 32; ++k2) {
                float2 tv = txb[k2*WB + x];
                float2 d = drow[k2];
                a += d.x*tv.x - d.y*tv.y;
            }
            SB[((size_t)c*HB + yg*8 + rr)*WB + x] = a;
        }
    }
}

// ---------------- B-branch 3x3 conv via MFMA ----------------
__global__ __launch_bounds__(256) void k_conv3x3_mfma(
        const float* __restrict__ in, float* __restrict__ out,
        const short* __restrict__ wt, const float* __restrict__ bias,
        const float* resid) {
    __shared__ float smf[3072];
    short* tile = (short*)smf;
    int y  = blockIdx.x >> 3;
    int x0 = (blockIdx.x & 7) << 4;
    int tid = threadIdx.x;

    for (int idx = tid; idx < 3456; idx += 256) {
        int r = idx / 1152;
        int rem = idx - r*1152;
        int ic = rem / 18;
        int px = rem - ic*18;
        int gy = y - 1 + r, gx = x0 - 1 + px;
        float v = 0.f;
        if (ic < 48 && gy >= 0 && gy < HB && gx >= 0 && gx < WB)
            v = in[(size_t)ic*NPIXB + gy*WB + gx];
        tile[(r*18 + px)*72 + ic] = f2bf(v);
    }
    __syncthreads();

    int w = tid >> 6, lane = tid & 63;
    int n = lane & 15, kg = lane >> 4, m = lane & 15;
    f32x4 acc0 = {0.f,0.f,0.f,0.f}, acc1 = {0.f,0.f,0.f,0.f}, acc2 = {0.f,0.f,0.f,0.f};
    for (int s = w; s < 18; s += 4) {
        int tap = s >> 1;
        int kb = (s & 1) << 5;
        int dy = tap / 3, dx = tap - dy*3;
        bf16x8 bfrag = *(const bf16x8*)(tile + ((dy*18 + n + dx)*72 + kb + kg*8));
        const short* ap = wt + ((size_t)tap*48)*64 + kb + kg*8;
        bf16x8 a0 = *(const bf16x8*)(ap + (size_t)(m     )*64);
        bf16x8 a1 = *(const bf16x8*)(ap + (size_t)(16 + m)*64);
        bf16x8 a2 = *(const bf16x8*)(ap + (size_t)(32 + m)*64);
        acc0 = __builtin_amdgcn_mfma_f32_16x16x32_bf16(a0, bfrag, acc0, 0, 0, 0);
        acc1 = __builtin_amdgcn_mfma_f32_16x16x32_bf16(a1, bfrag, acc1, 0, 0, 0);
        acc2 = __builtin_amdgcn_mfma_f32_16x16x32_bf16(a2, bfrag, acc2, 0, 0, 0);
    }
    __syncthreads();
    float4* red = (float4*)smf;
    red[(w*3 + 0)*64 + lane] = make_float4(acc0[0], acc0[1], acc0[2], acc0[3]);
    red[(w*3 + 1)*64 + lane] = make_float4(acc1[0], acc1[1], acc1[2], acc1[3]);
    red[(w*3 + 2)*64 + lane] = make_float4(acc2[0], acc2[1], acc2[2], acc2[3]);
    __syncthreads();
    if (tid < 192) {
        int mt = tid >> 6, ln = tid & 63;
        float4 s0 = red[(0*3 + mt)*64 + ln];
        float4 s1 = red[(1*3 + mt)*64 + ln];
        float4 s2 = red[(2*3 + mt)*64 + ln];
        float4 s3 = red[(3*3 + mt)*64 + ln];
        float sum[4];
        sum[0] = s0.x + s1.x + s2.x + s3.x;
        sum[1] = s0.y + s1.y + s2.y + s3.y;
        sum[2] = s0.z + s1.z + s2.z + s3.z;
        sum[3] = s0.w + s1.w + s2.w + s3.w;
        int px = x0 + (ln & 15);
        #pragma unroll
        for (int r = 0; r < 4; ++r) {
            int oc = mt*16 + (ln >> 4)*4 + r;
            float v = sum[r] + bias[oc];
            v = gelu_f(v);
            size_t o = (size_t)oc*NPIXB + (size_t)y*WB + px;
            if (resid) v += resid[o];
            out[o] = v;
        }
    }
}

// ---------------- decoder ----------------
__global__ __launch_bounds__(256) void k_decode(
        const float* __restrict__ UA, const float* __restrict__ UB,
        const float* dwa, const float* dba,
        const float* dwb, const float* dbb, float* outp) {
    int t = blockIdx.x*256 + threadIdx.x;
    if (t < NPIXA) {
        float acc = dba[0];
        #pragma unroll 8
        for (int p = 0; p < PA; ++p) acc += dwa[p]*UA[(size_t)p*NPIXA + t];
        outp[t] = acc;
    } else {
        int u = t - NPIXA;
        float acc = dbb[0];
        #pragma unroll 8
        for (int p = 0; p < PB; ++p) acc += dwb[p]*UB[(size_t)p*NPIXB + u];
        outp[t] = acc;
    }
}

extern "C" void kernel_launch(void* const* d_in, const int* in_sizes, int n_in,
                              void* d_out, int out_size, void* d_ws, size_t ws_size,
                              hipStream_t stream) {
    const float* u_a   = (const float*)d_in[0];
    const float* x_a   = (const float*)d_in[1];
    const float* u_b   = (const float*)d_in[2];
    const float* x_b   = (const float*)d_in[3];
    const float* enc_a_w = (const float*)d_in[4];
    const float* enc_a_b = (const float*)d_in[5];
    const float* enc_b_w = (const float*)d_in[6];
    const float* enc_b_b = (const float*)d_in[7];
    const float* dec_a_w = (const float*)d_in[8];
    const float* dec_a_b = (const float*)d_in[9];
    const float* dec_b_w = (const float*)d_in[10];
    const float* dec_b_b = (const float*)d_in[11];
    const float* c1a_w = (const float*)d_in[12];
    const float* c1a_b = (const float*)d_in[13];
    const float* c2a_w = (const float*)d_in[14];
    const float* c2a_b = (const float*)d_in[15];
    const float* c1b_w = (const float*)d_in[16];
    const float* c1b_b = (const float*)d_in[17];
    const float* c2b_w = (const float*)d_in[18];
    const float* c2b_b = (const float*)d_in[19];
    const float* A_re = (const float*)d_in[20];
    const float* A_im = (const float*)d_in[21];

    float* ws = (float*)d_ws;
    size_t off = 0;
    auto alloc = [&](size_t n) { float* p = ws + off; off += n; return p; };
    short* WT    = (short*)alloc(4*2*9*48*64/2);
    short* TbfA  = (short*)alloc(64*WA/2);
    short* TbfB  = (short*)alloc(64*WB/2);
    short* WcT   = (short*)alloc(4*2*48*64/2);
    short* T2x   = (short*)alloc(WA*64/2);
    short* Ty2A  = (short*)alloc(64*512/2);
    short* Ty2B  = (short*)alloc(64*256/2);
    float* TiyA  = alloc(MM*HA*2);
    float* TixB  = alloc(MM*WB*2);
    float* TiyB  = alloc(MM*HB*2);
    float* UA = alloc((size_t)PA*NPIXA);
    float* UB = alloc((size_t)PB*NPIXB);
    float* SB = alloc((size_t)PB*NPIXB);
    float* TB = alloc((size_t)PB*NPIXB);
    short* FTA = (short*)alloc((size_t)PA*MM*512/2);
    short* FTB = (short*)alloc((size_t)PB*MM*256/2);
    float* CINa = alloc((size_t)PP*MM*MM*2);
    float* CINb = alloc((size_t)PP*MM*MM*2);
    float2* PART = (float2*)alloc((size_t)2*PP*MM*MM*2);
    float2* COUT = (float2*)alloc((size_t)PP*MM*MM*2);
    if (off * sizeof(float) > ws_size) return;

    k_pre<<<dim3(16656), dim3(256), 0, stream>>>(
        TiyA, TixB, TiyB, T2x,
        u_a,x_a,u_b,x_b, enc_a_w,enc_a_b,enc_b_w,enc_b_b, UA,UB,
        c1b_w, c2b_w, WT, TbfA, TbfB, c1a_w, c2a_w, WcT, Ty2A, Ty2B);
    for (int l = 0; l < 4; ++l) {
        k_fwd_x<<<dim3(576), dim3(256), 32*(WA+8)*2, stream>>>(UA,UB,FTA,FTB,TbfA,TbfB);
        k_fwd_y<<<dim3(192), dim3(256), 0, stream>>>(FTA,FTB,Ty2A,Ty2B,CINa,CINb);
        k_spectral<<<dim3(384,2), dim3(256), 0, stream>>>(
            A_re + (size_t)l*PP*PP*MM*MM, A_im + (size_t)l*PP*PP*MM*MM,
            (const float2*)CINa, (const float2*)CINb, PART);
        k_cred<<<dim3(384), dim3(256), 0, stream>>>((const float2*)PART, COUT);
        k_inv<<<dim3(512 + 768), dim3(256), 0, stream>>>((const float2*)COUT, UA, SB,
            TiyA, TiyB, TixB, T2x,
            WcT + (size_t)(l*2 + 0)*3072, WcT + (size_t)(l*2 + 1)*3072,
            c1a_b + (size_t)l*PA, c2a_b + (size_t)l*PA);
        k_conv3x3_mfma<<<dim3(1024), dim3(256), 0, stream>>>(SB, TB,
            WT + (size_t)(l*2 + 0)*27648, c1b_b + (size_t)l*PB, (const float*)nullptr);
        k_conv3x3_mfma<<<dim3(1024), dim3(256), 0, stream>>>(TB, UB,
            WT + (size_t)(l*2 + 1)*27648, c2b_b + (size_t)l*PB, UB);
    }
    k_decode<<<dim3(320), dim3(256), 0, stream>>>(UA, UB,
        dec_a_w, dec_a_b, dec_b_w, dec_b_b, (float*)d_out);
}

// Round 11
// 411.493 us; speedup vs baseline: 2.0794x; 1.0037x over previous
//
#include <hip/hip_runtime.h>

#define HA 256
#define WA 256
#define HB 128
#define WB 128
#define PA 48
#define PB 48
#define PP 96
#define MM 32
#define NPIXA (HA*WA)   // 65536
#define NPIXB (HB*WB)   // 16384

typedef short bf16x8 __attribute__((ext_vector_type(8)));
typedef float f32x4 __attribute__((ext_vector_type(4)));

__device__ __forceinline__ float gelu_f(float x) {
    float z = 0.7978845608028654f * (x + 0.044715f * x * x * x);
    float e = __expf(2.0f * z);
    return x - x / (e + 1.0f);
}

__device__ __forceinline__ short f2bf(float f) {
    unsigned u = __float_as_uint(f);
    unsigned r = (u + 0x7FFFu + ((u >> 16) & 1u)) >> 16;
    return (short)r;
}

__device__ __forceinline__ unsigned pack2(float a, float b) {
    return (unsigned)(unsigned short)f2bf(a) | ((unsigned)(unsigned short)f2bf(b) << 16);
}

// ---------------- tables + encoder + weight transforms, fused ----------------
__global__ __launch_bounds__(256) void k_pre(
        float* tiyA, float* tixB, float* tiyB, short* T2x,
        const float* u_a, const float* x_a, const float* u_b, const float* x_b,
        const float* wa, const float* ba, const float* wb, const float* bb,
        float* UA, float* UB,
        const float* c1b_w, const float* c2b_w, short* WT,
        short* TbfA, short* TbfB,
        const float* c1a_w, const float* c2a_w, short* WcT,
        short* Ty2A, short* Ty2B) {
    const float TWO_PI = 6.28318530717958647692f;
    int bid = blockIdx.x;
    if (bid < 48) {
        int t = bid * 256 + threadIdx.x;
        if (t < MM * WA) {
            int k = t / WA, x = t - k * WA;
            int m = (k * x) & (WA - 1);
            float ang = TWO_PI * (float)m / (float)WA;
            float s, c; __sincosf(ang, &s, &c);
            float wgt = (k == 0) ? 1.0f : 2.0f;
            T2x[x*64 + 2*k]   = f2bf(wgt * c);
            T2x[x*64 + 2*k+1] = f2bf(-wgt * s);
            int ky = k - 16;
            int my = (ky * x) & (HA - 1);
            float angy = TWO_PI * (float)my / (float)HA;
            float sy, cy; __sincosf(angy, &sy, &cy);
            tiyA[2*t] = cy; tiyA[2*t+1] = sy;
        } else if (t < MM * WA + MM * WB) {
            int t2 = t - MM * WA;
            int k = t2 / WB, x = t2 - k * WB;
            int m = (k * x) & (WB - 1);
            float ang = TWO_PI * (float)m / (float)WB;
            float s, c; __sincosf(ang, &s, &c);
            float wgt = (k == 0) ? 1.0f : 2.0f;
            tixB[2*t2] = wgt * c; tixB[2*t2+1] = wgt * s;
            int ky = k - 16;
            int my = (ky * x) & (HB - 1);
            float angy = TWO_PI * (float)my / (float)HB;
            float sy, cy; __sincosf(angy, &sy, &cy);
            tiyB[2*t2] = cy; tiyB[2*t2+1] = sy;
        }
    } else if (bid < 15408) {
        int eb = bid - 48;
        int o = eb / 320;
        int chunk = eb - o * 320;
        if (chunk < 256) {
            int pix = chunk * 256 + threadIdx.x;
            UA[(size_t)o*NPIXA + pix] = wa[o*3+0]*x_a[pix] + wa[o*3+1]*x_a[NPIXA+pix]
                                      + wa[o*3+2]*u_a[pix] + ba[o];
        } else {
            int pix = (chunk - 256) * 256 + threadIdx.x;
            UB[(size_t)o*NPIXB + pix] = wb[o*3+0]*x_b[pix] + wb[o*3+1]*x_b[NPIXB+pix]
                                      + wb[o*3+2]*u_b[pix] + bb[o];
        }
    } else if (bid < 16272) {
        int g = (bid - 15408) * 256 + threadIdx.x;
        if (g < 4*2*9*48*64) {
            int l  = g / 55296;
            int r1 = g - l*55296;
            int cv = r1 / 27648;
            int r2 = r1 - cv*27648;
            int tap = r2 / 3072;
            int r3 = r2 - tap*3072;
            int oc = r3 >> 6;
            int ic = r3 & 63;
            const float* src = cv ? c2b_w : c1b_w;
            float v = 0.f;
            if (ic < 48) v = src[(((size_t)l*48 + oc)*48 + ic)*9 + tap];
            WT[g] = f2bf(v);
        }
    } else if (bid < 16336) {
        int g = (bid - 16272) * 256 + threadIdx.x;   // 16384
        int col = g >> 8, x = g & 255;
        int k = col >> 1, comp = col & 1;
        int m = (k * x) & (WA - 1);
        float ang = TWO_PI * (float)m / (float)WA;
        float s, c; __sincosf(ang, &s, &c);
        float sc = 1.0f / (float)(HA * WA);
        TbfA[col*WA + x] = f2bf(comp ? -s * sc : c * sc);
    } else if (bid < 16368) {
        int g = (bid - 16336) * 256 + threadIdx.x;   // 8192
        int col = g >> 7, x = g & 127;
        int k = col >> 1, comp = col & 1;
        int m = (k * x) & (WB - 1);
        float ang = TWO_PI * (float)m / (float)WB;
        float s, c; __sincosf(ang, &s, &c);
        float sc = 1.0f / (float)(HB * WB);
        TbfB[col*WB + x] = f2bf(comp ? -s * sc : c * sc);
    } else if (bid < 16464) {
        int g = (bid - 16368) * 256 + threadIdx.x;   // 24576
        int l  = g / 6144;
        int r  = g - l*6144;
        int cv = r / 3072;
        int r2 = r - cv*3072;
        int oc = r2 >> 6;
        int ic = r2 & 63;
        const float* src = cv ? c2a_w : c1a_w;
        float v = 0.f;
        if (ic < 48) v = src[((size_t)l*48 + oc)*48 + ic];
        WcT[g] = f2bf(v);
    } else if (bid < 16592) {
        int g = (bid - 16464) * 256 + threadIdx.x;   // 32768
        int row = g >> 9, col = g & 511;
        int j = row >> 1, comp = row & 1;
        int y = col >> 1, comp2 = col & 1;
        int my = ((j - 16) * y) & (HA - 1);
        float ang = TWO_PI * (float)my / (float)HA;
        float sy, cy; __sincosf(ang, &sy, &cy);
        float v = comp == 0 ? (comp2 == 0 ? cy : sy) : (comp2 == 0 ? -sy : cy);
        Ty2A[g] = f2bf(v);
    } else {
        int g = (bid - 16592) * 256 + threadIdx.x;   // 16384
        int row = g >> 8, col = g & 255;
        int j = row >> 1, comp = row & 1;
        int y = col >> 1, comp2 = col & 1;
        int my = ((j - 16) * y) & (HB - 1);
        float ang = TWO_PI * (float)my / (float)HB;
        float sy, cy; __sincosf(ang, &sy, &cy);
        float v = comp == 0 ? (comp2 == 0 ? cy : sy) : (comp2 == 0 ? -sy : cy);
        Ty2B[g] = f2bf(v);
    }
}

// ---------------- forward DFT along x via MFMA; output FT bf16 [c][kx][2y] ----------------
__global__ __launch_bounds__(256) void k_fwd_x(
        const float* __restrict__ UA, const float* __restrict__ UB,
        short* __restrict__ FTA, short* __restrict__ FTB,
        const short* __restrict__ TbfA, const short* __restrict__ TbfB) {
    extern __shared__ short lsb[];   // [32][N+8] bf16
    int bid = blockIdx.x;
    const float* U; short* FT; const short* T; int N, ymask, cshift;
    if (bid < 384) { U = UA; FT = FTA; T = TbfA; N = WA; ymask = 255; cshift = 8; }
    else { bid -= 384; U = UB; FT = FTB; T = TbfB; N = WB; ymask = 127; cshift = 7; }
    int r0 = bid * 32;
    int c = r0 >> cshift;
    int ybase = r0 & ymask;
    int NP = N + 8;
    int nq = N >> 2;
    const float4* src = (const float4*)(U + (size_t)r0 * N);
    for (int i = threadIdx.x; i < 32*nq; i += 256) {
        int r = i / nq, q = i - r*nq;
        float4 v = src[i];
        *(uint2*)(lsb + r*NP + q*4) = make_uint2(pack2(v.x, v.y), pack2(v.z, v.w));
    }
    __syncthreads();
    int wv = threadIdx.x >> 6, lane = threadIdx.x & 63;
    int n = lane & 15, kg = lane >> 4;
    int col = wv*16 + n;
    const short* Tc = T + (size_t)col * N;
    f32x4 acc0 = {0.f,0.f,0.f,0.f}, acc1 = {0.f,0.f,0.f,0.f};
    for (int ks = 0; ks < (N >> 5); ++ks) {
        bf16x8 bfrag = *(const bf16x8*)(Tc + ks*32 + kg*8);
        bf16x8 a0 = *(const bf16x8*)(lsb + (size_t)n*NP + ks*32 + kg*8);
        bf16x8 a1 = *(const bf16x8*)(lsb + (size_t)(16+n)*NP + ks*32 + kg*8);
        acc0 = __builtin_amdgcn_mfma_f32_16x16x32_bf16(a0, bfrag, acc0, 0, 0, 0);
        acc1 = __builtin_amdgcn_mfma_f32_16x16x32_bf16(a1, bfrag, acc1, 0, 0, 0);
    }
    int kxg = col >> 1, comp = col & 1;
    int K2 = 2 * (ymask + 1);
    short* base = FT + ((size_t)c*32 + kxg) * K2 + comp;
    #pragma unroll
    for (int r = 0; r < 4; ++r) {
        int y0 = ybase + kg*4 + r;
        base[2*y0]        = f2bf(acc0[r]);
        base[2*(y0 + 16)] = f2bf(acc1[r]);
    }
}

// ---------------- forward DFT along y via MFMA (2-way K-split partials) ----------------
__global__ __launch_bounds__(256) void k_fwd_y(
        const short* __restrict__ FTA, const short* __restrict__ FTB,
        const short* __restrict__ Ty2A, const short* __restrict__ Ty2B,
        float* __restrict__ CINa, float* __restrict__ CINb) {
    __shared__ short lsb[32*264];
    int bid = blockIdx.x;
    const short* FT; const short* Ty; int K2, NP, pbase, c, h;
    if (bid < 96) { c = bid>>1; h = bid&1; FT = FTA; Ty = Ty2A; K2 = 512; NP = 264; pbase = 0; }
    else { int b2 = bid - 96; c = b2>>1; h = b2&1; FT = FTB; Ty = Ty2B; K2 = 256; NP = 136; pbase = 48; }
    float* CO = (h == 0) ? CINa : CINb;
    int hlen = K2 >> 1;
    int nchunk = hlen >> 3;
    for (int idx = threadIdx.x; idx < 32*nchunk; idx += 256) {
        int row = idx / nchunk, q = idx - row*nchunk;
        *(uint4*)(lsb + row*NP + q*8) =
            *(const uint4*)(FT + ((size_t)c*32 + row)*K2 + h*hlen + q*8);
    }
    __syncthreads();
    int w = threadIdx.x >> 6, lane = threadIdx.x & 63;
    int n = lane & 15, kg = lane >> 4;
    f32x4 acc0 = {0.f,0.f,0.f,0.f}, acc1 = {0.f,0.f,0.f,0.f};
    int nks = hlen >> 5;
    for (int ks = 0; ks < nks; ++ks) {
        bf16x8 af = *(const bf16x8*)(Ty + (size_t)(w*16 + n)*K2 + h*hlen + ks*32 + kg*8);
        bf16x8 b0 = *(const bf16x8*)(lsb + n*NP + ks*32 + kg*8);
        bf16x8 b1 = *(const bf16x8*)(lsb + (16+n)*NP + ks*32 + kg*8);
        acc0 = __builtin_amdgcn_mfma_f32_16x16x32_bf16(af, b0, acc0, 0, 0, 0);
        acc1 = __builtin_amdgcn_mfma_f32_16x16x32_bf16(af, b1, acc1, 0, 0, 0);
    }
    #pragma unroll
    for (int r = 0; r < 4; ++r) {
        int row = w*16 + kg*4 + r;
        int j = row >> 1, comp = row & 1;
        size_t base = (((size_t)(pbase + c))*32 + j)*32;
        CO[(base + n)*2 + comp]      = acc0[r];
        CO[(base + 16 + n)*2 + comp] = acc1[r];
    }
}

// ---------------- spectral mix: float4, 8-way q-split, 4 modes/thread ----------------
__global__ __launch_bounds__(256) void k_spectral(
        const float* __restrict__ Wre, const float* __restrict__ Wim,
        const float* __restrict__ CINa, const float* __restrict__ CINb,
        float2* __restrict__ PART) {
    int part = blockIdx.y;                       // 0..7, 12 q each
    int t = blockIdx.x * 256 + threadIdx.x;      // 24576 = 96 p x 256 mode-quads
    int p = t >> 8;
    int m4 = (t & 255) << 2;
    int q0 = part * 12;
    const float4* wr = (const float4*)(Wre + ((size_t)p * PP + q0) * 1024 + m4);
    const float4* wi = (const float4*)(Wim + ((size_t)p * PP + q0) * 1024 + m4);
    const float4* ca = (const float4*)(CINa + (size_t)q0 * 2048 + m4*2);
    const float4* cb = (const float4*)(CINb + (size_t)q0 * 2048 + m4*2);
    float re0=0,re1=0,re2=0,re3=0, im0=0,im1=0,im2=0,im3=0;
    #pragma unroll
    for (int q = 0; q < 12; ++q) {
        float4 a = wr[q * 256];
        float4 b = wi[q * 256];
        float4 c0 = ca[q * 512];
        float4 c1 = ca[q * 512 + 1];
        float4 d0 = cb[q * 512];
        float4 d1 = cb[q * 512 + 1];
        float cr0 = c0.x + d0.x, ci0 = c0.y + d0.y;
        float cr1 = c0.z + d0.z, ci1 = c0.w + d0.w;
        float cr2 = c1.x + d1.x, ci2 = c1.y + d1.y;
        float cr3 = c1.z + d1.z, ci3 = c1.w + d1.w;
        re0 += a.x*cr0 - b.x*ci0;  im0 += a.x*ci0 + b.x*cr0;
        re1 += a.y*cr1 - b.y*ci1;  im1 += a.y*ci1 + b.y*cr1;
        re2 += a.z*cr2 - b.z*ci2;  im2 += a.z*ci2 + b.z*cr2;
        re3 += a.w*cr3 - b.w*ci3;  im3 += a.w*ci3 + b.w*cr3;
    }
    float2* po = PART + ((size_t)part * PP + p) * 1024 + m4;
    po[0] = make_float2(re0, im0);
    po[1] = make_float2(re1, im1);
    po[2] = make_float2(re2, im2);
    po[3] = make_float2(re3, im3);
}

__global__ __launch_bounds__(256) void k_cred(
        const float2* __restrict__ PART, float2* __restrict__ COUT) {
    int t = blockIdx.x * 256 + threadIdx.x;   // 98304
    float2 s = PART[t];
    #pragma unroll
    for (int u = 1; u < 8; ++u) {
        float2 v = PART[(size_t)u*PP*1024 + t];
        s.x += v.x; s.y += v.y;
    }
    COUT[t] = s;
}

// ---------------- fused inverse ----------------
__global__ __launch_bounds__(256) void k_inv(
        const float2* __restrict__ COUT, float* __restrict__ UA,
        short* __restrict__ SBbf,
        const float* __restrict__ tiyA, const float* __restrict__ tiyB,
        const float* __restrict__ tixB, const short* __restrict__ T2x,
        const short* __restrict__ W1T, const short* __restrict__ W2T,
        const float* __restrict__ b1v, const float* __restrict__ b2v) {
    __shared__ __attribute__((aligned(16))) char smc[37888];
    int t = threadIdx.x;
    if (blockIdx.x < 512) {
        short* dwbf  = (short*)smc;                  // [48][72]
        short* b0bf  = (short*)smc;                  // [128][72]
        short* slbf  = (short*)(smc + 18432);        // [128][72]
        float2* tl   = (float2*)(smc + 36864);
        float* bl1   = (float*)(smc + 37120);
        float* bl2   = (float*)(smc + 37312);
        int y  = blockIdx.x >> 1;
        int xh = (blockIdx.x & 1) << 7;
        if (t < 32) tl[t] = ((const float2*)tiyA)[t*HA + y];
        if (t >= 64 && t < 112) bl1[t-64] = b1v[t-64];
        if (t >= 128 && t < 176) bl2[t-128] = b2v[t-128];
        __syncthreads();
        {
            int kx = t & 31, c0 = t >> 5;
            float re[6] = {0,0,0,0,0,0}, im[6] = {0,0,0,0,0,0};
            for (int j = 0; j < 32; ++j) {
                float2 ty = tl[j];
                #pragma unroll
                for (int k = 0; k < 6; ++k) {
                    float2 w = COUT[((c0 + 8*k)*32 + j)*32 + kx];
                    re[k] += w.x*ty.x - w.y*ty.y;
                    im[k] += w.x*ty.y + w.y*ty.x;
                }
            }
            #pragma unroll
            for (int k = 0; k < 6; ++k)
                *(unsigned*)(dwbf + (c0 + 8*k)*72 + 2*kx) = pack2(re[k], im[k]);
        }
        __syncthreads();
        int wv = t >> 6, lane = t & 63;
        int n = lane & 15, kg = lane >> 4;
        {
            f32x4 acc[2][3];
            #pragma unroll
            for (int i = 0; i < 2; ++i)
                #pragma unroll
                for (int mt = 0; mt < 3; ++mt)
                    acc[i][mt] = (f32x4){0.f,0.f,0.f,0.f};
            #pragma unroll
            for (int ks = 0; ks < 2; ++ks) {
                bf16x8 bfr[2];
                #pragma unroll
                for (int i = 0; i < 2; ++i) {
                    int px = xh + (wv*2 + i)*16 + n;
                    bfr[i] = *(const bf16x8*)(T2x + (size_t)px*64 + ks*32 + kg*8);
                }
                #pragma unroll
                for (int mt = 0; mt < 3; ++mt) {
                    bf16x8 af = *(const bf16x8*)(dwbf + (mt*16 + n)*72 + ks*32 + kg*8);
                    #pragma unroll
                    for (int i = 0; i < 2; ++i)
                        acc[i][mt] = __builtin_amdgcn_mfma_f32_16x16x32_bf16(af, bfr[i], acc[i][mt], 0, 0, 0);
                }
            }
            #pragma unroll
            for (int i = 0; i < 2; ++i) {
                int xl = (wv*2 + i)*16 + n;
                #pragma unroll
                for (int mt = 0; mt < 3; ++mt)
                    #pragma unroll
                    for (int r = 0; r < 4; ++r)
                        slbf[xl*72 + mt*16 + kg*4 + r] = f2bf(acc[i][mt][r]);
            }
            for (int idx = t; idx < 2048; idx += 256)
                slbf[(idx >> 4)*72 + 48 + (idx & 15)] = 0;
        }
        __syncthreads();
        {
            bf16x8 aw[3][2];
            #pragma unroll
            for (int mt = 0; mt < 3; ++mt)
                #pragma unroll
                for (int ks = 0; ks < 2; ++ks)
                    aw[mt][ks] = *(const bf16x8*)(W1T + (size_t)(mt*16 + n)*64 + ks*32 + kg*8);
            f32x4 acc[2][3];
            #pragma unroll
            for (int nt = 0; nt < 2; ++nt)
                #pragma unroll
                for (int mt = 0; mt < 3; ++mt)
                    acc[nt][mt] = (f32x4){0.f,0.f,0.f,0.f};
            #pragma unroll
            for (int nt = 0; nt < 2; ++nt) {
                int ntile = wv*2 + nt;
                #pragma unroll
                for (int ks = 0; ks < 2; ++ks) {
                    bf16x8 bfrag = *(const bf16x8*)(slbf + (size_t)(ntile*16 + n)*72 + ks*32 + kg*8);
                    #pragma unroll
                    for (int mt = 0; mt < 3; ++mt)
                        acc[nt][mt] = __builtin_amdgcn_mfma_f32_16x16x32_bf16(aw[mt][ks], bfrag, acc[nt][mt], 0, 0, 0);
                }
            }
            #pragma unroll
            for (int nt = 0; nt < 2; ++nt) {
                int px = (wv*2 + nt)*16 + n;
                #pragma unroll
                for (int mt = 0; mt < 3; ++mt) {
                    int oc0 = mt*16 + kg*4;
                    float g0 = gelu_f(acc[nt][mt][0] + bl1[oc0+0]);
                    float g1 = gelu_f(acc[nt][mt][1] + bl1[oc0+1]);
                    float g2 = gelu_f(acc[nt][mt][2] + bl1[oc0+2]);
                    float g3 = gelu_f(acc[nt][mt][3] + bl1[oc0+3]);
                    *(uint2*)(b0bf + (size_t)px*72 + oc0) = make_uint2(pack2(g0,g1), pack2(g2,g3));
                }
            }
            for (int idx = t; idx < 2048; idx += 256)
                b0bf[(idx >> 4)*72 + 48 + (idx & 15)] = 0;
        }
        __syncthreads();
        {
            bf16x8 aw[3][2];
            #pragma unroll
            for (int mt = 0; mt < 3; ++mt)
                #pragma unroll
                for (int ks = 0; ks < 2; ++ks)
                    aw[mt][ks] = *(const bf16x8*)(W2T + (size_t)(mt*16 + n)*64 + ks*32 + kg*8);
            f32x4 acc[2][3];
            #pragma unroll
            for (int nt = 0; nt < 2; ++nt)
                #pragma unroll
                for (int mt = 0; mt < 3; ++mt)
                    acc[nt][mt] = (f32x4){0.f,0.f,0.f,0.f};
            #pragma unroll
            for (int nt = 0; nt < 2; ++nt) {
                int ntile = wv*2 + nt;
                #pragma unroll
                for (int ks = 0; ks < 2; ++ks) {
                    bf16x8 bfrag = *(const bf16x8*)(b0bf + (size_t)(ntile*16 + n)*72 + ks*32 + kg*8);
                    #pragma unroll
                    for (int mt = 0; mt < 3; ++mt)
                        acc[nt][mt] = __builtin_amdgcn_mfma_f32_16x16x32_bf16(aw[mt][ks], bfrag, acc[nt][mt], 0, 0, 0);
                }
            }
            #pragma unroll
            for (int nt = 0; nt < 2; ++nt) {
                int px = (wv*2 + nt)*16 + n;
                #pragma unroll
                for (int mt = 0; mt < 3; ++mt) {
                    int oc0 = mt*16 + kg*4;
                    #pragma unroll
                    for (int r = 0; r < 4; ++r) {
                        int oc = oc0 + r;
                        size_t o = (size_t)oc*NPIXA + (size_t)y*WA + xh + px;
                        UA[o] = gelu_f(acc[nt][mt][r] + bl2[oc]) + UA[o];
                    }
                }
            }
        }
    } else {
        int b = blockIdx.x - 512;
        int c = b >> 4, yg = b & 15;
        int kx = t & 31, yr = t >> 5;
        int y = yg * 8 + yr;
        float re = 0.f, im = 0.f;
        const float2* crow = COUT + (size_t)(PA + c) * MM * MM + kx;
        const float2* tab = (const float2*)tiyB;
        #pragma unroll 8
        for (int j = 0; j < 32; ++j) {
            float2 w = crow[j * MM];
            float2 tv = tab[j * HB + y];
            re += w.x*tv.x - w.y*tv.y;
            im += w.x*tv.y + w.y*tv.x;
        }
        float2* ds = (float2*)smc;
        ds[yr*32 + kx] = make_float2(re, im);
        __syncthreads();
        int x = t & 127, rp = t >> 7;
        const float2* txb = (const float2*)tixB;
        for (int rr = rp; rr < 8; rr += 2) {
            const float2* drow = ds + rr*32;
            float a = 0.f;
            #pragma unroll
            for (int k2 = 0; k2 < 32; ++k2) {
                float2 tv = txb[k2*WB + x];
                float2 d = drow[k2];
                a += d.x*tv.x - d.y*tv.y;
            }
            SBbf[((size_t)c*HB + yg*8 + rr)*WB + x] = f2bf(a);
        }
    }
}

// ---------------- B-branch 3x3 conv via MFMA; bf16 in, bf16 or f32(+resid) out ----------------
__global__ __launch_bounds__(256) void k_conv3x3_mfma(
        const short* __restrict__ in, float* __restrict__ outf,
        short* __restrict__ outbf,
        const short* __restrict__ wt, const float* __restrict__ bias,
        const float* resid) {
    __shared__ float smf[3072];
    short* tile = (short*)smf;
    int y  = blockIdx.x >> 3;
    int x0 = (blockIdx.x & 7) << 4;
    int tid = threadIdx.x;

    for (int idx = tid; idx < 3456; idx += 256) {
        int r = idx / 1152;
        int rem = idx - r*1152;
        int ic = rem / 18;
        int px = rem - ic*18;
        int gy = y - 1 + r, gx = x0 - 1 + px;
        short v = 0;
        if (ic < 48 && gy >= 0 && gy < HB && gx >= 0 && gx < WB)
            v = in[(size_t)ic*NPIXB + gy*WB + gx];
        tile[(r*18 + px)*72 + ic] = v;
    }
    __syncthreads();

    int w = tid >> 6, lane = tid & 63;
    int n = lane & 15, kg = lane >> 4, m = lane & 15;
    f32x4 acc0 = {0.f,0.f,0.f,0.f}, acc1 = {0.f,0.f,0.f,0.f}, acc2 = {0.f,0.f,0.f,0.f};
    for (int s = w; s < 18; s += 4) {
        int tap = s >> 1;
        int kb = (s & 1) << 5;
        int dy = tap / 3, dx = tap - dy*3;
        bf16x8 bfrag = *(const bf16x8*)(tile + ((dy*18 + n + dx)*72 + kb + kg*8));
        const short* ap = wt + ((size_t)tap*48)*64 + kb + kg*8;
        bf16x8 a0 = *(const bf16x8*)(ap + (size_t)(m     )*64);
        bf16x8 a1 = *(const bf16x8*)(ap + (size_t)(16 + m)*64);
        bf16x8 a2 = *(const bf16x8*)(ap + (size_t)(32 + m)*64);
        acc0 = __builtin_amdgcn_mfma_f32_16x16x32_bf16(a0, bfrag, acc0, 0, 0, 0);
        acc1 = __builtin_amdgcn_mfma_f32_16x16x32_bf16(a1, bfrag, acc1, 0, 0, 0);
        acc2 = __builtin_amdgcn_mfma_f32_16x16x32_bf16(a2, bfrag, acc2, 0, 0, 0);
    }
    __syncthreads();
    float4* red = (float4*)smf;
    red[(w*3 + 0)*64 + lane] = make_float4(acc0[0], acc0[1], acc0[2], acc0[3]);
    red[(w*3 + 1)*64 + lane] = make_float4(acc1[0], acc1[1], acc1[2], acc1[3]);
    red[(w*3 + 2)*64 + lane] = make_float4(acc2[0], acc2[1], acc2[2], acc2[3]);
    __syncthreads();
    if (tid < 192) {
        int mt = tid >> 6, ln = tid & 63;
        float4 s0 = red[(0*3 + mt)*64 + ln];
        float4 s1 = red[(1*3 + mt)*64 + ln];
        float4 s2 = red[(2*3 + mt)*64 + ln];
        float4 s3 = red[(3*3 + mt)*64 + ln];
        float sum[4];
        sum[0] = s0.x + s1.x + s2.x + s3.x;
        sum[1] = s0.y + s1.y + s2.y + s3.y;
        sum[2] = s0.z + s1.z + s2.z + s3.z;
        sum[3] = s0.w + s1.w + s2.w + s3.w;
        int px = x0 + (ln & 15);
        #pragma unroll
        for (int r = 0; r < 4; ++r) {
            int oc = mt*16 + (ln >> 4)*4 + r;
            float v = sum[r] + bias[oc];
            v = gelu_f(v);
            size_t o = (size_t)oc*NPIXB + (size_t)y*WB + px;
            if (outbf) {
                outbf[o] = f2bf(v);
            } else {
                if (resid) v += resid[o];
                outf[o] = v;
            }
        }
    }
}

// ---------------- decoder ----------------
__global__ __launch_bounds__(256) void k_decode(
        const float* __restrict__ UA, const float* __restrict__ UB,
        const float* dwa, const float* dba,
        const float* dwb, const float* dbb, float* outp) {
    int t = blockIdx.x*256 + threadIdx.x;
    if (t < NPIXA) {
        float acc = dba[0];
        #pragma unroll 8
        for (int p = 0; p < PA; ++p) acc += dwa[p]*UA[(size_t)p*NPIXA + t];
        outp[t] = acc;
    } else {
        int u = t - NPIXA;
        float acc = dbb[0];
        #pragma unroll 8
        for (int p = 0; p < PB; ++p) acc += dwb[p]*UB[(size_t)p*NPIXB + u];
        outp[t] = acc;
    }
}

extern "C" void kernel_launch(void* const* d_in, const int* in_sizes, int n_in,
                              void* d_out, int out_size, void* d_ws, size_t ws_size,
                              hipStream_t stream) {
    const float* u_a   = (const float*)d_in[0];
    const float* x_a   = (const float*)d_in[1];
    const float* u_b   = (const float*)d_in[2];
    const float* x_b   = (const float*)d_in[3];
    const float* enc_a_w = (const float*)d_in[4];
    const float* enc_a_b = (const float*)d_in[5];
    const float* enc_b_w = (const float*)d_in[6];
    const float* enc_b_b = (const float*)d_in[7];
    const float* dec_a_w = (const float*)d_in[8];
    const float* dec_a_b = (const float*)d_in[9];
    const float* dec_b_w = (const float*)d_in[10];
    const float* dec_b_b = (const float*)d_in[11];
    const float* c1a_w = (const float*)d_in[12];
    const float* c1a_b = (const float*)d_in[13];
    const float* c2a_w = (const float*)d_in[14];
    const float* c2a_b = (const float*)d_in[15];
    const float* c1b_w = (const float*)d_in[16];
    const float* c1b_b = (const float*)d_in[17];
    const float* c2b_w = (const float*)d_in[18];
    const float* c2b_b = (const float*)d_in[19];
    const float* A_re = (const float*)d_in[20];
    const float* A_im = (const float*)d_in[21];

    float* ws = (float*)d_ws;
    size_t off = 0;
    auto alloc = [&](size_t n) { float* p = ws + off; off += n; return p; };
    short* WT    = (short*)alloc(4*2*9*48*64/2);
    short* TbfA  = (short*)alloc(64*WA/2);
    short* TbfB  = (short*)alloc(64*WB/2);
    short* WcT   = (short*)alloc(4*2*48*64/2);
    short* T2x   = (short*)alloc(WA*64/2);
    short* Ty2A  = (short*)alloc(64*512/2);
    short* Ty2B  = (short*)alloc(64*256/2);
    float* TiyA  = alloc(MM*HA*2);
    float* TixB  = alloc(MM*WB*2);
    float* TiyB  = alloc(MM*HB*2);
    float* UA = alloc((size_t)PA*NPIXA);
    float* UB = alloc((size_t)PB*NPIXB);
    short* SBbf = (short*)alloc((size_t)PB*NPIXB/2);
    short* TBbf = (short*)alloc((size_t)PB*NPIXB/2);
    short* FTA = (short*)alloc((size_t)PA*MM*512/2);
    short* FTB = (short*)alloc((size_t)PB*MM*256/2);
    float* CINa = alloc((size_t)PP*MM*MM*2);
    float* CINb = alloc((size_t)PP*MM*MM*2);
    float2* PART = (float2*)alloc((size_t)8*PP*MM*MM*2);
    float2* COUT = (float2*)alloc((size_t)PP*MM*MM*2);
    if (off * sizeof(float) > ws_size) return;

    k_pre<<<dim3(16656), dim3(256), 0, stream>>>(
        TiyA, TixB, TiyB, T2x,
        u_a,x_a,u_b,x_b, enc_a_w,enc_a_b,enc_b_w,enc_b_b, UA,UB,
        c1b_w, c2b_w, WT, TbfA, TbfB, c1a_w, c2a_w, WcT, Ty2A, Ty2B);
    for (int l = 0; l < 4; ++l) {
        k_fwd_x<<<dim3(576), dim3(256), 32*(WA+8)*2, stream>>>(UA,UB,FTA,FTB,TbfA,TbfB);
        k_fwd_y<<<dim3(192), dim3(256), 0, stream>>>(FTA,FTB,Ty2A,Ty2B,CINa,CINb);
        k_spectral<<<dim3(96,8), dim3(256), 0, stream>>>(
            A_re + (size_t)l*PP*PP*MM*MM, A_im + (size_t)l*PP*PP*MM*MM,
            CINa, CINb, PART);
        k_cred<<<dim3(384), dim3(256), 0, stream>>>((const float2*)PART, COUT);
        k_inv<<<dim3(512 + 768), dim3(256), 0, stream>>>((const float2*)COUT, UA, SBbf,
            TiyA, TiyB, TixB, T2x,
            WcT + (size_t)(l*2 + 0)*3072, WcT + (size_t)(l*2 + 1)*3072,
            c1a_b + (size_t)l*PA, c2a_b + (size_t)l*PA);
        k_conv3x3_mfma<<<dim3(1024), dim3(256), 0, stream>>>(SBbf, (float*)nullptr, TBbf,
            WT + (size_t)(l*2 + 0)*27648, c1b_b + (size_t)l*PB, (const float*)nullptr);
        k_conv3x3_mfma<<<dim3(1024), dim3(256), 0, stream>>>(TBbf, UB, (short*)nullptr,
            WT + (size_t)(l*2 + 1)*27648, c2b_b + (size_t)l*PB, UB);
    }
    k_decode<<<dim3(320), dim3(256), 0, stream>>>(UA, UB,
        dec_a_w, dec_a_b, dec_b_w, dec_b_b, (float*)d_out);
}

// Round 12
// 341.004 us; speedup vs baseline: 2.5092x; 1.2067x over previous
//
#include <hip/hip_runtime.h>

#define HA 256
#define WA 256
#define HB 128
#define WB 128
#define PA 48
#define PB 48
#define PP 96
#define MM 32
#define NPIXA (HA*WA)   // 65536
#define NPIXB (HB*WB)   // 16384

typedef short bf16x8 __attribute__((ext_vector_type(8)));
typedef float f32x4 __attribute__((ext_vector_type(4)));

__device__ __forceinline__ float gelu_f(float x) {
    float z = 0.7978845608028654f * (x + 0.044715f * x * x * x);
    float e = __expf(2.0f * z);
    return x - x / (e + 1.0f);
}

__device__ __forceinline__ short f2bf(float f) {
    unsigned u = __float_as_uint(f);
    unsigned r = (u + 0x7FFFu + ((u >> 16) & 1u)) >> 16;
    return (short)r;
}

__device__ __forceinline__ unsigned pack2(float a, float b) {
    return (unsigned)(unsigned short)f2bf(a) | ((unsigned)(unsigned short)f2bf(b) << 16);
}

// ---------------- tables + encoder + weight transforms, fused ----------------
// [0,48) trig | [48,15408) encode | [15408,16272) WT | [16272,16336) TbfA
// [16336,16368) TbfB | [16368,16464) WcT | [16464,16592) Ty2A | [16592,16656) Ty2B
// [16656,16720) TyIA | [16720,16752) TyIB | [16752,16784) T2xB
__global__ __launch_bounds__(256) void k_pre(
        float* tiyA, float* tixB, float* tiyB, short* T2x,
        const float* u_a, const float* x_a, const float* u_b, const float* x_b,
        const float* wa, const float* ba, const float* wb, const float* bb,
        float* UA, float* UB,
        const float* c1b_w, const float* c2b_w, short* WT,
        short* TbfA, short* TbfB,
        const float* c1a_w, const float* c2a_w, short* WcT,
        short* Ty2A, short* Ty2B,
        short* TyIA, short* TyIB, short* T2xB) {
    const float TWO_PI = 6.28318530717958647692f;
    int bid = blockIdx.x;
    if (bid < 48) {
        int t = bid * 256 + threadIdx.x;
        if (t < MM * WA) {
            int k = t / WA, x = t - k * WA;
            int m = (k * x) & (WA - 1);
            float ang = TWO_PI * (float)m / (float)WA;
            float s, c; __sincosf(ang, &s, &c);
            float wgt = (k == 0) ? 1.0f : 2.0f;
            T2x[x*64 + 2*k]   = f2bf(wgt * c);
            T2x[x*64 + 2*k+1] = f2bf(-wgt * s);
            int ky = k - 16;
            int my = (ky * x) & (HA - 1);
            float angy = TWO_PI * (float)my / (float)HA;
            float sy, cy; __sincosf(angy, &sy, &cy);
            tiyA[2*t] = cy; tiyA[2*t+1] = sy;
        } else if (t < MM * WA + MM * WB) {
            int t2 = t - MM * WA;
            int k = t2 / WB, x = t2 - k * WB;
            int m = (k * x) & (WB - 1);
            float ang = TWO_PI * (float)m / (float)WB;
            float s, c; __sincosf(ang, &s, &c);
            float wgt = (k == 0) ? 1.0f : 2.0f;
            tixB[2*t2] = wgt * c; tixB[2*t2+1] = wgt * s;
            int ky = k - 16;
            int my = (ky * x) & (HB - 1);
            float angy = TWO_PI * (float)my / (float)HB;
            float sy, cy; __sincosf(angy, &sy, &cy);
            tiyB[2*t2] = cy; tiyB[2*t2+1] = sy;
        }
    } else if (bid < 15408) {
        int eb = bid - 48;
        int o = eb / 320;
        int chunk = eb - o * 320;
        if (chunk < 256) {
            int pix = chunk * 256 + threadIdx.x;
            UA[(size_t)o*NPIXA + pix] = wa[o*3+0]*x_a[pix] + wa[o*3+1]*x_a[NPIXA+pix]
                                      + wa[o*3+2]*u_a[pix] + ba[o];
        } else {
            int pix = (chunk - 256) * 256 + threadIdx.x;
            UB[(size_t)o*NPIXB + pix] = wb[o*3+0]*x_b[pix] + wb[o*3+1]*x_b[NPIXB+pix]
                                      + wb[o*3+2]*u_b[pix] + bb[o];
        }
    } else if (bid < 16272) {
        int g = (bid - 15408) * 256 + threadIdx.x;
        if (g < 4*2*9*48*64) {
            int l  = g / 55296;
            int r1 = g - l*55296;
            int cv = r1 / 27648;
            int r2 = r1 - cv*27648;
            int tap = r2 / 3072;
            int r3 = r2 - tap*3072;
            int oc = r3 >> 6;
            int ic = r3 & 63;
            const float* src = cv ? c2b_w : c1b_w;
            float v = 0.f;
            if (ic < 48) v = src[(((size_t)l*48 + oc)*48 + ic)*9 + tap];
            WT[g] = f2bf(v);
        }
    } else if (bid < 16336) {
        int g = (bid - 16272) * 256 + threadIdx.x;   // 16384
        int col = g >> 8, x = g & 255;
        int k = col >> 1, comp = col & 1;
        int m = (k * x) & (WA - 1);
        float ang = TWO_PI * (float)m / (float)WA;
        float s, c; __sincosf(ang, &s, &c);
        float sc = 1.0f / (float)(HA * WA);
        TbfA[col*WA + x] = f2bf(comp ? -s * sc : c * sc);
    } else if (bid < 16368) {
        int g = (bid - 16336) * 256 + threadIdx.x;   // 8192
        int col = g >> 7, x = g & 127;
        int k = col >> 1, comp = col & 1;
        int m = (k * x) & (WB - 1);
        float ang = TWO_PI * (float)m / (float)WB;
        float s, c; __sincosf(ang, &s, &c);
        float sc = 1.0f / (float)(HB * WB);
        TbfB[col*WB + x] = f2bf(comp ? -s * sc : c * sc);
    } else if (bid < 16464) {
        int g = (bid - 16368) * 256 + threadIdx.x;   // 24576
        int l  = g / 6144;
        int r  = g - l*6144;
        int cv = r / 3072;
        int r2 = r - cv*3072;
        int oc = r2 >> 6;
        int ic = r2 & 63;
        const float* src = cv ? c2a_w : c1a_w;
        float v = 0.f;
        if (ic < 48) v = src[((size_t)l*48 + oc)*48 + ic];
        WcT[g] = f2bf(v);
    } else if (bid < 16592) {
        int g = (bid - 16464) * 256 + threadIdx.x;   // 32768
        int row = g >> 9, col = g & 511;
        int j = row >> 1, comp = row & 1;
        int y = col >> 1, comp2 = col & 1;
        int my = ((j - 16) * y) & (HA - 1);
        float ang = TWO_PI * (float)my / (float)HA;
        float sy, cy; __sincosf(ang, &sy, &cy);
        float v = comp == 0 ? (comp2 == 0 ? cy : sy) : (comp2 == 0 ? -sy : cy);
        Ty2A[g] = f2bf(v);
    } else if (bid < 16656) {
        int g = (bid - 16592) * 256 + threadIdx.x;   // 16384
        int row = g >> 8, col = g & 255;
        int j = row >> 1, comp = row & 1;
        int y = col >> 1, comp2 = col & 1;
        int my = ((j - 16) * y) & (HB - 1);
        float ang = TWO_PI * (float)my / (float)HB;
        float sy, cy; __sincosf(ang, &sy, &cy);
        float v = comp == 0 ? (comp2 == 0 ? cy : sy) : (comp2 == 0 ? -sy : cy);
        Ty2B[g] = f2bf(v);
    } else if (bid < 16720) {
        // TyIA[y][2j]: inv-y twiddles e^{+i}, (cy, sy)
        int g = (bid - 16656) * 256 + threadIdx.x;   // 16384
        int y = g >> 6, col = g & 63;
        int j = col >> 1, comp = col & 1;
        int my = ((j - 16) * y) & (HA - 1);
        float ang = TWO_PI * (float)my / (float)HA;
        float sy, cy; __sincosf(ang, &sy, &cy);
        TyIA[g] = f2bf(comp ? sy : cy);
    } else if (bid < 16752) {
        int g = (bid - 16720) * 256 + threadIdx.x;   // 8192
        int y = g >> 6, col = g & 63;
        int j = col >> 1, comp = col & 1;
        int my = ((j - 16) * y) & (HB - 1);
        float ang = TWO_PI * (float)my / (float)HB;
        float sy, cy; __sincosf(ang, &sy, &cy);
        TyIB[g] = f2bf(comp ? sy : cy);
    } else {
        // T2xB[x][2k]: inv-x B-branch, (wgt*c, -wgt*s)
        int g = (bid - 16752) * 256 + threadIdx.x;   // 8192
        int x = g >> 6, col = g & 63;
        int k = col >> 1, comp = col & 1;
        int m = (k * x) & (WB - 1);
        float ang = TWO_PI * (float)m / (float)WB;
        float s, c; __sincosf(ang, &s, &c);
        float wgt = (k == 0) ? 1.0f : 2.0f;
        T2xB[g] = f2bf(comp ? -wgt * s : wgt * c);
    }
}

// ---------------- forward DFT along x via MFMA; coalesced FT writes ----------------
__global__ __launch_bounds__(256) void k_fwd_x(
        const float* __restrict__ UA, const float* __restrict__ UB,
        short* __restrict__ FTA, short* __restrict__ FTB,
        const short* __restrict__ TbfA, const short* __restrict__ TbfB) {
    extern __shared__ short lsb[];   // [32][N+8] bf16; reused as trb[64][36]
    int bid = blockIdx.x;
    const float* U; short* FT; const short* T; int N, ymask, cshift;
    if (bid < 384) { U = UA; FT = FTA; T = TbfA; N = WA; ymask = 255; cshift = 8; }
    else { bid -= 384; U = UB; FT = FTB; T = TbfB; N = WB; ymask = 127; cshift = 7; }
    int r0 = bid * 32;
    int c = r0 >> cshift;
    int ybase = r0 & ymask;
    int NP = N + 8;
    int nq = N >> 2;
    const float4* src = (const float4*)(U + (size_t)r0 * N);
    for (int i = threadIdx.x; i < 32*nq; i += 256) {
        int r = i / nq, q = i - r*nq;
        float4 v = src[i];
        *(uint2*)(lsb + r*NP + q*4) = make_uint2(pack2(v.x, v.y), pack2(v.z, v.w));
    }
    __syncthreads();
    int wv = threadIdx.x >> 6, lane = threadIdx.x & 63;
    int n = lane & 15, kg = lane >> 4;
    int col = wv*16 + n;
    const short* Tc = T + (size_t)col * N;
    f32x4 acc0 = {0.f,0.f,0.f,0.f}, acc1 = {0.f,0.f,0.f,0.f};
    for (int ks = 0; ks < (N >> 5); ++ks) {
        bf16x8 bfrag = *(const bf16x8*)(Tc + ks*32 + kg*8);
        bf16x8 a0 = *(const bf16x8*)(lsb + (size_t)n*NP + ks*32 + kg*8);
        bf16x8 a1 = *(const bf16x8*)(lsb + (size_t)(16+n)*NP + ks*32 + kg*8);
        acc0 = __builtin_amdgcn_mfma_f32_16x16x32_bf16(a0, bfrag, acc0, 0, 0, 0);
        acc1 = __builtin_amdgcn_mfma_f32_16x16x32_bf16(a1, bfrag, acc1, 0, 0, 0);
    }
    __syncthreads();
    short* trb = lsb;   // [64 col][36]
    #pragma unroll
    for (int r = 0; r < 4; ++r) {
        trb[col*36 + kg*4 + r]      = f2bf(acc0[r]);
        trb[col*36 + 16 + kg*4 + r] = f2bf(acc1[r]);
    }
    __syncthreads();
    int K2 = 2 * (ymask + 1);
    for (int idx = threadIdx.x; idx < 512; idx += 256) {
        int kx = idx >> 4, q = idx & 15;
        int yl = q * 2;
        unsigned lo = (unsigned)(unsigned short)trb[(2*kx+0)*36 + yl]
                    | ((unsigned)(unsigned short)trb[(2*kx+1)*36 + yl] << 16);
        unsigned hi = (unsigned)(unsigned short)trb[(2*kx+0)*36 + yl+1]
                    | ((unsigned)(unsigned short)trb[(2*kx+1)*36 + yl+1] << 16);
        *(uint2*)(FT + ((size_t)(c*32 + kx))*K2 + 2*(size_t)ybase + yl*2) = make_uint2(lo, hi);
    }
}

// ---------------- forward DFT along y via MFMA (2-way K-split partials) ----------------
__global__ __launch_bounds__(256) void k_fwd_y(
        const short* __restrict__ FTA, const short* __restrict__ FTB,
        const short* __restrict__ Ty2A, const short* __restrict__ Ty2B,
        float* __restrict__ CINa, float* __restrict__ CINb) {
    __shared__ short lsb[32*264];
    int bid = blockIdx.x;
    const short* FT; const short* Ty; int K2, NP, pbase, c, h;
    if (bid < 96) { c = bid>>1; h = bid&1; FT = FTA; Ty = Ty2A; K2 = 512; NP = 264; pbase = 0; }
    else { int b2 = bid - 96; c = b2>>1; h = b2&1; FT = FTB; Ty = Ty2B; K2 = 256; NP = 136; pbase = 48; }
    float* CO = (h == 0) ? CINa : CINb;
    int hlen = K2 >> 1;
    int nchunk = hlen >> 3;
    for (int idx = threadIdx.x; idx < 32*nchunk; idx += 256) {
        int row = idx / nchunk, q = idx - row*nchunk;
        *(uint4*)(lsb + row*NP + q*8) =
            *(const uint4*)(FT + ((size_t)c*32 + row)*K2 + h*hlen + q*8);
    }
    __syncthreads();
    int w = threadIdx.x >> 6, lane = threadIdx.x & 63;
    int n = lane & 15, kg = lane >> 4;
    f32x4 acc0 = {0.f,0.f,0.f,0.f}, acc1 = {0.f,0.f,0.f,0.f};
    int nks = hlen >> 5;
    for (int ks = 0; ks < nks; ++ks) {
        bf16x8 af = *(const bf16x8*)(Ty + (size_t)(w*16 + n)*K2 + h*hlen + ks*32 + kg*8);
        bf16x8 b0 = *(const bf16x8*)(lsb + n*NP + ks*32 + kg*8);
        bf16x8 b1 = *(const bf16x8*)(lsb + (16+n)*NP + ks*32 + kg*8);
        acc0 = __builtin_amdgcn_mfma_f32_16x16x32_bf16(af, b0, acc0, 0, 0, 0);
        acc1 = __builtin_amdgcn_mfma_f32_16x16x32_bf16(af, b1, acc1, 0, 0, 0);
    }
    #pragma unroll
    for (int r = 0; r < 4; ++r) {
        int row = w*16 + kg*4 + r;
        int j = row >> 1, comp = row & 1;
        size_t base = (((size_t)(pbase + c))*32 + j)*32;
        CO[(base + n)*2 + comp]      = acc0[r];
        CO[(base + 16 + n)*2 + comp] = acc1[r];
    }
}

// ---------------- spectral mix: float4, 8-way q-split, 4 modes/thread ----------------
__global__ __launch_bounds__(256) void k_spectral(
        const float* __restrict__ Wre, const float* __restrict__ Wim,
        const float* __restrict__ CINa, const float* __restrict__ CINb,
        float2* __restrict__ PART) {
    int part = blockIdx.y;
    int t = blockIdx.x * 256 + threadIdx.x;
    int p = t >> 8;
    int m4 = (t & 255) << 2;
    int q0 = part * 12;
    const float4* wr = (const float4*)(Wre + ((size_t)p * PP + q0) * 1024 + m4);
    const float4* wi = (const float4*)(Wim + ((size_t)p * PP + q0) * 1024 + m4);
    const float4* ca = (const float4*)(CINa + (size_t)q0 * 2048 + m4*2);
    const float4* cb = (const float4*)(CINb + (size_t)q0 * 2048 + m4*2);
    float re0=0,re1=0,re2=0,re3=0, im0=0,im1=0,im2=0,im3=0;
    #pragma unroll
    for (int q = 0; q < 12; ++q) {
        float4 a = wr[q * 256];
        float4 b = wi[q * 256];
        float4 c0 = ca[q * 512];
        float4 c1 = ca[q * 512 + 1];
        float4 d0 = cb[q * 512];
        float4 d1 = cb[q * 512 + 1];
        float cr0 = c0.x + d0.x, ci0 = c0.y + d0.y;
        float cr1 = c0.z + d0.z, ci1 = c0.w + d0.w;
        float cr2 = c1.x + d1.x, ci2 = c1.y + d1.y;
        float cr3 = c1.z + d1.z, ci3 = c1.w + d1.w;
        re0 += a.x*cr0 - b.x*ci0;  im0 += a.x*ci0 + b.x*cr0;
        re1 += a.y*cr1 - b.y*ci1;  im1 += a.y*ci1 + b.y*cr1;
        re2 += a.z*cr2 - b.z*ci2;  im2 += a.z*ci2 + b.z*cr2;
        re3 += a.w*cr3 - b.w*ci3;  im3 += a.w*ci3 + b.w*cr3;
    }
    float2* po = PART + ((size_t)part * PP + p) * 1024 + m4;
    po[0] = make_float2(re0, im0);
    po[1] = make_float2(re1, im1);
    po[2] = make_float2(re2, im2);
    po[3] = make_float2(re3, im3);
}

// ---------------- inverse DFT along y via MFMA (fuses cred) ----------------
// A: bid<96 (c, y-half); B: bid 96..143 (c). Output DA[y][c][2kx+comp] bf16, DB likewise.
__global__ __launch_bounds__(256) void k_invy(
        const float2* __restrict__ PART,
        const short* __restrict__ TyIA, const short* __restrict__ TyIB,
        short* __restrict__ DA, short* __restrict__ DB) {
    __shared__ short A2[64*72];
    int bid = blockIdx.x;
    int c, yh, cb; const short* Ty; short* D;
    if (bid < 96) { c = bid >> 1; yh = bid & 1; Ty = TyIA; D = DA; cb = c; }
    else { c = bid - 96 + 48; yh = 0; Ty = TyIB; D = DB; cb = c - 48; }
    for (int idx = threadIdx.x; idx < 1024; idx += 256) {
        int j = idx >> 5, kx = idx & 31;
        float re = 0.f, im = 0.f;
        const float2* pp = PART + (size_t)c*1024 + idx;
        #pragma unroll
        for (int u = 0; u < 8; ++u) {
            float2 v = pp[(size_t)u*PP*1024];
            re += v.x; im += v.y;
        }
        A2[(2*kx+0)*72 + 2*j]   = f2bf(re);
        A2[(2*kx+0)*72 + 2*j+1] = f2bf(-im);
        A2[(2*kx+1)*72 + 2*j]   = f2bf(im);
        A2[(2*kx+1)*72 + 2*j+1] = f2bf(re);
    }
    __syncthreads();
    int wv = threadIdx.x >> 6, lane = threadIdx.x & 63;
    int n = lane & 15, kg = lane >> 4;
    #pragma unroll
    for (int ntl = 0; ntl < 2; ++ntl) {
        int nt = wv*2 + ntl;
        int y = yh*128 + nt*16 + n;
        bf16x8 bf0 = *(const bf16x8*)(Ty + (size_t)y*64 + kg*8);
        bf16x8 bf1 = *(const bf16x8*)(Ty + (size_t)y*64 + 32 + kg*8);
        #pragma unroll
        for (int mt = 0; mt < 4; ++mt) {
            bf16x8 a0 = *(const bf16x8*)(A2 + (mt*16 + n)*72 + kg*8);
            bf16x8 a1 = *(const bf16x8*)(A2 + (mt*16 + n)*72 + 32 + kg*8);
            f32x4 acc = {0.f,0.f,0.f,0.f};
            acc = __builtin_amdgcn_mfma_f32_16x16x32_bf16(a0, bf0, acc, 0, 0, 0);
            acc = __builtin_amdgcn_mfma_f32_16x16x32_bf16(a1, bf1, acc, 0, 0, 0);
            int row0 = mt*16 + kg*4;
            *(uint2*)(D + (size_t)y*3072 + cb*64 + row0) =
                make_uint2(pack2(acc[0], acc[1]), pack2(acc[2], acc[3]));
        }
    }
}

// ---------------- fused inverse tail ----------------
// A (0..511): DA -> inv_x MFMA -> conv1 MFMA -> conv2 MFMA + resid -> UA
// B (512..639): DB -> inv_x MFMA -> SBbf (LDS-transposed coalesced write)
__global__ __launch_bounds__(256) void k_inv(
        const short* __restrict__ DA, const short* __restrict__ DB,
        float* __restrict__ UA, short* __restrict__ SBbf,
        const short* __restrict__ T2x, const short* __restrict__ T2xB,
        const short* __restrict__ W1T, const short* __restrict__ W2T,
        const float* __restrict__ b1v, const float* __restrict__ b2v) {
    __shared__ __attribute__((aligned(16))) char smc[37888];
    int t = threadIdx.x;
    int wv = t >> 6, lane = t & 63;
    int n = lane & 15, kg = lane >> 4;
    if (blockIdx.x < 512) {
        short* b0bf  = (short*)smc;                  // [128][72]
        short* slbf  = (short*)(smc + 18432);        // [128][72]
        float* bl1   = (float*)(smc + 37120);
        float* bl2   = (float*)(smc + 37312);
        int y  = blockIdx.x >> 1;
        int xh = (blockIdx.x & 1) << 7;
        if (t >= 64 && t < 112) bl1[t-64] = b1v[t-64];
        if (t >= 128 && t < 176) bl2[t-128] = b2v[t-128];
        const short* DAy = DA + (size_t)y*3072;
        // phase 2: inv-x via MFMA
        {
            f32x4 acc[2][3];
            #pragma unroll
            for (int i = 0; i < 2; ++i)
                #pragma unroll
                for (int mt = 0; mt < 3; ++mt)
                    acc[i][mt] = (f32x4){0.f,0.f,0.f,0.f};
            #pragma unroll
            for (int ks = 0; ks < 2; ++ks) {
                bf16x8 bfr[2];
                #pragma unroll
                for (int i = 0; i < 2; ++i) {
                    int px = xh + (wv*2 + i)*16 + n;
                    bfr[i] = *(const bf16x8*)(T2x + (size_t)px*64 + ks*32 + kg*8);
                }
                #pragma unroll
                for (int mt = 0; mt < 3; ++mt) {
                    bf16x8 af = *(const bf16x8*)(DAy + (mt*16 + n)*64 + ks*32 + kg*8);
                    #pragma unroll
                    for (int i = 0; i < 2; ++i)
                        acc[i][mt] = __builtin_amdgcn_mfma_f32_16x16x32_bf16(af, bfr[i], acc[i][mt], 0, 0, 0);
                }
            }
            #pragma unroll
            for (int i = 0; i < 2; ++i) {
                int xl = (wv*2 + i)*16 + n;
                #pragma unroll
                for (int mt = 0; mt < 3; ++mt)
                    #pragma unroll
                    for (int r = 0; r < 4; ++r)
                        slbf[xl*72 + mt*16 + kg*4 + r] = f2bf(acc[i][mt][r]);
            }
            for (int idx = t; idx < 2048; idx += 256)
                slbf[(idx >> 4)*72 + 48 + (idx & 15)] = 0;
        }
        __syncthreads();
        // phase 3: conv1 MFMA + gelu -> b0bf
        {
            bf16x8 aw[3][2];
            #pragma unroll
            for (int mt = 0; mt < 3; ++mt)
                #pragma unroll
                for (int ks = 0; ks < 2; ++ks)
                    aw[mt][ks] = *(const bf16x8*)(W1T + (size_t)(mt*16 + n)*64 + ks*32 + kg*8);
            f32x4 acc[2][3];
            #pragma unroll
            for (int nt = 0; nt < 2; ++nt)
                #pragma unroll
                for (int mt = 0; mt < 3; ++mt)
                    acc[nt][mt] = (f32x4){0.f,0.f,0.f,0.f};
            #pragma unroll
            for (int nt = 0; nt < 2; ++nt) {
                int ntile = wv*2 + nt;
                #pragma unroll
                for (int ks = 0; ks < 2; ++ks) {
                    bf16x8 bfrag = *(const bf16x8*)(slbf + (size_t)(ntile*16 + n)*72 + ks*32 + kg*8);
                    #pragma unroll
                    for (int mt = 0; mt < 3; ++mt)
                        acc[nt][mt] = __builtin_amdgcn_mfma_f32_16x16x32_bf16(aw[mt][ks], bfrag, acc[nt][mt], 0, 0, 0);
                }
            }
            #pragma unroll
            for (int nt = 0; nt < 2; ++nt) {
                int px = (wv*2 + nt)*16 + n;
                #pragma unroll
                for (int mt = 0; mt < 3; ++mt) {
                    int oc0 = mt*16 + kg*4;
                    float g0 = gelu_f(acc[nt][mt][0] + bl1[oc0+0]);
                    float g1 = gelu_f(acc[nt][mt][1] + bl1[oc0+1]);
                    float g2 = gelu_f(acc[nt][mt][2] + bl1[oc0+2]);
                    float g3 = gelu_f(acc[nt][mt][3] + bl1[oc0+3]);
                    *(uint2*)(b0bf + (size_t)px*72 + oc0) = make_uint2(pack2(g0,g1), pack2(g2,g3));
                }
            }
            for (int idx = t; idx < 2048; idx += 256)
                b0bf[(idx >> 4)*72 + 48 + (idx & 15)] = 0;
        }
        __syncthreads();
        // phase 4: conv2 MFMA + gelu + residual -> UA
        {
            bf16x8 aw[3][2];
            #pragma unroll
            for (int mt = 0; mt < 3; ++mt)
                #pragma unroll
                for (int ks = 0; ks < 2; ++ks)
                    aw[mt][ks] = *(const bf16x8*)(W2T + (size_t)(mt*16 + n)*64 + ks*32 + kg*8);
            f32x4 acc[2][3];
            #pragma unroll
            for (int nt = 0; nt < 2; ++nt)
                #pragma unroll
                for (int mt = 0; mt < 3; ++mt)
                    acc[nt][mt] = (f32x4){0.f,0.f,0.f,0.f};
            #pragma unroll
            for (int nt = 0; nt < 2; ++nt) {
                int ntile = wv*2 + nt;
                #pragma unroll
                for (int ks = 0; ks < 2; ++ks) {
                    bf16x8 bfrag = *(const bf16x8*)(b0bf + (size_t)(ntile*16 + n)*72 + ks*32 + kg*8);
                    #pragma unroll
                    for (int mt = 0; mt < 3; ++mt)
                        acc[nt][mt] = __builtin_amdgcn_mfma_f32_16x16x32_bf16(aw[mt][ks], bfrag, acc[nt][mt], 0, 0, 0);
                }
            }
            #pragma unroll
            for (int nt = 0; nt < 2; ++nt) {
                int px = (wv*2 + nt)*16 + n;
                #pragma unroll
                for (int mt = 0; mt < 3; ++mt) {
                    int oc0 = mt*16 + kg*4;
                    #pragma unroll
                    for (int r = 0; r < 4; ++r) {
                        int oc = oc0 + r;
                        size_t o = (size_t)oc*NPIXA + (size_t)y*WA + xh + px;
                        UA[o] = gelu_f(acc[nt][mt][r] + bl2[oc]) + UA[o];
                    }
                }
            }
        }
    } else {
        // B path: inv_x MFMA, M=48 c, N=128 x, K=64
        int y = blockIdx.x - 512;
        short* sbuf = (short*)smc;    // [48][132]
        const short* DBy = DB + (size_t)y*3072;
        #pragma unroll
        for (int ntl = 0; ntl < 2; ++ntl) {
            int nt = wv*2 + ntl;
            int x = nt*16 + n;
            bf16x8 bf0 = *(const bf16x8*)(T2xB + (size_t)x*64 + kg*8);
            bf16x8 bf1 = *(const bf16x8*)(T2xB + (size_t)x*64 + 32 + kg*8);
            #pragma unroll
            for (int mt = 0; mt < 3; ++mt) {
                bf16x8 a0 = *(const bf16x8*)(DBy + (mt*16 + n)*64 + kg*8);
                bf16x8 a1 = *(const bf16x8*)(DBy + (mt*16 + n)*64 + 32 + kg*8);
                f32x4 acc = {0.f,0.f,0.f,0.f};
                acc = __builtin_amdgcn_mfma_f32_16x16x32_bf16(a0, bf0, acc, 0, 0, 0);
                acc = __builtin_amdgcn_mfma_f32_16x16x32_bf16(a1, bf1, acc, 0, 0, 0);
                int c0 = mt*16 + kg*4;
                #pragma unroll
                for (int r = 0; r < 4; ++r)
                    sbuf[(c0 + r)*132 + x] = f2bf(acc[r]);
            }
        }
        __syncthreads();
        for (int idx = t; idx < 768; idx += 256) {
            int cc = idx >> 4, q = idx & 15;
            uint4 v = *(const uint4*)(sbuf + cc*132 + q*8);
            *(uint4*)(SBbf + (size_t)cc*NPIXB + (size_t)y*WB + q*8) = v;
        }
    }
}

// ---------------- B-branch 3x3 conv via MFMA; bf16 in, bf16 or f32(+resid) out ----------------
__global__ __launch_bounds__(256) void k_conv3x3_mfma(
        const short* __restrict__ in, float* __restrict__ outf,
        short* __restrict__ outbf,
        const short* __restrict__ wt, const float* __restrict__ bias,
        const float* resid) {
    __shared__ float smf[3072];
    short* tile = (short*)smf;
    int y  = blockIdx.x >> 3;
    int x0 = (blockIdx.x & 7) << 4;
    int tid = threadIdx.x;

    for (int idx = tid; idx < 3456; idx += 256) {
        int r = idx / 1152;
        int rem = idx - r*1152;
        int ic = rem / 18;
        int px = rem - ic*18;
        int gy = y - 1 + r, gx = x0 - 1 + px;
        short v = 0;
        if (ic < 48 && gy >= 0 && gy < HB && gx >= 0 && gx < WB)
            v = in[(size_t)ic*NPIXB + gy*WB + gx];
        tile[(r*18 + px)*72 + ic] = v;
    }
    __syncthreads();

    int w = tid >> 6, lane = tid & 63;
    int n = lane & 15, kg = lane >> 4, m = lane & 15;
    f32x4 acc0 = {0.f,0.f,0.f,0.f}, acc1 = {0.f,0.f,0.f,0.f}, acc2 = {0.f,0.f,0.f,0.f};
    for (int s = w; s < 18; s += 4) {
        int tap = s >> 1;
        int kb = (s & 1) << 5;
        int dy = tap / 3, dx = tap - dy*3;
        bf16x8 bfrag = *(const bf16x8*)(tile + ((dy*18 + n + dx)*72 + kb + kg*8));
        const short* ap = wt + ((size_t)tap*48)*64 + kb + kg*8;
        bf16x8 a0 = *(const bf16x8*)(ap + (size_t)(m     )*64);
        bf16x8 a1 = *(const bf16x8*)(ap + (size_t)(16 + m)*64);
        bf16x8 a2 = *(const bf16x8*)(ap + (size_t)(32 + m)*64);
        acc0 = __builtin_amdgcn_mfma_f32_16x16x32_bf16(a0, bfrag, acc0, 0, 0, 0);
        acc1 = __builtin_amdgcn_mfma_f32_16x16x32_bf16(a1, bfrag, acc1, 0, 0, 0);
        acc2 = __builtin_amdgcn_mfma_f32_16x16x32_bf16(a2, bfrag, acc2, 0, 0, 0);
    }
    __syncthreads();
    float4* red = (float4*)smf;
    red[(w*3 + 0)*64 + lane] = make_float4(acc0[0], acc0[1], acc0[2], acc0[3]);
    red[(w*3 + 1)*64 + lane] = make_float4(acc1[0], acc1[1], acc1[2], acc1[3]);
    red[(w*3 + 2)*64 + lane] = make_float4(acc2[0], acc2[1], acc2[2], acc2[3]);
    __syncthreads();
    if (tid < 192) {
        int mt = tid >> 6, ln = tid & 63;
        float4 s0 = red[(0*3 + mt)*64 + ln];
        float4 s1 = red[(1*3 + mt)*64 + ln];
        float4 s2 = red[(2*3 + mt)*64 + ln];
        float4 s3 = red[(3*3 + mt)*64 + ln];
        float sum[4];
        sum[0] = s0.x + s1.x + s2.x + s3.x;
        sum[1] = s0.y + s1.y + s2.y + s3.y;
        sum[2] = s0.z + s1.z + s2.z + s3.z;
        sum[3] = s0.w + s1.w + s2.w + s3.w;
        int px = x0 + (ln & 15);
        #pragma unroll
        for (int r = 0; r < 4; ++r) {
            int oc = mt*16 + (ln >> 4)*4 + r;
            float v = sum[r] + bias[oc];
            v = gelu_f(v);
            size_t o = (size_t)oc*NPIXB + (size_t)y*WB + px;
            if (outbf) {
                outbf[o] = f2bf(v);
            } else {
                if (resid) v += resid[o];
                outf[o] = v;
            }
        }
    }
}

// ---------------- decoder ----------------
__global__ __launch_bounds__(256) void k_decode(
        const float* __restrict__ UA, const float* __restrict__ UB,
        const float* dwa, const float* dba,
        const float* dwb, const float* dbb, float* outp) {
    int t = blockIdx.x*256 + threadIdx.x;
    if (t < NPIXA) {
        float acc = dba[0];
        #pragma unroll 8
        for (int p = 0; p < PA; ++p) acc += dwa[p]*UA[(size_t)p*NPIXA + t];
        outp[t] = acc;
    } else {
        int u = t - NPIXA;
        float acc = dbb[0];
        #pragma unroll 8
        for (int p = 0; p < PB; ++p) acc += dwb[p]*UB[(size_t)p*NPIXB + u];
        outp[t] = acc;
    }
}

extern "C" void kernel_launch(void* const* d_in, const int* in_sizes, int n_in,
                              void* d_out, int out_size, void* d_ws, size_t ws_size,
                              hipStream_t stream) {
    const float* u_a   = (const float*)d_in[0];
    const float* x_a   = (const float*)d_in[1];
    const float* u_b   = (const float*)d_in[2];
    const float* x_b   = (const float*)d_in[3];
    const float* enc_a_w = (const float*)d_in[4];
    const float* enc_a_b = (const float*)d_in[5];
    const float* enc_b_w = (const float*)d_in[6];
    const float* enc_b_b = (const float*)d_in[7];
    const float* dec_a_w = (const float*)d_in[8];
    const float* dec_a_b = (const float*)d_in[9];
    const float* dec_b_w = (const float*)d_in[10];
    const float* dec_b_b = (const float*)d_in[11];
    const float* c1a_w = (const float*)d_in[12];
    const float* c1a_b = (const float*)d_in[13];
    const float* c2a_w = (const float*)d_in[14];
    const float* c2a_b = (const float*)d_in[15];
    const float* c1b_w = (const float*)d_in[16];
    const float* c1b_b = (const float*)d_in[17];
    const float* c2b_w = (const float*)d_in[18];
    const float* c2b_b = (const float*)d_in[19];
    const float* A_re = (const float*)d_in[20];
    const float* A_im = (const float*)d_in[21];

    float* ws = (float*)d_ws;
    size_t off = 0;
    auto alloc = [&](size_t n) { float* p = ws + off; off += n; return p; };
    short* WT    = (short*)alloc(4*2*9*48*64/2);
    short* TbfA  = (short*)alloc(64*WA/2);
    short* TbfB  = (short*)alloc(64*WB/2);
    short* WcT   = (short*)alloc(4*2*48*64/2);
    short* T2x   = (short*)alloc(WA*64/2);
    short* T2xB  = (short*)alloc(WB*64/2);
    short* Ty2A  = (short*)alloc(64*512/2);
    short* Ty2B  = (short*)alloc(64*256/2);
    short* TyIA  = (short*)alloc(HA*64/2);
    short* TyIB  = (short*)alloc(HB*64/2);
    float* TiyA  = alloc(MM*HA*2);
    float* TixB  = alloc(MM*WB*2);
    float* TiyB  = alloc(MM*HB*2);
    float* UA = alloc((size_t)PA*NPIXA);
    float* UB = alloc((size_t)PB*NPIXB);
    short* SBbf = (short*)alloc((size_t)PB*NPIXB/2);
    short* TBbf = (short*)alloc((size_t)PB*NPIXB/2);
    short* FTA = (short*)alloc((size_t)PA*MM*512/2);
    short* FTB = (short*)alloc((size_t)PB*MM*256/2);
    short* DA  = (short*)alloc((size_t)HA*3072/2);
    short* DB  = (short*)alloc((size_t)HB*3072/2);
    float* CINa = alloc((size_t)PP*MM*MM*2);
    float* CINb = alloc((size_t)PP*MM*MM*2);
    float2* PART = (float2*)alloc((size_t)8*PP*MM*MM*2);
    if (off * sizeof(float) > ws_size) return;

    k_pre<<<dim3(16784), dim3(256), 0, stream>>>(
        TiyA, TixB, TiyB, T2x,
        u_a,x_a,u_b,x_b, enc_a_w,enc_a_b,enc_b_w,enc_b_b, UA,UB,
        c1b_w, c2b_w, WT, TbfA, TbfB, c1a_w, c2a_w, WcT, Ty2A, Ty2B,
        TyIA, TyIB, T2xB);
    for (int l = 0; l < 4; ++l) {
        k_fwd_x<<<dim3(576), dim3(256), 32*(WA+8)*2, stream>>>(UA,UB,FTA,FTB,TbfA,TbfB);
        k_fwd_y<<<dim3(192), dim3(256), 0, stream>>>(FTA,FTB,Ty2A,Ty2B,CINa,CINb);
        k_spectral<<<dim3(96,8), dim3(256), 0, stream>>>(
            A_re + (size_t)l*PP*PP*MM*MM, A_im + (size_t)l*PP*PP*MM*MM,
            CINa, CINb, PART);
        k_invy<<<dim3(144), dim3(256), 0, stream>>>(PART, TyIA, TyIB, DA, DB);
        k_inv<<<dim3(512 + 128), dim3(256), 0, stream>>>(DA, DB, UA, SBbf,
            T2x, T2xB,
            WcT + (size_t)(l*2 + 0)*3072, WcT + (size_t)(l*2 + 1)*3072,
            c1a_b + (size_t)l*PA, c2a_b + (size_t)l*PA);
        k_conv3x3_mfma<<<dim3(1024), dim3(256), 0, stream>>>(SBbf, (float*)nullptr, TBbf,
            WT + (size_t)(l*2 + 0)*27648, c1b_b + (size_t)l*PB, (const float*)nullptr);
        k_conv3x3_mfma<<<dim3(1024), dim3(256), 0, stream>>>(TBbf, UB, (short*)nullptr,
            WT + (size_t)(l*2 + 1)*27648, c2b_b + (size_t)l*PB, UB);
    }
    k_decode<<<dim3(320), dim3(256), 0, stream>>>(UA, UB,
        dec_a_w, dec_a_b, dec_b_w, dec_b_b, (float*)d_out);
}

// Round 13
// 308.208 us; speedup vs baseline: 2.7762x; 1.1064x over previous
//
#include <hip/hip_runtime.h>

#define HA 256
#define WA 256
#define HB 128
#define WB 128
#define PA 48
#define PB 48
#define PP 96
#define MM 32
#define NPIXA (HA*WA)   // 65536
#define NPIXB (HB*WB)   // 16384

typedef short bf16x8 __attribute__((ext_vector_type(8)));
typedef float f32x4 __attribute__((ext_vector_type(4)));

__device__ __forceinline__ float gelu_f(float x) {
    float z = 0.7978845608028654f * (x + 0.044715f * x * x * x);
    float e = __expf(2.0f * z);
    return x - x / (e + 1.0f);
}

__device__ __forceinline__ short f2bf(float f) {
    unsigned u = __float_as_uint(f);
    unsigned r = (u + 0x7FFFu + ((u >> 16) & 1u)) >> 16;
    return (short)r;
}

__device__ __forceinline__ unsigned pack2(float a, float b) {
    return (unsigned)(unsigned short)f2bf(a) | ((unsigned)(unsigned short)f2bf(b) << 16);
}

// ---------------- tables + encoder + weight transforms, fused ----------------
__global__ __launch_bounds__(256) void k_pre(
        float* tiyA, float* tixB, float* tiyB, short* T2x,
        const float* u_a, const float* x_a, const float* u_b, const float* x_b,
        const float* wa, const float* ba, const float* wb, const float* bb,
        float* UA, float* UB,
        const float* c1b_w, const float* c2b_w, short* WT,
        short* TbfA, short* TbfB,
        const float* c1a_w, const float* c2a_w, short* WcT,
        short* Ty2A, short* Ty2B,
        short* TyIA, short* TyIB, short* T2xB) {
    const float TWO_PI = 6.28318530717958647692f;
    int bid = blockIdx.x;
    if (bid < 48) {
        int t = bid * 256 + threadIdx.x;
        if (t < MM * WA) {
            int k = t / WA, x = t - k * WA;
            int m = (k * x) & (WA - 1);
            float ang = TWO_PI * (float)m / (float)WA;
            float s, c; __sincosf(ang, &s, &c);
            float wgt = (k == 0) ? 1.0f : 2.0f;
            T2x[x*64 + 2*k]   = f2bf(wgt * c);
            T2x[x*64 + 2*k+1] = f2bf(-wgt * s);
            int ky = k - 16;
            int my = (ky * x) & (HA - 1);
            float angy = TWO_PI * (float)my / (float)HA;
            float sy, cy; __sincosf(angy, &sy, &cy);
            tiyA[2*t] = cy; tiyA[2*t+1] = sy;
        } else if (t < MM * WA + MM * WB) {
            int t2 = t - MM * WA;
            int k = t2 / WB, x = t2 - k * WB;
            int m = (k * x) & (WB - 1);
            float ang = TWO_PI * (float)m / (float)WB;
            float s, c; __sincosf(ang, &s, &c);
            float wgt = (k == 0) ? 1.0f : 2.0f;
            tixB[2*t2] = wgt * c; tixB[2*t2+1] = wgt * s;
            int ky = k - 16;
            int my = (ky * x) & (HB - 1);
            float angy = TWO_PI * (float)my / (float)HB;
            float sy, cy; __sincosf(angy, &sy, &cy);
            tiyB[2*t2] = cy; tiyB[2*t2+1] = sy;
        }
    } else if (bid < 15408) {
        int eb = bid - 48;
        int o = eb / 320;
        int chunk = eb - o * 320;
        if (chunk < 256) {
            int pix = chunk * 256 + threadIdx.x;
            UA[(size_t)o*NPIXA + pix] = wa[o*3+0]*x_a[pix] + wa[o*3+1]*x_a[NPIXA+pix]
                                      + wa[o*3+2]*u_a[pix] + ba[o];
        } else {
            int pix = (chunk - 256) * 256 + threadIdx.x;
            UB[(size_t)o*NPIXB + pix] = wb[o*3+0]*x_b[pix] + wb[o*3+1]*x_b[NPIXB+pix]
                                      + wb[o*3+2]*u_b[pix] + bb[o];
        }
    } else if (bid < 16272) {
        int g = (bid - 15408) * 256 + threadIdx.x;
        if (g < 4*2*9*48*64) {
            int l  = g / 55296;
            int r1 = g - l*55296;
            int cv = r1 / 27648;
            int r2 = r1 - cv*27648;
            int tap = r2 / 3072;
            int r3 = r2 - tap*3072;
            int oc = r3 >> 6;
            int ic = r3 & 63;
            const float* src = cv ? c2b_w : c1b_w;
            float v = 0.f;
            if (ic < 48) v = src[(((size_t)l*48 + oc)*48 + ic)*9 + tap];
            WT[g] = f2bf(v);
        }
    } else if (bid < 16336) {
        int g = (bid - 16272) * 256 + threadIdx.x;
        int col = g >> 8, x = g & 255;
        int k = col >> 1, comp = col & 1;
        int m = (k * x) & (WA - 1);
        float ang = TWO_PI * (float)m / (float)WA;
        float s, c; __sincosf(ang, &s, &c);
        float sc = 1.0f / (float)(HA * WA);
        TbfA[col*WA + x] = f2bf(comp ? -s * sc : c * sc);
    } else if (bid < 16368) {
        int g = (bid - 16336) * 256 + threadIdx.x;
        int col = g >> 7, x = g & 127;
        int k = col >> 1, comp = col & 1;
        int m = (k * x) & (WB - 1);
        float ang = TWO_PI * (float)m / (float)WB;
        float s, c; __sincosf(ang, &s, &c);
        float sc = 1.0f / (float)(HB * WB);
        TbfB[col*WB + x] = f2bf(comp ? -s * sc : c * sc);
    } else if (bid < 16464) {
        int g = (bid - 16368) * 256 + threadIdx.x;
        int l  = g / 6144;
        int r  = g - l*6144;
        int cv = r / 3072;
        int r2 = r - cv*3072;
        int oc = r2 >> 6;
        int ic = r2 & 63;
        const float* src = cv ? c2a_w : c1a_w;
        float v = 0.f;
        if (ic < 48) v = src[((size_t)l*48 + oc)*48 + ic];
        WcT[g] = f2bf(v);
    } else if (bid < 16592) {
        int g = (bid - 16464) * 256 + threadIdx.x;
        int row = g >> 9, col = g & 511;
        int j = row >> 1, comp = row & 1;
        int y = col >> 1, comp2 = col & 1;
        int my = ((j - 16) * y) & (HA - 1);
        float ang = TWO_PI * (float)my / (float)HA;
        float sy, cy; __sincosf(ang, &sy, &cy);
        float v = comp == 0 ? (comp2 == 0 ? cy : sy) : (comp2 == 0 ? -sy : cy);
        Ty2A[g] = f2bf(v);
    } else if (bid < 16656) {
        int g = (bid - 16592) * 256 + threadIdx.x;
        int row = g >> 8, col = g & 255;
        int j = row >> 1, comp = row & 1;
        int y = col >> 1, comp2 = col & 1;
        int my = ((j - 16) * y) & (HB - 1);
        float ang = TWO_PI * (float)my / (float)HB;
        float sy, cy; __sincosf(ang, &sy, &cy);
        float v = comp == 0 ? (comp2 == 0 ? cy : sy) : (comp2 == 0 ? -sy : cy);
        Ty2B[g] = f2bf(v);
    } else if (bid < 16720) {
        int g = (bid - 16656) * 256 + threadIdx.x;
        int y = g >> 6, col = g & 63;
        int j = col >> 1, comp = col & 1;
        int my = ((j - 16) * y) & (HA - 1);
        float ang = TWO_PI * (float)my / (float)HA;
        float sy, cy; __sincosf(ang, &sy, &cy);
        TyIA[g] = f2bf(comp ? sy : cy);
    } else if (bid < 16752) {
        int g = (bid - 16720) * 256 + threadIdx.x;
        int y = g >> 6, col = g & 63;
        int j = col >> 1, comp = col & 1;
        int my = ((j - 16) * y) & (HB - 1);
        float ang = TWO_PI * (float)my / (float)HB;
        float sy, cy; __sincosf(ang, &sy, &cy);
        TyIB[g] = f2bf(comp ? sy : cy);
    } else {
        int g = (bid - 16752) * 256 + threadIdx.x;
        int x = g >> 6, col = g & 63;
        int k = col >> 1, comp = col & 1;
        int m = (k * x) & (WB - 1);
        float ang = TWO_PI * (float)m / (float)WB;
        float s, c; __sincosf(ang, &s, &c);
        float wgt = (k == 0) ? 1.0f : 2.0f;
        T2xB[g] = f2bf(comp ? -wgt * s : wgt * c);
    }
}

// ---------------- forward DFT along x via MFMA; coalesced FT writes ----------------
__global__ __launch_bounds__(256) void k_fwd_x(
        const float* __restrict__ UA, const float* __restrict__ UB,
        short* __restrict__ FTA, short* __restrict__ FTB,
        const short* __restrict__ TbfA, const short* __restrict__ TbfB) {
    extern __shared__ short lsb[];
    int bid = blockIdx.x;
    const float* U; short* FT; const short* T; int N, ymask, cshift;
    if (bid < 384) { U = UA; FT = FTA; T = TbfA; N = WA; ymask = 255; cshift = 8; }
    else { bid -= 384; U = UB; FT = FTB; T = TbfB; N = WB; ymask = 127; cshift = 7; }
    int r0 = bid * 32;
    int c = r0 >> cshift;
    int ybase = r0 & ymask;
    int NP = N + 8;
    int nq = N >> 2;
    const float4* src = (const float4*)(U + (size_t)r0 * N);
    for (int i = threadIdx.x; i < 32*nq; i += 256) {
        int r = i / nq, q = i - r*nq;
        float4 v = src[i];
        *(uint2*)(lsb + r*NP + q*4) = make_uint2(pack2(v.x, v.y), pack2(v.z, v.w));
    }
    __syncthreads();
    int wv = threadIdx.x >> 6, lane = threadIdx.x & 63;
    int n = lane & 15, kg = lane >> 4;
    int col = wv*16 + n;
    const short* Tc = T + (size_t)col * N;
    f32x4 acc0 = {0.f,0.f,0.f,0.f}, acc1 = {0.f,0.f,0.f,0.f};
    for (int ks = 0; ks < (N >> 5); ++ks) {
        bf16x8 bfrag = *(const bf16x8*)(Tc + ks*32 + kg*8);
        bf16x8 a0 = *(const bf16x8*)(lsb + (size_t)n*NP + ks*32 + kg*8);
        bf16x8 a1 = *(const bf16x8*)(lsb + (size_t)(16+n)*NP + ks*32 + kg*8);
        acc0 = __builtin_amdgcn_mfma_f32_16x16x32_bf16(a0, bfrag, acc0, 0, 0, 0);
        acc1 = __builtin_amdgcn_mfma_f32_16x16x32_bf16(a1, bfrag, acc1, 0, 0, 0);
    }
    __syncthreads();
    short* trb = lsb;
    #pragma unroll
    for (int r = 0; r < 4; ++r) {
        trb[col*36 + kg*4 + r]      = f2bf(acc0[r]);
        trb[col*36 + 16 + kg*4 + r] = f2bf(acc1[r]);
    }
    __syncthreads();
    int K2 = 2 * (ymask + 1);
    for (int idx = threadIdx.x; idx < 512; idx += 256) {
        int kx = idx >> 4, q = idx & 15;
        int yl = q * 2;
        unsigned lo = (unsigned)(unsigned short)trb[(2*kx+0)*36 + yl]
                    | ((unsigned)(unsigned short)trb[(2*kx+1)*36 + yl] << 16);
        unsigned hi = (unsigned)(unsigned short)trb[(2*kx+0)*36 + yl+1]
                    | ((unsigned)(unsigned short)trb[(2*kx+1)*36 + yl+1] << 16);
        *(uint2*)(FT + ((size_t)(c*32 + kx))*K2 + 2*(size_t)ybase + yl*2) = make_uint2(lo, hi);
    }
}

// ---------------- forward DFT along y via MFMA (2-way K-split partials) ----------------
__global__ __launch_bounds__(256) void k_fwd_y(
        const short* __restrict__ FTA, const short* __restrict__ FTB,
        const short* __restrict__ Ty2A, const short* __restrict__ Ty2B,
        float* __restrict__ CINa, float* __restrict__ CINb) {
    __shared__ short lsb[32*264];
    int bid = blockIdx.x;
    const short* FT; const short* Ty; int K2, NP, pbase, c, h;
    if (bid < 96) { c = bid>>1; h = bid&1; FT = FTA; Ty = Ty2A; K2 = 512; NP = 264; pbase = 0; }
    else { int b2 = bid - 96; c = b2>>1; h = b2&1; FT = FTB; Ty = Ty2B; K2 = 256; NP = 136; pbase = 48; }
    float* CO = (h == 0) ? CINa : CINb;
    int hlen = K2 >> 1;
    int nchunk = hlen >> 3;
    for (int idx = threadIdx.x; idx < 32*nchunk; idx += 256) {
        int row = idx / nchunk, q = idx - row*nchunk;
        *(uint4*)(lsb + row*NP + q*8) =
            *(const uint4*)(FT + ((size_t)c*32 + row)*K2 + h*hlen + q*8);
    }
    __syncthreads();
    int w = threadIdx.x >> 6, lane = threadIdx.x & 63;
    int n = lane & 15, kg = lane >> 4;
    f32x4 acc0 = {0.f,0.f,0.f,0.f}, acc1 = {0.f,0.f,0.f,0.f};
    int nks = hlen >> 5;
    for (int ks = 0; ks < nks; ++ks) {
        bf16x8 af = *(const bf16x8*)(Ty + (size_t)(w*16 + n)*K2 + h*hlen + ks*32 + kg*8);
        bf16x8 b0 = *(const bf16x8*)(lsb + n*NP + ks*32 + kg*8);
        bf16x8 b1 = *(const bf16x8*)(lsb + (16+n)*NP + ks*32 + kg*8);
        acc0 = __builtin_amdgcn_mfma_f32_16x16x32_bf16(af, b0, acc0, 0, 0, 0);
        acc1 = __builtin_amdgcn_mfma_f32_16x16x32_bf16(af, b1, acc1, 0, 0, 0);
    }
    #pragma unroll
    for (int r = 0; r < 4; ++r) {
        int row = w*16 + kg*4 + r;
        int j = row >> 1, comp = row & 1;
        size_t base = (((size_t)(pbase + c))*32 + j)*32;
        CO[(base + n)*2 + comp]      = acc0[r];
        CO[(base + 16 + n)*2 + comp] = acc1[r];
    }
}

// ---------------- spectral mix: float4, 8-way q-split, 4 modes/thread ----------------
__global__ __launch_bounds__(256) void k_spectral(
        const float* __restrict__ Wre, const float* __restrict__ Wim,
        const float* __restrict__ CINa, const float* __restrict__ CINb,
        float2* __restrict__ PART) {
    int part = blockIdx.y;
    int t = blockIdx.x * 256 + threadIdx.x;
    int p = t >> 8;
    int m4 = (t & 255) << 2;
    int q0 = part * 12;
    const float4* wr = (const float4*)(Wre + ((size_t)p * PP + q0) * 1024 + m4);
    const float4* wi = (const float4*)(Wim + ((size_t)p * PP + q0) * 1024 + m4);
    const float4* ca = (const float4*)(CINa + (size_t)q0 * 2048 + m4*2);
    const float4* cb = (const float4*)(CINb + (size_t)q0 * 2048 + m4*2);
    float re0=0,re1=0,re2=0,re3=0, im0=0,im1=0,im2=0,im3=0;
    #pragma unroll
    for (int q = 0; q < 12; ++q) {
        float4 a = wr[q * 256];
        float4 b = wi[q * 256];
        float4 c0 = ca[q * 512];
        float4 c1 = ca[q * 512 + 1];
        float4 d0 = cb[q * 512];
        float4 d1 = cb[q * 512 + 1];
        float cr0 = c0.x + d0.x, ci0 = c0.y + d0.y;
        float cr1 = c0.z + d0.z, ci1 = c0.w + d0.w;
        float cr2 = c1.x + d1.x, ci2 = c1.y + d1.y;
        float cr3 = c1.z + d1.z, ci3 = c1.w + d1.w;
        re0 += a.x*cr0 - b.x*ci0;  im0 += a.x*ci0 + b.x*cr0;
        re1 += a.y*cr1 - b.y*ci1;  im1 += a.y*ci1 + b.y*cr1;
        re2 += a.z*cr2 - b.z*ci2;  im2 += a.z*ci2 + b.z*cr2;
        re3 += a.w*cr3 - b.w*ci3;  im3 += a.w*ci3 + b.w*cr3;
    }
    float2* po = PART + ((size_t)part * PP + p) * 1024 + m4;
    po[0] = make_float2(re0, im0);
    po[1] = make_float2(re1, im1);
    po[2] = make_float2(re2, im2);
    po[3] = make_float2(re3, im3);
}

// ---------------- inverse DFT along y via MFMA (fuses cred) ----------------
__global__ __launch_bounds__(256) void k_invy(
        const float2* __restrict__ PART,
        const short* __restrict__ TyIA, const short* __restrict__ TyIB,
        short* __restrict__ DA, short* __restrict__ DB) {
    __shared__ short A2[64*72];
    int bid = blockIdx.x;
    int c, yh, cb; const short* Ty; short* D;
    if (bid < 96) { c = bid >> 1; yh = bid & 1; Ty = TyIA; D = DA; cb = c; }
    else { c = bid - 96 + 48; yh = 0; Ty = TyIB; D = DB; cb = c - 48; }
    for (int idx = threadIdx.x; idx < 1024; idx += 256) {
        int j = idx >> 5, kx = idx & 31;
        float re = 0.f, im = 0.f;
        const float2* pp = PART + (size_t)c*1024 + idx;
        #pragma unroll
        for (int u = 0; u < 8; ++u) {
            float2 v = pp[(size_t)u*PP*1024];
            re += v.x; im += v.y;
        }
        A2[(2*kx+0)*72 + 2*j]   = f2bf(re);
        A2[(2*kx+0)*72 + 2*j+1] = f2bf(-im);
        A2[(2*kx+1)*72 + 2*j]   = f2bf(im);
        A2[(2*kx+1)*72 + 2*j+1] = f2bf(re);
    }
    __syncthreads();
    int wv = threadIdx.x >> 6, lane = threadIdx.x & 63;
    int n = lane & 15, kg = lane >> 4;
    #pragma unroll
    for (int ntl = 0; ntl < 2; ++ntl) {
        int nt = wv*2 + ntl;
        int y = yh*128 + nt*16 + n;
        bf16x8 bf0 = *(const bf16x8*)(Ty + (size_t)y*64 + kg*8);
        bf16x8 bf1 = *(const bf16x8*)(Ty + (size_t)y*64 + 32 + kg*8);
        #pragma unroll
        for (int mt = 0; mt < 4; ++mt) {
            bf16x8 a0 = *(const bf16x8*)(A2 + (mt*16 + n)*72 + kg*8);
            bf16x8 a1 = *(const bf16x8*)(A2 + (mt*16 + n)*72 + 32 + kg*8);
            f32x4 acc = {0.f,0.f,0.f,0.f};
            acc = __builtin_amdgcn_mfma_f32_16x16x32_bf16(a0, bf0, acc, 0, 0, 0);
            acc = __builtin_amdgcn_mfma_f32_16x16x32_bf16(a1, bf1, acc, 0, 0, 0);
            int row0 = mt*16 + kg*4;
            *(uint2*)(D + (size_t)y*3072 + cb*64 + row0) =
                make_uint2(pack2(acc[0], acc[1]), pack2(acc[2], acc[3]));
        }
    }
}

// ---------------- fused inverse tail ----------------
// A (0..511): DA -> inv_x MFMA -> conv1 MFMA -> conv2 MFMA + resid -> UA
// B (512..639): DB -> inv_x MFMA -> SBbf pixel-major [pix][48]
__global__ __launch_bounds__(256) void k_inv(
        const short* __restrict__ DA, const short* __restrict__ DB,
        float* __restrict__ UA, short* __restrict__ SBbf,
        const short* __restrict__ T2x, const short* __restrict__ T2xB,
        const short* __restrict__ W1T, const short* __restrict__ W2T,
        const float* __restrict__ b1v, const float* __restrict__ b2v) {
    __shared__ __attribute__((aligned(16))) char smc[37888];
    int t = threadIdx.x;
    int wv = t >> 6, lane = t & 63;
    int n = lane & 15, kg = lane >> 4;
    if (blockIdx.x < 512) {
        short* b0bf  = (short*)smc;                  // [128][72]
        short* slbf  = (short*)(smc + 18432);        // [128][72]
        float* bl1   = (float*)(smc + 37120);
        float* bl2   = (float*)(smc + 37312);
        int y  = blockIdx.x >> 1;
        int xh = (blockIdx.x & 1) << 7;
        if (t >= 64 && t < 112) bl1[t-64] = b1v[t-64];
        if (t >= 128 && t < 176) bl2[t-128] = b2v[t-128];
        const short* DAy = DA + (size_t)y*3072;
        {
            f32x4 acc[2][3];
            #pragma unroll
            for (int i = 0; i < 2; ++i)
                #pragma unroll
                for (int mt = 0; mt < 3; ++mt)
                    acc[i][mt] = (f32x4){0.f,0.f,0.f,0.f};
            #pragma unroll
            for (int ks = 0; ks < 2; ++ks) {
                bf16x8 bfr[2];
                #pragma unroll
                for (int i = 0; i < 2; ++i) {
                    int px = xh + (wv*2 + i)*16 + n;
                    bfr[i] = *(const bf16x8*)(T2x + (size_t)px*64 + ks*32 + kg*8);
                }
                #pragma unroll
                for (int mt = 0; mt < 3; ++mt) {
                    bf16x8 af = *(const bf16x8*)(DAy + (mt*16 + n)*64 + ks*32 + kg*8);
                    #pragma unroll
                    for (int i = 0; i < 2; ++i)
                        acc[i][mt] = __builtin_amdgcn_mfma_f32_16x16x32_bf16(af, bfr[i], acc[i][mt], 0, 0, 0);
                }
            }
            #pragma unroll
            for (int i = 0; i < 2; ++i) {
                int xl = (wv*2 + i)*16 + n;
                #pragma unroll
                for (int mt = 0; mt < 3; ++mt)
                    #pragma unroll
                    for (int r = 0; r < 4; ++r)
                        slbf[xl*72 + mt*16 + kg*4 + r] = f2bf(acc[i][mt][r]);
            }
            for (int idx = t; idx < 2048; idx += 256)
                slbf[(idx >> 4)*72 + 48 + (idx & 15)] = 0;
        }
        __syncthreads();
        {
            bf16x8 aw[3][2];
            #pragma unroll
            for (int mt = 0; mt < 3; ++mt)
                #pragma unroll
                for (int ks = 0; ks < 2; ++ks)
                    aw[mt][ks] = *(const bf16x8*)(W1T + (size_t)(mt*16 + n)*64 + ks*32 + kg*8);
            f32x4 acc[2][3];
            #pragma unroll
            for (int nt = 0; nt < 2; ++nt)
                #pragma unroll
                for (int mt = 0; mt < 3; ++mt)
                    acc[nt][mt] = (f32x4){0.f,0.f,0.f,0.f};
            #pragma unroll
            for (int nt = 0; nt < 2; ++nt) {
                int ntile = wv*2 + nt;
                #pragma unroll
                for (int ks = 0; ks < 2; ++ks) {
                    bf16x8 bfrag = *(const bf16x8*)(slbf + (size_t)(ntile*16 + n)*72 + ks*32 + kg*8);
                    #pragma unroll
                    for (int mt = 0; mt < 3; ++mt)
                        acc[nt][mt] = __builtin_amdgcn_mfma_f32_16x16x32_bf16(aw[mt][ks], bfrag, acc[nt][mt], 0, 0, 0);
                }
            }
            #pragma unroll
            for (int nt = 0; nt < 2; ++nt) {
                int px = (wv*2 + nt)*16 + n;
                #pragma unroll
                for (int mt = 0; mt < 3; ++mt) {
                    int oc0 = mt*16 + kg*4;
                    float g0 = gelu_f(acc[nt][mt][0] + bl1[oc0+0]);
                    float g1 = gelu_f(acc[nt][mt][1] + bl1[oc0+1]);
                    float g2 = gelu_f(acc[nt][mt][2] + bl1[oc0+2]);
                    float g3 = gelu_f(acc[nt][mt][3] + bl1[oc0+3]);
                    *(uint2*)(b0bf + (size_t)px*72 + oc0) = make_uint2(pack2(g0,g1), pack2(g2,g3));
                }
            }
            for (int idx = t; idx < 2048; idx += 256)
                b0bf[(idx >> 4)*72 + 48 + (idx & 15)] = 0;
        }
        __syncthreads();
        {
            bf16x8 aw[3][2];
            #pragma unroll
            for (int mt = 0; mt < 3; ++mt)
                #pragma unroll
                for (int ks = 0; ks < 2; ++ks)
                    aw[mt][ks] = *(const bf16x8*)(W2T + (size_t)(mt*16 + n)*64 + ks*32 + kg*8);
            f32x4 acc[2][3];
            #pragma unroll
            for (int nt = 0; nt < 2; ++nt)
                #pragma unroll
                for (int mt = 0; mt < 3; ++mt)
                    acc[nt][mt] = (f32x4){0.f,0.f,0.f,0.f};
            #pragma unroll
            for (int nt = 0; nt < 2; ++nt) {
                int ntile = wv*2 + nt;
                #pragma unroll
                for (int ks = 0; ks < 2; ++ks) {
                    bf16x8 bfrag = *(const bf16x8*)(b0bf + (size_t)(ntile*16 + n)*72 + ks*32 + kg*8);
                    #pragma unroll
                    for (int mt = 0; mt < 3; ++mt)
                        acc[nt][mt] = __builtin_amdgcn_mfma_f32_16x16x32_bf16(aw[mt][ks], bfrag, acc[nt][mt], 0, 0, 0);
                }
            }
            #pragma unroll
            for (int nt = 0; nt < 2; ++nt) {
                int px = (wv*2 + nt)*16 + n;
                #pragma unroll
                for (int mt = 0; mt < 3; ++mt) {
                    int oc0 = mt*16 + kg*4;
                    #pragma unroll
                    for (int r = 0; r < 4; ++r) {
                        int oc = oc0 + r;
                        size_t o = (size_t)oc*NPIXA + (size_t)y*WA + xh + px;
                        UA[o] = gelu_f(acc[nt][mt][r] + bl2[oc]) + UA[o];
                    }
                }
            }
        }
    } else {
        // B path: inv_x MFMA, then pixel-major coalesced write
        int y = blockIdx.x - 512;
        short* sbuf = (short*)smc;    // [48][132]
        const short* DBy = DB + (size_t)y*3072;
        #pragma unroll
        for (int ntl = 0; ntl < 2; ++ntl) {
            int nt = wv*2 + ntl;
            int x = nt*16 + n;
            bf16x8 bf0 = *(const bf16x8*)(T2xB + (size_t)x*64 + kg*8);
            bf16x8 bf1 = *(const bf16x8*)(T2xB + (size_t)x*64 + 32 + kg*8);
            #pragma unroll
            for (int mt = 0; mt < 3; ++mt) {
                bf16x8 a0 = *(const bf16x8*)(DBy + (mt*16 + n)*64 + kg*8);
                bf16x8 a1 = *(const bf16x8*)(DBy + (mt*16 + n)*64 + 32 + kg*8);
                f32x4 acc = {0.f,0.f,0.f,0.f};
                acc = __builtin_amdgcn_mfma_f32_16x16x32_bf16(a0, bf0, acc, 0, 0, 0);
                acc = __builtin_amdgcn_mfma_f32_16x16x32_bf16(a1, bf1, acc, 0, 0, 0);
                int c0 = mt*16 + kg*4;
                #pragma unroll
                for (int r = 0; r < 4; ++r)
                    sbuf[(c0 + r)*132 + x] = f2bf(acc[r]);
            }
        }
        __syncthreads();
        for (int idx = t; idx < 3072; idx += 256) {
            int x = idx / 24, cu = idx - x*24;
            unsigned v = (unsigned)(unsigned short)sbuf[(2*cu)*132 + x]
                       | ((unsigned)(unsigned short)sbuf[(2*cu+1)*132 + x] << 16);
            *(unsigned*)(SBbf + ((size_t)y*WB + x)*48 + 2*cu) = v;
        }
    }
}

// ---------------- B-branch 3x3 conv via MFMA, pixel-major bf16 I/O ----------------
// block = 384 threads (6 waves = 2nt x 3mt), 1 row x 32 px x 48 oc. grid 512.
__global__ __launch_bounds__(384) void k_conv3x3_mfma(
        const short* __restrict__ in, float* __restrict__ outf,
        short* __restrict__ outbf,
        const short* __restrict__ wt, const float* __restrict__ bias,
        const float* resid) {
    __shared__ __attribute__((aligned(16))) short tile[3*34*72];   // 14688 B
    int y  = blockIdx.x >> 2;
    int x0 = (blockIdx.x & 3) << 5;
    int tid = threadIdx.x;
    for (int idx = tid; idx < 102*6; idx += 384) {
        int pix = idx / 6, chunk = idx - pix*6;
        int r = pix / 34, px = pix - r*34;
        int gy = y - 1 + r, gx = x0 - 1 + px;
        uint4 v = {0u,0u,0u,0u};
        if (gy >= 0 && gy < HB && gx >= 0 && gx < WB)
            v = *(const uint4*)(in + ((size_t)gy*WB + gx)*48 + chunk*8);
        *(uint4*)(tile + pix*72 + chunk*8) = v;
    }
    for (int idx = tid; idx < 102*2; idx += 384) {
        int pix = idx >> 1, h = idx & 1;
        *(uint4*)(tile + pix*72 + 48 + h*8) = (uint4){0u,0u,0u,0u};
    }
    __syncthreads();

    int wv = tid / 64, lane = tid & 63;
    int n = lane & 15, kg = lane >> 4;
    int nt = wv & 1, mt = wv >> 1;   // nt 0..1, mt 0..2
    f32x4 acc = {0.f,0.f,0.f,0.f};
    #pragma unroll
    for (int tap = 0; tap < 9; ++tap) {
        int dy = tap / 3, dx = tap - dy*3;
        int pxl = nt*16 + n + dx;
        const short* brow = tile + (dy*34 + pxl)*72;
        const short* ap = wt + (size_t)tap*3072 + (size_t)(mt*16 + n)*64;
        #pragma unroll
        for (int ks = 0; ks < 2; ++ks) {
            bf16x8 bfrag = *(const bf16x8*)(brow + ks*32 + kg*8);
            bf16x8 afrag = *(const bf16x8*)(ap + ks*32 + kg*8);
            acc = __builtin_amdgcn_mfma_f32_16x16x32_bf16(afrag, bfrag, acc, 0, 0, 0);
        }
    }
    int px_g = x0 + nt*16 + n;
    int oc0 = mt*16 + kg*4;
    float g0 = gelu_f(acc[0] + bias[oc0+0]);
    float g1 = gelu_f(acc[1] + bias[oc0+1]);
    float g2 = gelu_f(acc[2] + bias[oc0+2]);
    float g3 = gelu_f(acc[3] + bias[oc0+3]);
    if (outbf) {
        *(uint2*)(outbf + ((size_t)y*WB + px_g)*48 + oc0) =
            make_uint2(pack2(g0, g1), pack2(g2, g3));
    } else {
        float gv[4] = {g0, g1, g2, g3};
        #pragma unroll
        for (int r = 0; r < 4; ++r) {
            size_t o = (size_t)(oc0 + r)*NPIXB + (size_t)y*WB + px_g;
            outf[o] = gv[r] + resid[o];
        }
    }
}

// ---------------- decoder ----------------
__global__ __launch_bounds__(256) void k_decode(
        const float* __restrict__ UA, const float* __restrict__ UB,
        const float* dwa, const float* dba,
        const float* dwb, const float* dbb, float* outp) {
    int t = blockIdx.x*256 + threadIdx.x;
    if (t < NPIXA) {
        float acc = dba[0];
        #pragma unroll 8
        for (int p = 0; p < PA; ++p) acc += dwa[p]*UA[(size_t)p*NPIXA + t];
        outp[t] = acc;
    } else {
        int u = t - NPIXA;
        float acc = dbb[0];
        #pragma unroll 8
        for (int p = 0; p < PB; ++p) acc += dwb[p]*UB[(size_t)p*NPIXB + u];
        outp[t] = acc;
    }
}

extern "C" void kernel_launch(void* const* d_in, const int* in_sizes, int n_in,
                              void* d_out, int out_size, void* d_ws, size_t ws_size,
                              hipStream_t stream) {
    const float* u_a   = (const float*)d_in[0];
    const float* x_a   = (const float*)d_in[1];
    const float* u_b   = (const float*)d_in[2];
    const float* x_b   = (const float*)d_in[3];
    const float* enc_a_w = (const float*)d_in[4];
    const float* enc_a_b = (const float*)d_in[5];
    const float* enc_b_w = (const float*)d_in[6];
    const float* enc_b_b = (const float*)d_in[7];
    const float* dec_a_w = (const float*)d_in[8];
    const float* dec_a_b = (const float*)d_in[9];
    const float* dec_b_w = (const float*)d_in[10];
    const float* dec_b_b = (const float*)d_in[11];
    const float* c1a_w = (const float*)d_in[12];
    const float* c1a_b = (const float*)d_in[13];
    const float* c2a_w = (const float*)d_in[14];
    const float* c2a_b = (const float*)d_in[15];
    const float* c1b_w = (const float*)d_in[16];
    const float* c1b_b = (const float*)d_in[17];
    const float* c2b_w = (const float*)d_in[18];
    const float* c2b_b = (const float*)d_in[19];
    const float* A_re = (const float*)d_in[20];
    const float* A_im = (const float*)d_in[21];

    float* ws = (float*)d_ws;
    size_t off = 0;
    auto alloc = [&](size_t n) { float* p = ws + off; off += n; return p; };
    short* WT    = (short*)alloc(4*2*9*48*64/2);
    short* TbfA  = (short*)alloc(64*WA/2);
    short* TbfB  = (short*)alloc(64*WB/2);
    short* WcT   = (short*)alloc(4*2*48*64/2);
    short* T2x   = (short*)alloc(WA*64/2);
    short* T2xB  = (short*)alloc(WB*64/2);
    short* Ty2A  = (short*)alloc(64*512/2);
    short* Ty2B  = (short*)alloc(64*256/2);
    short* TyIA  = (short*)alloc(HA*64/2);
    short* TyIB  = (short*)alloc(HB*64/2);
    float* TiyA  = alloc(MM*HA*2);
    float* TixB  = alloc(MM*WB*2);
    float* TiyB  = alloc(MM*HB*2);
    float* UA = alloc((size_t)PA*NPIXA);
    float* UB = alloc((size_t)PB*NPIXB);
    short* SBbf = (short*)alloc((size_t)PB*NPIXB/2);   // pixel-major [pix][48]
    short* TBbf = (short*)alloc((size_t)PB*NPIXB/2);   // pixel-major [pix][48]
    short* FTA = (short*)alloc((size_t)PA*MM*512/2);
    short* FTB = (short*)alloc((size_t)PB*MM*256/2);
    short* DA  = (short*)alloc((size_t)HA*3072/2);
    short* DB  = (short*)alloc((size_t)HB*3072/2);
    float* CINa = alloc((size_t)PP*MM*MM*2);
    float* CINb = alloc((size_t)PP*MM*MM*2);
    float2* PART = (float2*)alloc((size_t)8*PP*MM*MM*2);
    if (off * sizeof(float) > ws_size) return;

    k_pre<<<dim3(16784), dim3(256), 0, stream>>>(
        TiyA, TixB, TiyB, T2x,
        u_a,x_a,u_b,x_b, enc_a_w,enc_a_b,enc_b_w,enc_b_b, UA,UB,
        c1b_w, c2b_w, WT, TbfA, TbfB, c1a_w, c2a_w, WcT, Ty2A, Ty2B,
        TyIA, TyIB, T2xB);
    for (int l = 0; l < 4; ++l) {
        k_fwd_x<<<dim3(576), dim3(256), 32*(WA+8)*2, stream>>>(UA,UB,FTA,FTB,TbfA,TbfB);
        k_fwd_y<<<dim3(192), dim3(256), 0, stream>>>(FTA,FTB,Ty2A,Ty2B,CINa,CINb);
        k_spectral<<<dim3(96,8), dim3(256), 0, stream>>>(
            A_re + (size_t)l*PP*PP*MM*MM, A_im + (size_t)l*PP*PP*MM*MM,
            CINa, CINb, PART);
        k_invy<<<dim3(144), dim3(256), 0, stream>>>(PART, TyIA, TyIB, DA, DB);
        k_inv<<<dim3(512 + 128), dim3(256), 0, stream>>>(DA, DB, UA, SBbf,
            T2x, T2xB,
            WcT + (size_t)(l*2 + 0)*3072, WcT + (size_t)(l*2 + 1)*3072,
            c1a_b + (size_t)l*PA, c2a_b + (size_t)l*PA);
        k_conv3x3_mfma<<<dim3(512), dim3(384), 0, stream>>>(SBbf, (float*)nullptr, TBbf,
            WT + (size_t)(l*2 + 0)*27648, c1b_b + (size_t)l*PB, (const float*)nullptr);
        k_conv3x3_mfma<<<dim3(512), dim3(384), 0, stream>>>(TBbf, UB, (short*)nullptr,
            WT + (size_t)(l*2 + 1)*27648, c2b_b + (size_t)l*PB, UB);
    }
    k_decode<<<dim3(320), dim3(256), 0, stream>>>(UA, UB,
        dec_a_w, dec_a_b, dec_b_w, dec_b_b, (float*)d_out);
}